// Round 8
// baseline (2846.532 us; speedup 1.0000x reference)
//
#include <hip/hip_runtime.h>
#include <hip/hip_bf16.h>
#include <math.h>

// ---------------------------------------------------------------------------
// GraphEncoder round 8 (= round-7 resubmission; that bench died on container
// infra before launch, same flake as rounds 2/5):
// Round-7 delta vs round 6: in-kernel column-tile loop (nt) in mfma_gemm so
// each block covers all N col-tiles of its 128-row panel -> A is HBM-fetched
// once and re-staged from the same XCD's L2 (round-6 counters: LSTM GEMM
// FETCH 457MB vs ideal 205MB from A refetch).
// LSTM: grid(782,1) nt=8; xlr: nt=4; lin0: nt=2.
// ---------------------------------------------------------------------------

constexpr int NN    = 100000;
constexpr int EE    = 400000;
constexpr int EP    = EE + NN;      // 500000 (incl self loops)
constexpr int BG    = 4096;
constexpr int FIN   = 300;
constexpr int HEADS = 4;
constexpr int HID   = 256;
constexpr int G4H   = 1024;
constexpr int NH1   = 512;
constexpr int NH2   = 768;
constexpr int MP    = 100096;       // 782*128
constexpr int KP0   = 320;          // FIN padded to mult of 32

typedef __attribute__((ext_vector_type(4))) float f32x4;
typedef __attribute__((ext_vector_type(8))) short s16x8;

__device__ inline float sigm(float x) { return 1.f / (1.f + expf(-x)); }
__device__ inline float b2f(short s) { return __uint_as_float(((unsigned)(unsigned short)s) << 16); }
__device__ inline short f2b(float f) {
    unsigned u = __float_as_uint(f);
    u += 0x7fff + ((u >> 16) & 1);          // round-to-nearest-even
    return (short)(u >> 16);
}
__device__ inline float wsum64(float v) {
#pragma unroll
    for (int o = 32; o > 0; o >>= 1) v += __shfl_xor(v, o);
    return v;
}

// ---------------- utility kernels -------------------------------------------
__global__ __launch_bounds__(256) void zero_f32(float* __restrict__ p, long long n)
{
    long long i = (long long)blockIdx.x * 256 + threadIdx.x;
    long long stride = (long long)gridDim.x * 256;
    for (; i < n; i += stride) p[i] = 0.f;
}

// f32 -> bf16 with row/col zero padding
__global__ __launch_bounds__(256) void conv_bf16(
    const float* __restrict__ src, short* __restrict__ dst,
    int rsrc, int rdst, int Ks, int Kd)
{
    long long n = (long long)rdst * Kd;
    long long stride = (long long)gridDim.x * 256;
    for (long long i = (long long)blockIdx.x * 256 + threadIdx.x; i < n; i += stride) {
        int r = (int)(i / Kd);
        int k = (int)(i - (long long)r * Kd);
        float v = (r < rsrc && k < Ks) ? src[(long long)r * Ks + k] : 0.f;
        dst[i] = f2b(v);
    }
}

// gate-interleaved pack of LSTM weight [1024][K]:
// new row p -> orig row gate*256+ch, gate=(p>>4)&3, ch=(p>>7)*32+((p>>6)&1)*16+(p&15)
__global__ __launch_bounds__(256) void conv_gates(
    const float* __restrict__ src, short* __restrict__ dst, int K)
{
    long long n = (long long)G4H * K;
    long long stride = (long long)gridDim.x * 256;
    for (long long i = (long long)blockIdx.x * 256 + threadIdx.x; i < n; i += stride) {
        int p = (int)(i / K);
        int k = (int)(i - (long long)p * K);
        int gate = (p >> 4) & 3;
        int ch   = (p >> 7) * 32 + ((p >> 6) & 1) * 16 + (p & 15);
        dst[i] = f2b(src[(size_t)(gate * 256 + ch) * K + k]);
    }
}

__global__ __launch_bounds__(256) void concat2_f32(
    const float* __restrict__ a, const float* __restrict__ b,
    float* __restrict__ dst, int na, int nb)
{
    int i = blockIdx.x * 256 + threadIdx.x;
    if (i < na) dst[i] = a[i];
    else if (i < na + nb) dst[i] = b[i - na];
}

// ---------------- CSR build -------------------------------------------------
__global__ __launch_bounds__(256) void edge_hist(const int* __restrict__ ei,
                                                 int* __restrict__ deg)
{
    int e = blockIdx.x * 256 + threadIdx.x;
    if (e >= EP) return;
    int d = (e < EE) ? ei[EE + e] : e - EE;
    atomicAdd(&deg[d], 1);
}

__global__ __launch_bounds__(1024) void scan_deg(const int* __restrict__ deg,
                                                 int* __restrict__ rowptr,
                                                 int* __restrict__ cursor)
{
    __shared__ int part[1024];
    int t = threadIdx.x;
    const int CH = (NN + 1023) / 1024;
    int lo = t * CH, hi = min(lo + CH, NN);
    int s = 0;
    for (int i = lo; i < hi; ++i) s += deg[i];
    part[t] = s;
    __syncthreads();
    for (int off = 1; off < 1024; off <<= 1) {
        int v = (t >= off) ? part[t - off] : 0;
        __syncthreads();
        part[t] += v;
        __syncthreads();
    }
    int run = (t == 0) ? 0 : part[t - 1];
    for (int i = lo; i < hi; ++i) { rowptr[i] = run; cursor[i] = 0; run += deg[i]; }
    if (t == 1023) rowptr[NN] = run;   // == EP
}

__global__ __launch_bounds__(256) void edge_fill(const int* __restrict__ ei,
                                                 const int* __restrict__ rowptr,
                                                 int* __restrict__ cursor,
                                                 int* __restrict__ esrc)
{
    int e = blockIdx.x * 256 + threadIdx.x;
    if (e >= EP) return;
    int s, d;
    if (e < EE) { s = ei[e]; d = ei[EE + e]; }
    else        { s = d = e - EE; }
    int slot = rowptr[d] + atomicAdd(&cursor[d], 1);
    esrc[slot] = s;
}

// ---------------- MFMA GEMM with fused epilogues ----------------------------
// C[M x N] = A1[M x K1] @ B1[N x K1]^T (+ A2[M x K2] @ B2[N x K2]^T)
// Each block covers nt consecutive 128-col tiles of one 128-row panel
// (A re-staged from L2 after the first tile).
// mode 0: +bias -> f32 Cf      mode 1: +bias -> bf16 Cb
// mode 2: LSTM epilogue (gate-interleaved B; N=1024): reads c_in (or 0),
//         writes c_out f32 + h_out bf16, both [M][256].
__global__ __launch_bounds__(256) void mfma_gemm(
    const short* __restrict__ A1, const short* __restrict__ B1, int K1,
    const short* __restrict__ A2, const short* __restrict__ B2, int K2,
    const float* __restrict__ bias,
    const float* __restrict__ bih, const float* __restrict__ bhh,
    const float* __restrict__ c_in, float* __restrict__ c_out,
    short* __restrict__ h_out,
    float* __restrict__ Cf, short* __restrict__ Cb, int N, int mode, int nt)
{
    __shared__ __align__(16) short sA[128 * 32];
    __shared__ __align__(16) short sB[128 * 32];
    const int tid  = threadIdx.x;
    const int w    = tid >> 6, lane = tid & 63;
    const int wr   = w >> 1,  wc   = w & 1;      // 2x2 waves of 64x64
    const int row0 = blockIdx.x * 128;
    const int rs = lane >> 2;
    const int cs = lane & 3;
    const int KK = K1 + K2;

    for (int ct = 0; ct < nt; ++ct) {
        const int tcol = blockIdx.y * nt + ct;
        const int col0 = tcol * 128;

        f32x4 acc[4][4];
#pragma unroll
        for (int m = 0; m < 4; ++m)
#pragma unroll
            for (int n = 0; n < 4; ++n) acc[m][n] = (f32x4){0.f, 0.f, 0.f, 0.f};

        for (int k0 = 0; k0 < KK; k0 += 32) {
            const short* Ak; const short* Bk; int kk, ld;
            if (k0 < K1) { Ak = A1; Bk = B1; kk = k0;      ld = K1; }
            else         { Ak = A2; Bk = B2; kk = k0 - K1; ld = K2; }
#pragma unroll
            for (int i = 0; i < 2; ++i) {
                int seg = w * 2 + i;
                int row = seg * 16 + rs;
                int c8  = cs ^ ((row + (row >> 2)) & 3);
                const short* ga = Ak + (size_t)(row0 + row) * ld + kk + c8 * 8;
                const short* gb = Bk + (size_t)(col0 + row) * ld + kk + c8 * 8;
                short* la = sA + seg * 512 + lane * 8;
                short* lb = sB + seg * 512 + lane * 8;
                __builtin_amdgcn_global_load_lds((const __attribute__((address_space(1))) void*)ga,
                                                 (__attribute__((address_space(3))) void*)la, 16, 0, 0);
                __builtin_amdgcn_global_load_lds((const __attribute__((address_space(1))) void*)gb,
                                                 (__attribute__((address_space(3))) void*)lb, 16, 0, 0);
            }
            __syncthreads();

            s16x8 af[4], bg[4];
            {
                const int rl = lane & 15;
                const int cw = lane >> 4;
#pragma unroll
                for (int m = 0; m < 4; ++m) {
                    int r  = wr * 64 + m * 16 + rl;
                    int sl = cw ^ ((r + (r >> 2)) & 3);
                    af[m] = *(const s16x8*)(sA + r * 32 + sl * 8);
                    int c  = wc * 64 + m * 16 + rl;
                    int sc = cw ^ ((c + (c >> 2)) & 3);
                    bg[m] = *(const s16x8*)(sB + c * 32 + sc * 8);
                }
            }
#pragma unroll
            for (int m = 0; m < 4; ++m)
#pragma unroll
                for (int n = 0; n < 4; ++n)
                    acc[m][n] = __builtin_amdgcn_mfma_f32_16x16x32_bf16(af[m], bg[n], acc[m][n], 0, 0, 0);
            __syncthreads();
        }

        // C/D layout: col=lane&15, row=(lane>>4)*4+reg
        const int l16   = lane & 15;
        const int rbase = row0 + wr * 64 + (lane >> 4) * 4;
        if (mode == 2) {
            const int ch = tcol * 32 + wc * 16 + l16;
            float bi[4];
#pragma unroll
            for (int g = 0; g < 4; ++g) bi[g] = bih[g * 256 + ch] + bhh[g * 256 + ch];
#pragma unroll
            for (int m = 0; m < 4; ++m) {
#pragma unroll
                for (int r = 0; r < 4; ++r) {
                    int row = rbase + m * 16 + r;
                    float gi = acc[m][0][r] + bi[0];
                    float gf = acc[m][1][r] + bi[1];
                    float gg = acc[m][2][r] + bi[2];
                    float go = acc[m][3][r] + bi[3];
                    size_t idx = (size_t)row * HID + ch;
                    float co = c_in ? c_in[idx] : 0.f;
                    float c2 = sigm(gf) * co + sigm(gi) * tanhf(gg);
                    float h2 = sigm(go) * tanhf(c2);
                    c_out[idx] = c2;
                    h_out[idx] = f2b(h2);
                }
            }
        } else {
            const int cbase = col0 + wc * 64 + l16;
#pragma unroll
            for (int n = 0; n < 4; ++n) {
                int col = cbase + n * 16;
                float ba = bias ? bias[col] : 0.f;
#pragma unroll
                for (int m = 0; m < 4; ++m) {
#pragma unroll
                    for (int r = 0; r < 4; ++r) {
                        int row = rbase + m * 16 + r;
                        float v = acc[m][n][r] + ba;
                        size_t idx = (size_t)row * N + col;
                        if (mode == 1) Cb[idx] = f2b(v);
                        else           Cf[idx] = v;
                    }
                }
            }
        }
    }
}

// ---------------- fused GATv2 (softmax + aggregate + bias + LN + ELU) -------
// one 64-lane wave per dst node; lane l = channel h*64+l per head h.
// xlr: [MP][512] bf16, cols 0..255 = lin_l(x), 256..511 = lin_r(x).
__global__ __launch_bounds__(256) void gat_fused(
    const short* __restrict__ xlr, const int* __restrict__ rowptr,
    const int* __restrict__ esrc, const float* __restrict__ att,
    const float* __restrict__ gb, const float* __restrict__ lg,
    const float* __restrict__ lb, short* __restrict__ outb)
{
    int i    = blockIdx.x * 4 + (threadIdx.x >> 6);
    int lane = threadIdx.x & 63;
    if (i >= NN) return;
    float xr[HEADS], at[HEADS];
#pragma unroll
    for (int h = 0; h < HEADS; ++h) {
        xr[h] = b2f(xlr[(size_t)i * 512 + 256 + h * 64 + lane]);
        at[h] = att[h * 64 + lane];
    }
    float mx[HEADS], sm[HEADS], ac[HEADS];
#pragma unroll
    for (int h = 0; h < HEADS; ++h) { mx[h] = -INFINITY; sm[h] = 0.f; ac[h] = 0.f; }

    int lo = rowptr[i], hi = rowptr[i + 1];
    for (int e = lo; e < hi; ++e) {
        int s = esrc[e];
        float xs[HEADS], p[HEADS];
#pragma unroll
        for (int h = 0; h < HEADS; ++h) {
            xs[h] = b2f(xlr[(size_t)s * 512 + h * 64 + lane]);
            float v = xs[h] + xr[h];
            v = (v >= 0.f) ? v : 0.2f * v;
            p[h] = v * at[h];
        }
#pragma unroll
        for (int h = 0; h < HEADS; ++h) p[h] = wsum64(p[h]);
#pragma unroll
        for (int h = 0; h < HEADS; ++h) {
            float mn = fmaxf(mx[h], p[h]);
            float sc = expf(mx[h] - mn);     // first iter: exp(-inf)=0
            float a  = expf(p[h] - mn);
            sm[h] = sm[h] * sc + a;
            ac[h] = ac[h] * sc + a * xs[h];
            mx[h] = mn;
        }
    }
    // y = ac/sm (+ gat bias), then LayerNorm(256) + ELU, write bf16
    float val[HEADS], s1 = 0.f, s2 = 0.f;
#pragma unroll
    for (int h = 0; h < HEADS; ++h) {
        float v = ac[h] / sm[h] + gb[h * 64 + lane];
        val[h] = v; s1 += v; s2 += v * v;
    }
    s1 = wsum64(s1); s2 = wsum64(s2);
    float mean = s1 * (1.f / 256.f);
    float var  = s2 * (1.f / 256.f) - mean * mean;
    float inv  = rsqrtf(var + 1e-5f);
#pragma unroll
    for (int h = 0; h < HEADS; ++h) {
        float v = (val[h] - mean) * inv * lg[h * 64 + lane] + lb[h * 64 + lane];
        v = (v > 0.f) ? v : expm1f(v);
        outb[(size_t)i * HID + h * 64 + lane] = f2b(v);
    }
}

// ---------------- LayerNorm (+act) for the MLP head -------------------------
__global__ __launch_bounds__(256) void ln_act_kernel(
    const float* __restrict__ in, const float* __restrict__ gamma,
    const float* __restrict__ beta, float* __restrict__ outf,
    short* __restrict__ outb, int width, int act)
{
    int row = blockIdx.x;
    const float* ip = in + (size_t)row * width;
    float vals[3];
    float s = 0.f, ss = 0.f;
    int nw = width >> 8;
    for (int i = 0; i < nw; ++i) {
        int c = threadIdx.x + (i << 8);
        float v = ip[c];
        vals[i] = v; s += v; ss += v * v;
    }
#pragma unroll
    for (int off = 32; off > 0; off >>= 1) {
        s  += __shfl_down(s, off);
        ss += __shfl_down(ss, off);
    }
    __shared__ float sh[8];
    int wv = threadIdx.x >> 6, lane = threadIdx.x & 63;
    if (lane == 0) { sh[wv] = s; sh[4 + wv] = ss; }
    __syncthreads();
    if (threadIdx.x == 0) {
        sh[0] = sh[0] + sh[1] + sh[2] + sh[3];
        sh[4] = sh[4] + sh[5] + sh[6] + sh[7];
    }
    __syncthreads();
    float mean = sh[0] / width;
    float var  = sh[4] / width - mean * mean;
    float inv  = rsqrtf(var + 1e-5f);
    for (int i = 0; i < nw; ++i) {
        int c = threadIdx.x + (i << 8);
        float v = (vals[i] - mean) * inv * gamma[c] + beta[c];
        if (act == 1) v = fmaxf(v, 0.f);
        if (outb) outb[(size_t)row * width + c] = f2b(v);
        else      outf[(size_t)row * width + c] = v;
    }
}

// ---------------- sorted-batch mean pool ------------------------------------
__global__ __launch_bounds__(256) void pool_mean(
    const short* __restrict__ h, const int* __restrict__ batch,
    short* __restrict__ poolb)
{
    int b    = blockIdx.x * 4 + (threadIdx.x >> 6);
    int lane = threadIdx.x & 63;
    if (b >= BG) return;
    auto lbound = [&](int key) {
        int lo = 0, hi = NN;
        while (lo < hi) { int mid = (lo + hi) >> 1; if (batch[mid] < key) lo = mid + 1; else hi = mid; }
        return lo;
    };
    int lo = lbound(b), hi = lbound(b + 1);
    float acc[HEADS] = {0.f, 0.f, 0.f, 0.f};
    for (int r = lo; r < hi; ++r)
#pragma unroll
        for (int hh = 0; hh < HEADS; ++hh)
            acc[hh] += b2f(h[(size_t)r * HID + hh * 64 + lane]);
    float inv = 1.f / fmaxf((float)(hi - lo), 1.f);
#pragma unroll
    for (int hh = 0; hh < HEADS; ++hh)
        poolb[(size_t)b * HID + hh * 64 + lane] = f2b(acc[hh] * inv);
}

// ---------------------------------------------------------------------------
extern "C" void kernel_launch(void* const* d_in, const int* in_sizes, int n_in,
                              void* d_out, int out_size, void* d_ws, size_t ws_size,
                              hipStream_t stream)
{
    (void)in_sizes; (void)n_in; (void)out_size; (void)ws_size;
    const float* x      = (const float*)d_in[0];
    const int*   ei     = (const int*)d_in[1];
    const int*   batch  = (const int*)d_in[2];
    const float* lin0_w = (const float*)d_in[4];
    const float* lin0_b = (const float*)d_in[5];
    const float* r0_wih = (const float*)d_in[6];
    const float* r0_bih = (const float*)d_in[8];
    const float* r0_bhh = (const float*)d_in[9];
    const float* mh1_w  = (const float*)d_in[46];
    const float* mh1_b  = (const float*)d_in[47];
    const float* ln1_g  = (const float*)d_in[48];
    const float* ln1_b  = (const float*)d_in[49];
    const float* mh2_w  = (const float*)d_in[50];
    const float* mh2_b  = (const float*)d_in[51];
    const float* ln2_g  = (const float*)d_in[52];
    const float* ln2_b  = (const float*)d_in[53];
    float* out = (float*)d_out;

    // ---- workspace bump allocation ----
    char* wsb = (char*)d_ws;
    auto alloc = [&](size_t bytes) -> void* {
        void* p = (void*)wsb;
        wsb += (bytes + 255) & ~(size_t)255;
        return p;
    };
    const size_t NH = (size_t)MP * HID;
    float* cb   = (float*)alloc(NH * 4);          // LSTM cell state f32
    short* hA   = (short*)alloc(NH * 2);          // h ping
    short* hB   = (short*)alloc(NH * 2);          // h pong
    short* ybb  = (short*)alloc(NH * 2);          // LSTM-input / x0 bf16
    short* xlr  = (short*)alloc((size_t)MP * 512 * 2);  // [xl|xr] bf16
    int*   deg    = (int*)alloc((size_t)NN * 4);
    int*   rowptr = (int*)alloc((size_t)(NN + 1) * 4);
    int*   cursor = (int*)alloc((size_t)NN * 4);
    int*   esrc   = (int*)alloc((size_t)EP * 4);
    // weights bf16
    short* w_lin0 = (short*)alloc((size_t)256 * KP0 * 2);
    short* w_r0   = (short*)alloc((size_t)G4H * 256 * 2);
    short* w_lr[3]; short* w_ih[3]; short* w_hh[3]; float* blr[3];
    for (int l = 0; l < 3; ++l) {
        int Kp = (l == 0) ? KP0 : 256;
        w_lr[l] = (short*)alloc((size_t)512 * Kp * 2);
        w_ih[l] = (short*)alloc((size_t)G4H * 256 * 2);
        w_hh[l] = (short*)alloc((size_t)G4H * 256 * 2);
        blr[l]  = (float*)alloc(512 * 4);
    }
    short* w_m1 = (short*)alloc((size_t)NH1 * 256 * 2);
    short* w_m2 = (short*)alloc((size_t)NH2 * NH1 * 2);
    // xb (layer-0 padded input) with head temps aliased over it (head runs
    // only after xb is dead)
    short* xb = (short*)alloc((size_t)MP * KP0 * 2);   // 64 MB
    float* z1    = (float*)xb;                          // BG*NH1 f32 (8.4MB)
    short* z1b   = (short*)(z1 + (size_t)BG * NH1);     // BG*NH1 bf16
    short* poolb = z1b + (size_t)BG * NH1;              // BG*HID bf16

    auto conv = [&](const float* s, short* d, int rs, int rd, int Ks, int Kd) {
        conv_bf16<<<dim3(512), dim3(256), 0, stream>>>(s, d, rs, rd, Ks, Kd);
    };
    auto convg = [&](const float* s, short* d) {
        conv_gates<<<dim3(512), dim3(256), 0, stream>>>(s, d, 256);
    };
    // mode 0/1 GEMM; nt = col tiles per block
    auto G = [&](const short* A, const short* B, int K, const float* bias,
                 float* Cf, short* Cbb, int M, int N, int mode, int nt) {
        mfma_gemm<<<dim3(M / 128, N / 128 / nt), dim3(256), 0, stream>>>(
            A, B, K, nullptr, nullptr, 0, bias,
            nullptr, nullptr, nullptr, nullptr, nullptr, Cf, Cbb, N, mode, nt);
    };
    // mode 2 LSTM GEMM (nt=8: one block per 128-row panel covers all 1024 cols)
    auto GL = [&](const short* A1, const short* B1, int K1,
                  const short* A2, const short* B2, int K2,
                  const float* bih, const float* bhh,
                  const float* ci, float* co, short* ho) {
        mfma_gemm<<<dim3(MP / 128, 1), dim3(256), 0, stream>>>(
            A1, B1, K1, A2, B2, K2, nullptr,
            bih, bhh, ci, co, ho, nullptr, nullptr, G4H, 2, 8);
    };

    // ---- conversions + CSR build ----
    conv(x, xb, NN, MP, FIN, KP0);
    conv(lin0_w, w_lin0, 256, 256, FIN, KP0);
    convg(r0_wih, w_r0);
    for (int l = 0; l < 3; ++l) {
        int base = 10 + 12 * l;
        int K  = (l == 0) ? FIN : 256;
        int Kp = (l == 0) ? KP0 : 256;
        conv((const float*)d_in[base + 0], w_lr[l], 256, 256, K, Kp);
        conv((const float*)d_in[base + 2], w_lr[l] + (size_t)256 * Kp, 256, 256, K, Kp);
        convg((const float*)d_in[base + 8], w_ih[l]);
        convg((const float*)d_in[base + 9], w_hh[l]);
        concat2_f32<<<dim3(2), dim3(256), 0, stream>>>(
            (const float*)d_in[base + 1], (const float*)d_in[base + 3], blr[l], 256, 256);
    }
    conv(mh1_w, w_m1, NH1, NH1, 256, 256);
    conv(mh2_w, w_m2, NH2, NH2, NH1, NH1);

    zero_f32<<<dim3(256), dim3(256), 0, stream>>>((float*)deg, NN);
    edge_hist<<<dim3((EP + 255) / 256), dim3(256), 0, stream>>>(ei, deg);
    scan_deg<<<dim3(1), dim3(1024), 0, stream>>>(deg, rowptr, cursor);
    edge_fill<<<dim3((EP + 255) / 256), dim3(256), 0, stream>>>(ei, rowptr, cursor, esrc);

    // ---- lin0 -> x0 (bf16); rnn0 LSTM from zero state (fused epilogue) ----
    G(xb, w_lin0, KP0, lin0_b, nullptr, ybb, MP, HID, 1, 2);
    GL(ybb, w_r0, 256, nullptr, nullptr, 0, r0_bih, r0_bhh, nullptr, cb, hA);

    // ---- 3x (GATv2 -> LN+ELU -> LSTM) ----
    short* hprev = hA;
    short* hnext = hB;
    for (int l = 0; l < 3; ++l) {
        int base = 10 + 12 * l;
        const float* att = (const float*)d_in[base + 4];
        const float* gb  = (const float*)d_in[base + 5];
        const float* lg  = (const float*)d_in[base + 6];
        const float* lb  = (const float*)d_in[base + 7];
        const float* bih = (const float*)d_in[base + 10];
        const float* bhh = (const float*)d_in[base + 11];
        const short* Ain = (l == 0) ? xb : hprev;
        int K = (l == 0) ? KP0 : 256;

        G(Ain, w_lr[l], K, blr[l], nullptr, xlr, MP, 512, 1, 4);
        gat_fused<<<dim3((NN + 3) / 4), dim3(256), 0, stream>>>(
            xlr, rowptr, esrc, att, gb, lg, lb, ybb);
        GL(ybb, w_ih[l], 256, hprev, w_hh[l], 256, bih, bhh, cb, cb, hnext);
        short* t = hprev; hprev = hnext; hnext = t;
    }

    // ---- mean pool (sorted batch) + MLP head ----
    pool_mean<<<dim3((BG + 3) / 4), dim3(256), 0, stream>>>(hprev, batch, poolb);
    G(poolb, w_m1, 256, mh1_b, z1, nullptr, BG, NH1, 0, 1);
    ln_act_kernel<<<dim3(BG), dim3(256), 0, stream>>>(z1, ln1_g, ln1_b, nullptr, z1b, NH1, 1);
    G(z1b, w_m2, NH1, mh2_b, out, nullptr, BG, NH2, 0, 1);
    ln_act_kernel<<<dim3(BG), dim3(256), 0, stream>>>(out, ln2_g, ln2_b, out, nullptr, NH2, 0);
}

// Round 9
// 2533.039 us; speedup vs baseline: 1.1238x; 1.1238x over previous
//
#include <hip/hip_runtime.h>
#include <hip/hip_bf16.h>
#include <math.h>

// ---------------------------------------------------------------------------
// GraphEncoder round 9: revert round-8's in-kernel nt loop (regressed:
// 8MB/XCD working set thrashed L2, FETCH unchanged, occupancy down).
// Instead: XCD-aware block swizzle - one tile per block (round-6 structure),
// but bid -> (xcd=bid&7, slot=bid>>3, g=slot/nct, ct=slot%nct,
// row_panel=g*8+xcd). The nct col-tile blocks of a row panel are 8 bids
// apart -> co-resident on ONE XCD -> A-panel L2-shared (1MB/XCD working
// set < 4MB L2). MP padded to 100352 (784 panels, %8==0).
// ---------------------------------------------------------------------------

constexpr int NN    = 100000;
constexpr int EE    = 400000;
constexpr int EP    = EE + NN;      // 500000 (incl self loops)
constexpr int BG    = 4096;
constexpr int FIN   = 300;
constexpr int HEADS = 4;
constexpr int HID   = 256;
constexpr int G4H   = 1024;
constexpr int NH1   = 512;
constexpr int NH2   = 768;
constexpr int MP    = 100352;       // 784*128, 784 % 8 == 0
constexpr int KP0   = 320;          // FIN padded to mult of 32

typedef __attribute__((ext_vector_type(4))) float f32x4;
typedef __attribute__((ext_vector_type(8))) short s16x8;

__device__ inline float sigm(float x) { return 1.f / (1.f + expf(-x)); }
__device__ inline float b2f(short s) { return __uint_as_float(((unsigned)(unsigned short)s) << 16); }
__device__ inline short f2b(float f) {
    unsigned u = __float_as_uint(f);
    u += 0x7fff + ((u >> 16) & 1);          // round-to-nearest-even
    return (short)(u >> 16);
}
__device__ inline float wsum64(float v) {
#pragma unroll
    for (int o = 32; o > 0; o >>= 1) v += __shfl_xor(v, o);
    return v;
}

// ---------------- utility kernels -------------------------------------------
__global__ __launch_bounds__(256) void zero_f32(float* __restrict__ p, long long n)
{
    long long i = (long long)blockIdx.x * 256 + threadIdx.x;
    long long stride = (long long)gridDim.x * 256;
    for (; i < n; i += stride) p[i] = 0.f;
}

// f32 -> bf16 with row/col zero padding
__global__ __launch_bounds__(256) void conv_bf16(
    const float* __restrict__ src, short* __restrict__ dst,
    int rsrc, int rdst, int Ks, int Kd)
{
    long long n = (long long)rdst * Kd;
    long long stride = (long long)gridDim.x * 256;
    for (long long i = (long long)blockIdx.x * 256 + threadIdx.x; i < n; i += stride) {
        int r = (int)(i / Kd);
        int k = (int)(i - (long long)r * Kd);
        float v = (r < rsrc && k < Ks) ? src[(long long)r * Ks + k] : 0.f;
        dst[i] = f2b(v);
    }
}

// gate-interleaved pack of LSTM weight [1024][K]:
// new row p -> orig row gate*256+ch, gate=(p>>4)&3, ch=(p>>7)*32+((p>>6)&1)*16+(p&15)
__global__ __launch_bounds__(256) void conv_gates(
    const float* __restrict__ src, short* __restrict__ dst, int K)
{
    long long n = (long long)G4H * K;
    long long stride = (long long)gridDim.x * 256;
    for (long long i = (long long)blockIdx.x * 256 + threadIdx.x; i < n; i += stride) {
        int p = (int)(i / K);
        int k = (int)(i - (long long)p * K);
        int gate = (p >> 4) & 3;
        int ch   = (p >> 7) * 32 + ((p >> 6) & 1) * 16 + (p & 15);
        dst[i] = f2b(src[(size_t)(gate * 256 + ch) * K + k]);
    }
}

__global__ __launch_bounds__(256) void concat2_f32(
    const float* __restrict__ a, const float* __restrict__ b,
    float* __restrict__ dst, int na, int nb)
{
    int i = blockIdx.x * 256 + threadIdx.x;
    if (i < na) dst[i] = a[i];
    else if (i < na + nb) dst[i] = b[i - na];
}

// ---------------- CSR build -------------------------------------------------
__global__ __launch_bounds__(256) void edge_hist(const int* __restrict__ ei,
                                                 int* __restrict__ deg)
{
    int e = blockIdx.x * 256 + threadIdx.x;
    if (e >= EP) return;
    int d = (e < EE) ? ei[EE + e] : e - EE;
    atomicAdd(&deg[d], 1);
}

__global__ __launch_bounds__(1024) void scan_deg(const int* __restrict__ deg,
                                                 int* __restrict__ rowptr,
                                                 int* __restrict__ cursor)
{
    __shared__ int part[1024];
    int t = threadIdx.x;
    const int CH = (NN + 1023) / 1024;
    int lo = t * CH, hi = min(lo + CH, NN);
    int s = 0;
    for (int i = lo; i < hi; ++i) s += deg[i];
    part[t] = s;
    __syncthreads();
    for (int off = 1; off < 1024; off <<= 1) {
        int v = (t >= off) ? part[t - off] : 0;
        __syncthreads();
        part[t] += v;
        __syncthreads();
    }
    int run = (t == 0) ? 0 : part[t - 1];
    for (int i = lo; i < hi; ++i) { rowptr[i] = run; cursor[i] = 0; run += deg[i]; }
    if (t == 1023) rowptr[NN] = run;   // == EP
}

__global__ __launch_bounds__(256) void edge_fill(const int* __restrict__ ei,
                                                 const int* __restrict__ rowptr,
                                                 int* __restrict__ cursor,
                                                 int* __restrict__ esrc)
{
    int e = blockIdx.x * 256 + threadIdx.x;
    if (e >= EP) return;
    int s, d;
    if (e < EE) { s = ei[e]; d = ei[EE + e]; }
    else        { s = d = e - EE; }
    int slot = rowptr[d] + atomicAdd(&cursor[d], 1);
    esrc[slot] = s;
}

// ---------------- MFMA GEMM with fused epilogues ----------------------------
// C[M x N] = A1[M x K1] @ B1[N x K1]^T (+ A2[M x K2] @ B2[N x K2]^T)
// 1-D grid of (M/128)*(N/128) blocks; XCD swizzle: xcd=bid&7, slot=bid>>3,
// g=slot/nct, ct=slot%nct, row_panel=g*8+xcd. Requires (M/128)%8==0.
// mode 0: +bias -> f32 Cf      mode 1: +bias -> bf16 Cb
// mode 2: LSTM epilogue (gate-interleaved B; N=1024): reads c_in (or 0),
//         writes c_out f32 + h_out bf16, both [M][256].
__global__ __launch_bounds__(256) void mfma_gemm(
    const short* __restrict__ A1, const short* __restrict__ B1, int K1,
    const short* __restrict__ A2, const short* __restrict__ B2, int K2,
    const float* __restrict__ bias,
    const float* __restrict__ bih, const float* __restrict__ bhh,
    const float* __restrict__ c_in, float* __restrict__ c_out,
    short* __restrict__ h_out,
    float* __restrict__ Cf, short* __restrict__ Cb, int N, int mode, int nct)
{
    __shared__ __align__(16) short sA[128 * 32];
    __shared__ __align__(16) short sB[128 * 32];
    const int tid  = threadIdx.x;
    const int w    = tid >> 6, lane = tid & 63;
    const int wr   = w >> 1,  wc   = w & 1;      // 2x2 waves of 64x64
    // XCD-aware decode (consecutive bids round-robin across 8 XCDs)
    const int bid  = blockIdx.x;
    const int xcd  = bid & 7;
    const int slot = bid >> 3;
    const int g    = slot / nct;
    const int tcol = slot - g * nct;
    const int row0 = (g * 8 + xcd) * 128;
    const int col0 = tcol * 128;

    f32x4 acc[4][4];
#pragma unroll
    for (int m = 0; m < 4; ++m)
#pragma unroll
        for (int n = 0; n < 4; ++n) acc[m][n] = (f32x4){0.f, 0.f, 0.f, 0.f};

    const int rs = lane >> 2;
    const int cs = lane & 3;
    const int KK = K1 + K2;

    for (int k0 = 0; k0 < KK; k0 += 32) {
        const short* Ak; const short* Bk; int kk, ld;
        if (k0 < K1) { Ak = A1; Bk = B1; kk = k0;      ld = K1; }
        else         { Ak = A2; Bk = B2; kk = k0 - K1; ld = K2; }
#pragma unroll
        for (int i = 0; i < 2; ++i) {
            int seg = w * 2 + i;
            int row = seg * 16 + rs;
            int c8  = cs ^ ((row + (row >> 2)) & 3);
            const short* ga = Ak + (size_t)(row0 + row) * ld + kk + c8 * 8;
            const short* gb = Bk + (size_t)(col0 + row) * ld + kk + c8 * 8;
            short* la = sA + seg * 512 + lane * 8;
            short* lb = sB + seg * 512 + lane * 8;
            __builtin_amdgcn_global_load_lds((const __attribute__((address_space(1))) void*)ga,
                                             (__attribute__((address_space(3))) void*)la, 16, 0, 0);
            __builtin_amdgcn_global_load_lds((const __attribute__((address_space(1))) void*)gb,
                                             (__attribute__((address_space(3))) void*)lb, 16, 0, 0);
        }
        __syncthreads();

        s16x8 af[4], bg[4];
        {
            const int rl = lane & 15;
            const int cw = lane >> 4;
#pragma unroll
            for (int m = 0; m < 4; ++m) {
                int r  = wr * 64 + m * 16 + rl;
                int sl = cw ^ ((r + (r >> 2)) & 3);
                af[m] = *(const s16x8*)(sA + r * 32 + sl * 8);
                int c  = wc * 64 + m * 16 + rl;
                int sc = cw ^ ((c + (c >> 2)) & 3);
                bg[m] = *(const s16x8*)(sB + c * 32 + sc * 8);
            }
        }
#pragma unroll
        for (int m = 0; m < 4; ++m)
#pragma unroll
            for (int n = 0; n < 4; ++n)
                acc[m][n] = __builtin_amdgcn_mfma_f32_16x16x32_bf16(af[m], bg[n], acc[m][n], 0, 0, 0);
        __syncthreads();
    }

    // C/D layout: col=lane&15, row=(lane>>4)*4+reg
    const int l16   = lane & 15;
    const int rbase = row0 + wr * 64 + (lane >> 4) * 4;
    if (mode == 2) {
        const int ch = tcol * 32 + wc * 16 + l16;
        float bi[4];
#pragma unroll
        for (int gg2 = 0; gg2 < 4; ++gg2) bi[gg2] = bih[gg2 * 256 + ch] + bhh[gg2 * 256 + ch];
#pragma unroll
        for (int m = 0; m < 4; ++m) {
#pragma unroll
            for (int r = 0; r < 4; ++r) {
                int row = rbase + m * 16 + r;
                float gi = acc[m][0][r] + bi[0];
                float gf = acc[m][1][r] + bi[1];
                float gg = acc[m][2][r] + bi[2];
                float go = acc[m][3][r] + bi[3];
                size_t idx = (size_t)row * HID + ch;
                float co = c_in ? c_in[idx] : 0.f;
                float c2 = sigm(gf) * co + sigm(gi) * tanhf(gg);
                float h2 = sigm(go) * tanhf(c2);
                c_out[idx] = c2;
                h_out[idx] = f2b(h2);
            }
        }
    } else {
        const int cbase = col0 + wc * 64 + l16;
#pragma unroll
        for (int n = 0; n < 4; ++n) {
            int col = cbase + n * 16;
            float ba = bias ? bias[col] : 0.f;
#pragma unroll
            for (int m = 0; m < 4; ++m) {
#pragma unroll
                for (int r = 0; r < 4; ++r) {
                    int row = rbase + m * 16 + r;
                    float v = acc[m][n][r] + ba;
                    size_t idx = (size_t)row * N + col;
                    if (mode == 1) Cb[idx] = f2b(v);
                    else           Cf[idx] = v;
                }
            }
        }
    }
}

// ---------------- fused GATv2 (softmax + aggregate + bias + LN + ELU) -------
// one 64-lane wave per dst node; lane l = channel h*64+l per head h.
// xlr: [MP][512] bf16, cols 0..255 = lin_l(x), 256..511 = lin_r(x).
__global__ __launch_bounds__(256) void gat_fused(
    const short* __restrict__ xlr, const int* __restrict__ rowptr,
    const int* __restrict__ esrc, const float* __restrict__ att,
    const float* __restrict__ gb, const float* __restrict__ lg,
    const float* __restrict__ lb, short* __restrict__ outb)
{
    int i    = blockIdx.x * 4 + (threadIdx.x >> 6);
    int lane = threadIdx.x & 63;
    if (i >= NN) return;
    float xr[HEADS], at[HEADS];
#pragma unroll
    for (int h = 0; h < HEADS; ++h) {
        xr[h] = b2f(xlr[(size_t)i * 512 + 256 + h * 64 + lane]);
        at[h] = att[h * 64 + lane];
    }
    float mx[HEADS], sm[HEADS], ac[HEADS];
#pragma unroll
    for (int h = 0; h < HEADS; ++h) { mx[h] = -INFINITY; sm[h] = 0.f; ac[h] = 0.f; }

    int lo = rowptr[i], hi = rowptr[i + 1];
    for (int e = lo; e < hi; ++e) {
        int s = esrc[e];
        float xs[HEADS], p[HEADS];
#pragma unroll
        for (int h = 0; h < HEADS; ++h) {
            xs[h] = b2f(xlr[(size_t)s * 512 + h * 64 + lane]);
            float v = xs[h] + xr[h];
            v = (v >= 0.f) ? v : 0.2f * v;
            p[h] = v * at[h];
        }
#pragma unroll
        for (int h = 0; h < HEADS; ++h) p[h] = wsum64(p[h]);
#pragma unroll
        for (int h = 0; h < HEADS; ++h) {
            float mn = fmaxf(mx[h], p[h]);
            float sc = expf(mx[h] - mn);     // first iter: exp(-inf)=0
            float a  = expf(p[h] - mn);
            sm[h] = sm[h] * sc + a;
            ac[h] = ac[h] * sc + a * xs[h];
            mx[h] = mn;
        }
    }
    // y = ac/sm (+ gat bias), then LayerNorm(256) + ELU, write bf16
    float val[HEADS], s1 = 0.f, s2 = 0.f;
#pragma unroll
    for (int h = 0; h < HEADS; ++h) {
        float v = ac[h] / sm[h] + gb[h * 64 + lane];
        val[h] = v; s1 += v; s2 += v * v;
    }
    s1 = wsum64(s1); s2 = wsum64(s2);
    float mean = s1 * (1.f / 256.f);
    float var  = s2 * (1.f / 256.f) - mean * mean;
    float inv  = rsqrtf(var + 1e-5f);
#pragma unroll
    for (int h = 0; h < HEADS; ++h) {
        float v = (val[h] - mean) * inv * lg[h * 64 + lane] + lb[h * 64 + lane];
        v = (v > 0.f) ? v : expm1f(v);
        outb[(size_t)i * HID + h * 64 + lane] = f2b(v);
    }
}

// ---------------- LayerNorm (+act) for the MLP head -------------------------
__global__ __launch_bounds__(256) void ln_act_kernel(
    const float* __restrict__ in, const float* __restrict__ gamma,
    const float* __restrict__ beta, float* __restrict__ outf,
    short* __restrict__ outb, int width, int act)
{
    int row = blockIdx.x;
    const float* ip = in + (size_t)row * width;
    float vals[3];
    float s = 0.f, ss = 0.f;
    int nw = width >> 8;
    for (int i = 0; i < nw; ++i) {
        int c = threadIdx.x + (i << 8);
        float v = ip[c];
        vals[i] = v; s += v; ss += v * v;
    }
#pragma unroll
    for (int off = 32; off > 0; off >>= 1) {
        s  += __shfl_down(s, off);
        ss += __shfl_down(ss, off);
    }
    __shared__ float sh[8];
    int wv = threadIdx.x >> 6, lane = threadIdx.x & 63;
    if (lane == 0) { sh[wv] = s; sh[4 + wv] = ss; }
    __syncthreads();
    if (threadIdx.x == 0) {
        sh[0] = sh[0] + sh[1] + sh[2] + sh[3];
        sh[4] = sh[4] + sh[5] + sh[6] + sh[7];
    }
    __syncthreads();
    float mean = sh[0] / width;
    float var  = sh[4] / width - mean * mean;
    float inv  = rsqrtf(var + 1e-5f);
    for (int i = 0; i < nw; ++i) {
        int c = threadIdx.x + (i << 8);
        float v = (vals[i] - mean) * inv * gamma[c] + beta[c];
        if (act == 1) v = fmaxf(v, 0.f);
        if (outb) outb[(size_t)row * width + c] = f2b(v);
        else      outf[(size_t)row * width + c] = v;
    }
}

// ---------------- sorted-batch mean pool ------------------------------------
__global__ __launch_bounds__(256) void pool_mean(
    const short* __restrict__ h, const int* __restrict__ batch,
    short* __restrict__ poolb)
{
    int b    = blockIdx.x * 4 + (threadIdx.x >> 6);
    int lane = threadIdx.x & 63;
    if (b >= BG) return;
    auto lbound = [&](int key) {
        int lo = 0, hi = NN;
        while (lo < hi) { int mid = (lo + hi) >> 1; if (batch[mid] < key) lo = mid + 1; else hi = mid; }
        return lo;
    };
    int lo = lbound(b), hi = lbound(b + 1);
    float acc[HEADS] = {0.f, 0.f, 0.f, 0.f};
    for (int r = lo; r < hi; ++r)
#pragma unroll
        for (int hh = 0; hh < HEADS; ++hh)
            acc[hh] += b2f(h[(size_t)r * HID + hh * 64 + lane]);
    float inv = 1.f / fmaxf((float)(hi - lo), 1.f);
#pragma unroll
    for (int hh = 0; hh < HEADS; ++hh)
        poolb[(size_t)b * HID + hh * 64 + lane] = f2b(acc[hh] * inv);
}

// ---------------------------------------------------------------------------
extern "C" void kernel_launch(void* const* d_in, const int* in_sizes, int n_in,
                              void* d_out, int out_size, void* d_ws, size_t ws_size,
                              hipStream_t stream)
{
    (void)in_sizes; (void)n_in; (void)out_size; (void)ws_size;
    const float* x      = (const float*)d_in[0];
    const int*   ei     = (const int*)d_in[1];
    const int*   batch  = (const int*)d_in[2];
    const float* lin0_w = (const float*)d_in[4];
    const float* lin0_b = (const float*)d_in[5];
    const float* r0_wih = (const float*)d_in[6];
    const float* r0_bih = (const float*)d_in[8];
    const float* r0_bhh = (const float*)d_in[9];
    const float* mh1_w  = (const float*)d_in[46];
    const float* mh1_b  = (const float*)d_in[47];
    const float* ln1_g  = (const float*)d_in[48];
    const float* ln1_b  = (const float*)d_in[49];
    const float* mh2_w  = (const float*)d_in[50];
    const float* mh2_b  = (const float*)d_in[51];
    const float* ln2_g  = (const float*)d_in[52];
    const float* ln2_b  = (const float*)d_in[53];
    float* out = (float*)d_out;

    // ---- workspace bump allocation ----
    char* wsb = (char*)d_ws;
    auto alloc = [&](size_t bytes) -> void* {
        void* p = (void*)wsb;
        wsb += (bytes + 255) & ~(size_t)255;
        return p;
    };
    const size_t NH = (size_t)MP * HID;
    float* cb   = (float*)alloc(NH * 4);          // LSTM cell state f32
    short* hA   = (short*)alloc(NH * 2);          // h ping
    short* hB   = (short*)alloc(NH * 2);          // h pong
    short* ybb  = (short*)alloc(NH * 2);          // LSTM-input / x0 bf16
    short* xlr  = (short*)alloc((size_t)MP * 512 * 2);  // [xl|xr] bf16
    int*   deg    = (int*)alloc((size_t)NN * 4);
    int*   rowptr = (int*)alloc((size_t)(NN + 1) * 4);
    int*   cursor = (int*)alloc((size_t)NN * 4);
    int*   esrc   = (int*)alloc((size_t)EP * 4);
    // weights bf16
    short* w_lin0 = (short*)alloc((size_t)256 * KP0 * 2);
    short* w_r0   = (short*)alloc((size_t)G4H * 256 * 2);
    short* w_lr[3]; short* w_ih[3]; short* w_hh[3]; float* blr[3];
    for (int l = 0; l < 3; ++l) {
        int Kp = (l == 0) ? KP0 : 256;
        w_lr[l] = (short*)alloc((size_t)512 * Kp * 2);
        w_ih[l] = (short*)alloc((size_t)G4H * 256 * 2);
        w_hh[l] = (short*)alloc((size_t)G4H * 256 * 2);
        blr[l]  = (float*)alloc(512 * 4);
    }
    short* w_m1 = (short*)alloc((size_t)NH1 * 256 * 2);
    short* w_m2 = (short*)alloc((size_t)NH2 * NH1 * 2);
    // xb (layer-0 padded input) with head temps aliased over it (head runs
    // only after xb is dead)
    short* xb = (short*)alloc((size_t)MP * KP0 * 2);   // 64 MB
    float* z1    = (float*)xb;                          // BG*NH1 f32 (8.4MB)
    short* z1b   = (short*)(z1 + (size_t)BG * NH1);     // BG*NH1 bf16
    short* poolb = z1b + (size_t)BG * NH1;              // BG*HID bf16

    auto conv = [&](const float* s, short* d, int rs, int rd, int Ks, int Kd) {
        conv_bf16<<<dim3(512), dim3(256), 0, stream>>>(s, d, rs, rd, Ks, Kd);
    };
    auto convg = [&](const float* s, short* d) {
        conv_gates<<<dim3(512), dim3(256), 0, stream>>>(s, d, 256);
    };
    // mode 0/1 GEMM; 1-D grid with XCD swizzle (requires (M/128)%8==0)
    auto G = [&](const short* A, const short* B, int K, const float* bias,
                 float* Cf, short* Cbb, int M, int N, int mode) {
        int nrp = M / 128, nct = N / 128;
        mfma_gemm<<<dim3(nrp * nct), dim3(256), 0, stream>>>(
            A, B, K, nullptr, nullptr, 0, bias,
            nullptr, nullptr, nullptr, nullptr, nullptr, Cf, Cbb, N, mode, nct);
    };
    // mode 2 LSTM GEMM
    auto GL = [&](const short* A1, const short* B1, int K1,
                  const short* A2, const short* B2, int K2,
                  const float* bih, const float* bhh,
                  const float* ci, float* co, short* ho) {
        mfma_gemm<<<dim3((MP / 128) * 8), dim3(256), 0, stream>>>(
            A1, B1, K1, A2, B2, K2, nullptr,
            bih, bhh, ci, co, ho, nullptr, nullptr, G4H, 2, 8);
    };

    // ---- conversions + CSR build ----
    conv(x, xb, NN, MP, FIN, KP0);
    conv(lin0_w, w_lin0, 256, 256, FIN, KP0);
    convg(r0_wih, w_r0);
    for (int l = 0; l < 3; ++l) {
        int base = 10 + 12 * l;
        int K  = (l == 0) ? FIN : 256;
        int Kp = (l == 0) ? KP0 : 256;
        conv((const float*)d_in[base + 0], w_lr[l], 256, 256, K, Kp);
        conv((const float*)d_in[base + 2], w_lr[l] + (size_t)256 * Kp, 256, 256, K, Kp);
        convg((const float*)d_in[base + 8], w_ih[l]);
        convg((const float*)d_in[base + 9], w_hh[l]);
        concat2_f32<<<dim3(2), dim3(256), 0, stream>>>(
            (const float*)d_in[base + 1], (const float*)d_in[base + 3], blr[l], 256, 256);
    }
    conv(mh1_w, w_m1, NH1, NH1, 256, 256);
    conv(mh2_w, w_m2, NH2, NH2, NH1, NH1);

    zero_f32<<<dim3(256), dim3(256), 0, stream>>>((float*)deg, NN);
    edge_hist<<<dim3((EP + 255) / 256), dim3(256), 0, stream>>>(ei, deg);
    scan_deg<<<dim3(1), dim3(1024), 0, stream>>>(deg, rowptr, cursor);
    edge_fill<<<dim3((EP + 255) / 256), dim3(256), 0, stream>>>(ei, rowptr, cursor, esrc);

    // ---- lin0 -> x0 (bf16); rnn0 LSTM from zero state (fused epilogue) ----
    G(xb, w_lin0, KP0, lin0_b, nullptr, ybb, MP, HID, 1);
    GL(ybb, w_r0, 256, nullptr, nullptr, 0, r0_bih, r0_bhh, nullptr, cb, hA);

    // ---- 3x (GATv2 -> LN+ELU -> LSTM) ----
    short* hprev = hA;
    short* hnext = hB;
    for (int l = 0; l < 3; ++l) {
        int base = 10 + 12 * l;
        const float* att = (const float*)d_in[base + 4];
        const float* gb  = (const float*)d_in[base + 5];
        const float* lg  = (const float*)d_in[base + 6];
        const float* lb  = (const float*)d_in[base + 7];
        const float* bih = (const float*)d_in[base + 10];
        const float* bhh = (const float*)d_in[base + 11];
        const short* Ain = (l == 0) ? xb : hprev;
        int K = (l == 0) ? KP0 : 256;

        G(Ain, w_lr[l], K, blr[l], nullptr, xlr, MP, 512, 1);
        gat_fused<<<dim3((NN + 3) / 4), dim3(256), 0, stream>>>(
            xlr, rowptr, esrc, att, gb, lg, lb, ybb);
        GL(ybb, w_ih[l], 256, hprev, w_hh[l], 256, bih, bhh, cb, cb, hnext);
        short* t = hprev; hprev = hnext; hnext = t;
    }

    // ---- mean pool (sorted batch) + MLP head ----
    pool_mean<<<dim3((BG + 3) / 4), dim3(256), 0, stream>>>(hprev, batch, poolb);
    G(poolb, w_m1, 256, mh1_b, z1, nullptr, BG, NH1, 0);
    ln_act_kernel<<<dim3(BG), dim3(256), 0, stream>>>(z1, ln1_g, ln1_b, nullptr, z1b, NH1, 1);
    G(z1b, w_m2, NH1, mh2_b, out, nullptr, BG, NH2, 0);
    ln_act_kernel<<<dim3(BG), dim3(256), 0, stream>>>(out, ln2_g, ln2_b, out, nullptr, NH2, 0);
}

// Round 10
// 2255.068 us; speedup vs baseline: 1.2623x; 1.1233x over previous
//
#include <hip/hip_runtime.h>
#include <hip/hip_bf16.h>
#include <math.h>

// ---------------------------------------------------------------------------
// GraphEncoder round 10: round-9 structure (XCD-swizzled one-tile-per-block
// MFMA GEMM, fused GAT, fused-LSTM epilogue) + fast HW transcendentals.
// Round-9 PMC: LSTM GEMM FETCH 457->110MB (swizzle worked) but dur flat at
// 332us with VALUBusy 42% / MfmaUtil 13% / HBM 10% -> VALU-bound, and the
// dominant VALU is the epilogue's 80 libm expf/tanhf calls per thread
// (~1600 instrs). Replace with v_exp_f32/v_rcp_f32 sequences (~4 instrs per
// activation); same for gat_fused softmax exp and ELU expm1.
// ---------------------------------------------------------------------------

constexpr int NN    = 100000;
constexpr int EE    = 400000;
constexpr int EP    = EE + NN;      // 500000 (incl self loops)
constexpr int BG    = 4096;
constexpr int FIN   = 300;
constexpr int HEADS = 4;
constexpr int HID   = 256;
constexpr int G4H   = 1024;
constexpr int NH1   = 512;
constexpr int NH2   = 768;
constexpr int MP    = 100352;       // 784*128, 784 % 8 == 0
constexpr int KP0   = 320;          // FIN padded to mult of 32

typedef __attribute__((ext_vector_type(4))) float f32x4;
typedef __attribute__((ext_vector_type(8))) short s16x8;

#define LOG2E 1.4426950408889634f

// fast HW transcendentals (v_exp_f32 = 2^x, v_rcp_f32)
__device__ inline float fexp(float x)  { return __builtin_amdgcn_exp2f(x * LOG2E); }
__device__ inline float frcp(float x)  { return __builtin_amdgcn_rcpf(x); }
// sigm(x) = 1/(1+e^-x); x->-inf: exp2(+inf)=inf -> rcp=0 (correct)
__device__ inline float fsigm(float x) { return frcp(1.f + __builtin_amdgcn_exp2f(-LOG2E * x)); }
// tanh(x) = 1 - 2/(e^{2x}+1); x->+inf: exp2=inf -> 1; x->-inf: exp2=0 -> -1
__device__ inline float ftanh(float x) { return 1.f - 2.f * frcp(1.f + __builtin_amdgcn_exp2f(2.f * LOG2E * x)); }

__device__ inline float b2f(short s) { return __uint_as_float(((unsigned)(unsigned short)s) << 16); }
__device__ inline short f2b(float f) {
    unsigned u = __float_as_uint(f);
    u += 0x7fff + ((u >> 16) & 1);          // round-to-nearest-even
    return (short)(u >> 16);
}
__device__ inline float wsum64(float v) {
#pragma unroll
    for (int o = 32; o > 0; o >>= 1) v += __shfl_xor(v, o);
    return v;
}

// ---------------- utility kernels -------------------------------------------
__global__ __launch_bounds__(256) void zero_f32(float* __restrict__ p, long long n)
{
    long long i = (long long)blockIdx.x * 256 + threadIdx.x;
    long long stride = (long long)gridDim.x * 256;
    for (; i < n; i += stride) p[i] = 0.f;
}

// f32 -> bf16 with row/col zero padding
__global__ __launch_bounds__(256) void conv_bf16(
    const float* __restrict__ src, short* __restrict__ dst,
    int rsrc, int rdst, int Ks, int Kd)
{
    long long n = (long long)rdst * Kd;
    long long stride = (long long)gridDim.x * 256;
    for (long long i = (long long)blockIdx.x * 256 + threadIdx.x; i < n; i += stride) {
        int r = (int)(i / Kd);
        int k = (int)(i - (long long)r * Kd);
        float v = (r < rsrc && k < Ks) ? src[(long long)r * Ks + k] : 0.f;
        dst[i] = f2b(v);
    }
}

// gate-interleaved pack of LSTM weight [1024][K]:
// new row p -> orig row gate*256+ch, gate=(p>>4)&3, ch=(p>>7)*32+((p>>6)&1)*16+(p&15)
__global__ __launch_bounds__(256) void conv_gates(
    const float* __restrict__ src, short* __restrict__ dst, int K)
{
    long long n = (long long)G4H * K;
    long long stride = (long long)gridDim.x * 256;
    for (long long i = (long long)blockIdx.x * 256 + threadIdx.x; i < n; i += stride) {
        int p = (int)(i / K);
        int k = (int)(i - (long long)p * K);
        int gate = (p >> 4) & 3;
        int ch   = (p >> 7) * 32 + ((p >> 6) & 1) * 16 + (p & 15);
        dst[i] = f2b(src[(size_t)(gate * 256 + ch) * K + k]);
    }
}

__global__ __launch_bounds__(256) void concat2_f32(
    const float* __restrict__ a, const float* __restrict__ b,
    float* __restrict__ dst, int na, int nb)
{
    int i = blockIdx.x * 256 + threadIdx.x;
    if (i < na) dst[i] = a[i];
    else if (i < na + nb) dst[i] = b[i - na];
}

// ---------------- CSR build -------------------------------------------------
__global__ __launch_bounds__(256) void edge_hist(const int* __restrict__ ei,
                                                 int* __restrict__ deg)
{
    int e = blockIdx.x * 256 + threadIdx.x;
    if (e >= EP) return;
    int d = (e < EE) ? ei[EE + e] : e - EE;
    atomicAdd(&deg[d], 1);
}

__global__ __launch_bounds__(1024) void scan_deg(const int* __restrict__ deg,
                                                 int* __restrict__ rowptr,
                                                 int* __restrict__ cursor)
{
    __shared__ int part[1024];
    int t = threadIdx.x;
    const int CH = (NN + 1023) / 1024;
    int lo = t * CH, hi = min(lo + CH, NN);
    int s = 0;
    for (int i = lo; i < hi; ++i) s += deg[i];
    part[t] = s;
    __syncthreads();
    for (int off = 1; off < 1024; off <<= 1) {
        int v = (t >= off) ? part[t - off] : 0;
        __syncthreads();
        part[t] += v;
        __syncthreads();
    }
    int run = (t == 0) ? 0 : part[t - 1];
    for (int i = lo; i < hi; ++i) { rowptr[i] = run; cursor[i] = 0; run += deg[i]; }
    if (t == 1023) rowptr[NN] = run;   // == EP
}

__global__ __launch_bounds__(256) void edge_fill(const int* __restrict__ ei,
                                                 const int* __restrict__ rowptr,
                                                 int* __restrict__ cursor,
                                                 int* __restrict__ esrc)
{
    int e = blockIdx.x * 256 + threadIdx.x;
    if (e >= EP) return;
    int s, d;
    if (e < EE) { s = ei[e]; d = ei[EE + e]; }
    else        { s = d = e - EE; }
    int slot = rowptr[d] + atomicAdd(&cursor[d], 1);
    esrc[slot] = s;
}

// ---------------- MFMA GEMM with fused epilogues ----------------------------
// C[M x N] = A1[M x K1] @ B1[N x K1]^T (+ A2[M x K2] @ B2[N x K2]^T)
// 1-D grid of (M/128)*(N/128) blocks; XCD swizzle: xcd=bid&7, slot=bid>>3,
// g=slot/nct, ct=slot%nct, row_panel=g*8+xcd. Requires (M/128)%8==0.
// mode 0: +bias -> f32 Cf      mode 1: +bias -> bf16 Cb
// mode 2: LSTM epilogue (gate-interleaved B; N=1024): reads c_in (or 0),
//         writes c_out f32 + h_out bf16, both [M][256].
__global__ __launch_bounds__(256) void mfma_gemm(
    const short* __restrict__ A1, const short* __restrict__ B1, int K1,
    const short* __restrict__ A2, const short* __restrict__ B2, int K2,
    const float* __restrict__ bias,
    const float* __restrict__ bih, const float* __restrict__ bhh,
    const float* __restrict__ c_in, float* __restrict__ c_out,
    short* __restrict__ h_out,
    float* __restrict__ Cf, short* __restrict__ Cb, int N, int mode, int nct)
{
    __shared__ __align__(16) short sA[128 * 32];
    __shared__ __align__(16) short sB[128 * 32];
    const int tid  = threadIdx.x;
    const int w    = tid >> 6, lane = tid & 63;
    const int wr   = w >> 1,  wc   = w & 1;      // 2x2 waves of 64x64
    // XCD-aware decode (consecutive bids round-robin across 8 XCDs)
    const int bid  = blockIdx.x;
    const int xcd  = bid & 7;
    const int slot = bid >> 3;
    const int g    = slot / nct;
    const int tcol = slot - g * nct;
    const int row0 = (g * 8 + xcd) * 128;
    const int col0 = tcol * 128;

    f32x4 acc[4][4];
#pragma unroll
    for (int m = 0; m < 4; ++m)
#pragma unroll
        for (int n = 0; n < 4; ++n) acc[m][n] = (f32x4){0.f, 0.f, 0.f, 0.f};

    const int rs = lane >> 2;
    const int cs = lane & 3;
    const int KK = K1 + K2;

    for (int k0 = 0; k0 < KK; k0 += 32) {
        const short* Ak; const short* Bk; int kk, ld;
        if (k0 < K1) { Ak = A1; Bk = B1; kk = k0;      ld = K1; }
        else         { Ak = A2; Bk = B2; kk = k0 - K1; ld = K2; }
#pragma unroll
        for (int i = 0; i < 2; ++i) {
            int seg = w * 2 + i;
            int row = seg * 16 + rs;
            int c8  = cs ^ ((row + (row >> 2)) & 3);
            const short* ga = Ak + (size_t)(row0 + row) * ld + kk + c8 * 8;
            const short* gb = Bk + (size_t)(col0 + row) * ld + kk + c8 * 8;
            short* la = sA + seg * 512 + lane * 8;
            short* lb = sB + seg * 512 + lane * 8;
            __builtin_amdgcn_global_load_lds((const __attribute__((address_space(1))) void*)ga,
                                             (__attribute__((address_space(3))) void*)la, 16, 0, 0);
            __builtin_amdgcn_global_load_lds((const __attribute__((address_space(1))) void*)gb,
                                             (__attribute__((address_space(3))) void*)lb, 16, 0, 0);
        }
        __syncthreads();

        s16x8 af[4], bg[4];
        {
            const int rl = lane & 15;
            const int cw = lane >> 4;
#pragma unroll
            for (int m = 0; m < 4; ++m) {
                int r  = wr * 64 + m * 16 + rl;
                int sl = cw ^ ((r + (r >> 2)) & 3);
                af[m] = *(const s16x8*)(sA + r * 32 + sl * 8);
                int c  = wc * 64 + m * 16 + rl;
                int sc = cw ^ ((c + (c >> 2)) & 3);
                bg[m] = *(const s16x8*)(sB + c * 32 + sc * 8);
            }
        }
#pragma unroll
        for (int m = 0; m < 4; ++m)
#pragma unroll
            for (int n = 0; n < 4; ++n)
                acc[m][n] = __builtin_amdgcn_mfma_f32_16x16x32_bf16(af[m], bg[n], acc[m][n], 0, 0, 0);
        __syncthreads();
    }

    // C/D layout: col=lane&15, row=(lane>>4)*4+reg
    const int l16   = lane & 15;
    const int rbase = row0 + wr * 64 + (lane >> 4) * 4;
    if (mode == 2) {
        const int ch = tcol * 32 + wc * 16 + l16;
        float bi[4];
#pragma unroll
        for (int gg2 = 0; gg2 < 4; ++gg2) bi[gg2] = bih[gg2 * 256 + ch] + bhh[gg2 * 256 + ch];
#pragma unroll
        for (int m = 0; m < 4; ++m) {
#pragma unroll
            for (int r = 0; r < 4; ++r) {
                int row = rbase + m * 16 + r;
                float gi = acc[m][0][r] + bi[0];
                float gf = acc[m][1][r] + bi[1];
                float gg = acc[m][2][r] + bi[2];
                float go = acc[m][3][r] + bi[3];
                size_t idx = (size_t)row * HID + ch;
                float co = c_in ? c_in[idx] : 0.f;
                float c2 = fsigm(gf) * co + fsigm(gi) * ftanh(gg);
                float h2 = fsigm(go) * ftanh(c2);
                c_out[idx] = c2;
                h_out[idx] = f2b(h2);
            }
        }
    } else {
        const int cbase = col0 + wc * 64 + l16;
#pragma unroll
        for (int n = 0; n < 4; ++n) {
            int col = cbase + n * 16;
            float ba = bias ? bias[col] : 0.f;
#pragma unroll
            for (int m = 0; m < 4; ++m) {
#pragma unroll
                for (int r = 0; r < 4; ++r) {
                    int row = rbase + m * 16 + r;
                    float v = acc[m][n][r] + ba;
                    size_t idx = (size_t)row * N + col;
                    if (mode == 1) Cb[idx] = f2b(v);
                    else           Cf[idx] = v;
                }
            }
        }
    }
}

// ---------------- fused GATv2 (softmax + aggregate + bias + LN + ELU) -------
// one 64-lane wave per dst node; lane l = channel h*64+l per head h.
// xlr: [MP][512] bf16, cols 0..255 = lin_l(x), 256..511 = lin_r(x).
__global__ __launch_bounds__(256) void gat_fused(
    const short* __restrict__ xlr, const int* __restrict__ rowptr,
    const int* __restrict__ esrc, const float* __restrict__ att,
    const float* __restrict__ gb, const float* __restrict__ lg,
    const float* __restrict__ lb, short* __restrict__ outb)
{
    int i    = blockIdx.x * 4 + (threadIdx.x >> 6);
    int lane = threadIdx.x & 63;
    if (i >= NN) return;
    float xr[HEADS], at[HEADS];
#pragma unroll
    for (int h = 0; h < HEADS; ++h) {
        xr[h] = b2f(xlr[(size_t)i * 512 + 256 + h * 64 + lane]);
        at[h] = att[h * 64 + lane];
    }
    float mx[HEADS], sm[HEADS], ac[HEADS];
#pragma unroll
    for (int h = 0; h < HEADS; ++h) { mx[h] = -INFINITY; sm[h] = 0.f; ac[h] = 0.f; }

    int lo = rowptr[i], hi = rowptr[i + 1];
    for (int e = lo; e < hi; ++e) {
        int s = esrc[e];
        float xs[HEADS], p[HEADS];
#pragma unroll
        for (int h = 0; h < HEADS; ++h) {
            xs[h] = b2f(xlr[(size_t)s * 512 + h * 64 + lane]);
            float v = xs[h] + xr[h];
            v = (v >= 0.f) ? v : 0.2f * v;
            p[h] = v * at[h];
        }
#pragma unroll
        for (int h = 0; h < HEADS; ++h) p[h] = wsum64(p[h]);
#pragma unroll
        for (int h = 0; h < HEADS; ++h) {
            float mn = fmaxf(mx[h], p[h]);
            float sc = fexp(mx[h] - mn);     // first iter: exp(-inf)=0
            float a  = fexp(p[h] - mn);
            sm[h] = sm[h] * sc + a;
            ac[h] = ac[h] * sc + a * xs[h];
            mx[h] = mn;
        }
    }
    // y = ac/sm (+ gat bias), then LayerNorm(256) + ELU, write bf16
    float val[HEADS], s1 = 0.f, s2 = 0.f;
#pragma unroll
    for (int h = 0; h < HEADS; ++h) {
        float v = ac[h] * frcp(sm[h]) + gb[h * 64 + lane];
        val[h] = v; s1 += v; s2 += v * v;
    }
    s1 = wsum64(s1); s2 = wsum64(s2);
    float mean = s1 * (1.f / 256.f);
    float var  = s2 * (1.f / 256.f) - mean * mean;
    float inv  = rsqrtf(var + 1e-5f);
#pragma unroll
    for (int h = 0; h < HEADS; ++h) {
        float v = (val[h] - mean) * inv * lg[h * 64 + lane] + lb[h * 64 + lane];
        v = (v > 0.f) ? v : (fexp(v) - 1.f);
        outb[(size_t)i * HID + h * 64 + lane] = f2b(v);
    }
}

// ---------------- LayerNorm (+act) for the MLP head -------------------------
__global__ __launch_bounds__(256) void ln_act_kernel(
    const float* __restrict__ in, const float* __restrict__ gamma,
    const float* __restrict__ beta, float* __restrict__ outf,
    short* __restrict__ outb, int width, int act)
{
    int row = blockIdx.x;
    const float* ip = in + (size_t)row * width;
    float vals[3];
    float s = 0.f, ss = 0.f;
    int nw = width >> 8;
    for (int i = 0; i < nw; ++i) {
        int c = threadIdx.x + (i << 8);
        float v = ip[c];
        vals[i] = v; s += v; ss += v * v;
    }
#pragma unroll
    for (int off = 32; off > 0; off >>= 1) {
        s  += __shfl_down(s, off);
        ss += __shfl_down(ss, off);
    }
    __shared__ float sh[8];
    int wv = threadIdx.x >> 6, lane = threadIdx.x & 63;
    if (lane == 0) { sh[wv] = s; sh[4 + wv] = ss; }
    __syncthreads();
    if (threadIdx.x == 0) {
        sh[0] = sh[0] + sh[1] + sh[2] + sh[3];
        sh[4] = sh[4] + sh[5] + sh[6] + sh[7];
    }
    __syncthreads();
    float mean = sh[0] / width;
    float var  = sh[4] / width - mean * mean;
    float inv  = rsqrtf(var + 1e-5f);
    for (int i = 0; i < nw; ++i) {
        int c = threadIdx.x + (i << 8);
        float v = (vals[i] - mean) * inv * gamma[c] + beta[c];
        if (act == 1) v = fmaxf(v, 0.f);
        if (outb) outb[(size_t)row * width + c] = f2b(v);
        else      outf[(size_t)row * width + c] = v;
    }
}

// ---------------- sorted-batch mean pool ------------------------------------
__global__ __launch_bounds__(256) void pool_mean(
    const short* __restrict__ h, const int* __restrict__ batch,
    short* __restrict__ poolb)
{
    int b    = blockIdx.x * 4 + (threadIdx.x >> 6);
    int lane = threadIdx.x & 63;
    if (b >= BG) return;
    auto lbound = [&](int key) {
        int lo = 0, hi = NN;
        while (lo < hi) { int mid = (lo + hi) >> 1; if (batch[mid] < key) lo = mid + 1; else hi = mid; }
        return lo;
    };
    int lo = lbound(b), hi = lbound(b + 1);
    float acc[HEADS] = {0.f, 0.f, 0.f, 0.f};
    for (int r = lo; r < hi; ++r)
#pragma unroll
        for (int hh = 0; hh < HEADS; ++hh)
            acc[hh] += b2f(h[(size_t)r * HID + hh * 64 + lane]);
    float inv = 1.f / fmaxf((float)(hi - lo), 1.f);
#pragma unroll
    for (int hh = 0; hh < HEADS; ++hh)
        poolb[(size_t)b * HID + hh * 64 + lane] = f2b(acc[hh] * inv);
}

// ---------------------------------------------------------------------------
extern "C" void kernel_launch(void* const* d_in, const int* in_sizes, int n_in,
                              void* d_out, int out_size, void* d_ws, size_t ws_size,
                              hipStream_t stream)
{
    (void)in_sizes; (void)n_in; (void)out_size; (void)ws_size;
    const float* x      = (const float*)d_in[0];
    const int*   ei     = (const int*)d_in[1];
    const int*   batch  = (const int*)d_in[2];
    const float* lin0_w = (const float*)d_in[4];
    const float* lin0_b = (const float*)d_in[5];
    const float* r0_wih = (const float*)d_in[6];
    const float* r0_bih = (const float*)d_in[8];
    const float* r0_bhh = (const float*)d_in[9];
    const float* mh1_w  = (const float*)d_in[46];
    const float* mh1_b  = (const float*)d_in[47];
    const float* ln1_g  = (const float*)d_in[48];
    const float* ln1_b  = (const float*)d_in[49];
    const float* mh2_w  = (const float*)d_in[50];
    const float* mh2_b  = (const float*)d_in[51];
    const float* ln2_g  = (const float*)d_in[52];
    const float* ln2_b  = (const float*)d_in[53];
    float* out = (float*)d_out;

    // ---- workspace bump allocation ----
    char* wsb = (char*)d_ws;
    auto alloc = [&](size_t bytes) -> void* {
        void* p = (void*)wsb;
        wsb += (bytes + 255) & ~(size_t)255;
        return p;
    };
    const size_t NH = (size_t)MP * HID;
    float* cb   = (float*)alloc(NH * 4);          // LSTM cell state f32
    short* hA   = (short*)alloc(NH * 2);          // h ping
    short* hB   = (short*)alloc(NH * 2);          // h pong
    short* ybb  = (short*)alloc(NH * 2);          // LSTM-input / x0 bf16
    short* xlr  = (short*)alloc((size_t)MP * 512 * 2);  // [xl|xr] bf16
    int*   deg    = (int*)alloc((size_t)NN * 4);
    int*   rowptr = (int*)alloc((size_t)(NN + 1) * 4);
    int*   cursor = (int*)alloc((size_t)NN * 4);
    int*   esrc   = (int*)alloc((size_t)EP * 4);
    // weights bf16
    short* w_lin0 = (short*)alloc((size_t)256 * KP0 * 2);
    short* w_r0   = (short*)alloc((size_t)G4H * 256 * 2);
    short* w_lr[3]; short* w_ih[3]; short* w_hh[3]; float* blr[3];
    for (int l = 0; l < 3; ++l) {
        int Kp = (l == 0) ? KP0 : 256;
        w_lr[l] = (short*)alloc((size_t)512 * Kp * 2);
        w_ih[l] = (short*)alloc((size_t)G4H * 256 * 2);
        w_hh[l] = (short*)alloc((size_t)G4H * 256 * 2);
        blr[l]  = (float*)alloc(512 * 4);
    }
    short* w_m1 = (short*)alloc((size_t)NH1 * 256 * 2);
    short* w_m2 = (short*)alloc((size_t)NH2 * NH1 * 2);
    // xb (layer-0 padded input) with head temps aliased over it (head runs
    // only after xb is dead)
    short* xb = (short*)alloc((size_t)MP * KP0 * 2);   // 64 MB
    float* z1    = (float*)xb;                          // BG*NH1 f32 (8.4MB)
    short* z1b   = (short*)(z1 + (size_t)BG * NH1);     // BG*NH1 bf16
    short* poolb = z1b + (size_t)BG * NH1;              // BG*HID bf16

    auto conv = [&](const float* s, short* d, int rs, int rd, int Ks, int Kd) {
        conv_bf16<<<dim3(512), dim3(256), 0, stream>>>(s, d, rs, rd, Ks, Kd);
    };
    auto convg = [&](const float* s, short* d) {
        conv_gates<<<dim3(512), dim3(256), 0, stream>>>(s, d, 256);
    };
    // mode 0/1 GEMM; 1-D grid with XCD swizzle (requires (M/128)%8==0)
    auto G = [&](const short* A, const short* B, int K, const float* bias,
                 float* Cf, short* Cbb, int M, int N, int mode) {
        int nrp = M / 128, nct = N / 128;
        mfma_gemm<<<dim3(nrp * nct), dim3(256), 0, stream>>>(
            A, B, K, nullptr, nullptr, 0, bias,
            nullptr, nullptr, nullptr, nullptr, nullptr, Cf, Cbb, N, mode, nct);
    };
    // mode 2 LSTM GEMM
    auto GL = [&](const short* A1, const short* B1, int K1,
                  const short* A2, const short* B2, int K2,
                  const float* bih, const float* bhh,
                  const float* ci, float* co, short* ho) {
        mfma_gemm<<<dim3((MP / 128) * 8), dim3(256), 0, stream>>>(
            A1, B1, K1, A2, B2, K2, nullptr,
            bih, bhh, ci, co, ho, nullptr, nullptr, G4H, 2, 8);
    };

    // ---- conversions + CSR build ----
    conv(x, xb, NN, MP, FIN, KP0);
    conv(lin0_w, w_lin0, 256, 256, FIN, KP0);
    convg(r0_wih, w_r0);
    for (int l = 0; l < 3; ++l) {
        int base = 10 + 12 * l;
        int K  = (l == 0) ? FIN : 256;
        int Kp = (l == 0) ? KP0 : 256;
        conv((const float*)d_in[base + 0], w_lr[l], 256, 256, K, Kp);
        conv((const float*)d_in[base + 2], w_lr[l] + (size_t)256 * Kp, 256, 256, K, Kp);
        convg((const float*)d_in[base + 8], w_ih[l]);
        convg((const float*)d_in[base + 9], w_hh[l]);
        concat2_f32<<<dim3(2), dim3(256), 0, stream>>>(
            (const float*)d_in[base + 1], (const float*)d_in[base + 3], blr[l], 256, 256);
    }
    conv(mh1_w, w_m1, NH1, NH1, 256, 256);
    conv(mh2_w, w_m2, NH2, NH2, NH1, NH1);

    zero_f32<<<dim3(256), dim3(256), 0, stream>>>((float*)deg, NN);
    edge_hist<<<dim3((EP + 255) / 256), dim3(256), 0, stream>>>(ei, deg);
    scan_deg<<<dim3(1), dim3(1024), 0, stream>>>(deg, rowptr, cursor);
    edge_fill<<<dim3((EP + 255) / 256), dim3(256), 0, stream>>>(ei, rowptr, cursor, esrc);

    // ---- lin0 -> x0 (bf16); rnn0 LSTM from zero state (fused epilogue) ----
    G(xb, w_lin0, KP0, lin0_b, nullptr, ybb, MP, HID, 1);
    GL(ybb, w_r0, 256, nullptr, nullptr, 0, r0_bih, r0_bhh, nullptr, cb, hA);

    // ---- 3x (GATv2 -> LN+ELU -> LSTM) ----
    short* hprev = hA;
    short* hnext = hB;
    for (int l = 0; l < 3; ++l) {
        int base = 10 + 12 * l;
        const float* att = (const float*)d_in[base + 4];
        const float* gb  = (const float*)d_in[base + 5];
        const float* lg  = (const float*)d_in[base + 6];
        const float* lb  = (const float*)d_in[base + 7];
        const float* bih = (const float*)d_in[base + 10];
        const float* bhh = (const float*)d_in[base + 11];
        const short* Ain = (l == 0) ? xb : hprev;
        int K = (l == 0) ? KP0 : 256;

        G(Ain, w_lr[l], K, blr[l], nullptr, xlr, MP, 512, 1);
        gat_fused<<<dim3((NN + 3) / 4), dim3(256), 0, stream>>>(
            xlr, rowptr, esrc, att, gb, lg, lb, ybb);
        GL(ybb, w_ih[l], 256, hprev, w_hh[l], 256, bih, bhh, cb, cb, hnext);
        short* t = hprev; hprev = hnext; hnext = t;
    }

    // ---- mean pool (sorted batch) + MLP head ----
    pool_mean<<<dim3((BG + 3) / 4), dim3(256), 0, stream>>>(hprev, batch, poolb);
    G(poolb, w_m1, 256, mh1_b, z1, nullptr, BG, NH1, 0);
    ln_act_kernel<<<dim3(BG), dim3(256), 0, stream>>>(z1, ln1_g, ln1_b, nullptr, z1b, NH1, 1);
    G(z1b, w_m2, NH1, mh2_b, out, nullptr, BG, NH2, 0);
    ln_act_kernel<<<dim3(BG), dim3(256), 0, stream>>>(out, ln2_g, ln2_b, out, nullptr, NH2, 0);
}

// Round 11
// 2182.553 us; speedup vs baseline: 1.3042x; 1.0332x over previous
//
#include <hip/hip_runtime.h>
#include <hip/hip_bf16.h>
#include <math.h>

// ---------------------------------------------------------------------------
// GraphEncoder round 11: round-10 + double-buffered LDS prefetch in mfma_gemm
// (minimum 2-phase pipeline): stage K-step t+1 into buf[cur^1] BEFORE the
// ds_read+MFMA of step t; one __syncthreads per K-step. The barrier's
// vmcnt(0) drain now lands after MFMA instead of before it - the staging
// latency (L2-hit ~200cyc) is hidden under compute.
// Round-10 PMC said latency-bound: MfmaUtil 14 / VALU 21 / HBM 11 / Occ 22.
// ---------------------------------------------------------------------------

constexpr int NN    = 100000;
constexpr int EE    = 400000;
constexpr int EP    = EE + NN;      // 500000 (incl self loops)
constexpr int BG    = 4096;
constexpr int FIN   = 300;
constexpr int HEADS = 4;
constexpr int HID   = 256;
constexpr int G4H   = 1024;
constexpr int NH1   = 512;
constexpr int NH2   = 768;
constexpr int MP    = 100352;       // 784*128, 784 % 8 == 0
constexpr int KP0   = 320;          // FIN padded to mult of 32

typedef __attribute__((ext_vector_type(4))) float f32x4;
typedef __attribute__((ext_vector_type(8))) short s16x8;

#define LOG2E 1.4426950408889634f

// fast HW transcendentals (v_exp_f32 = 2^x, v_rcp_f32)
__device__ inline float fexp(float x)  { return __builtin_amdgcn_exp2f(x * LOG2E); }
__device__ inline float frcp(float x)  { return __builtin_amdgcn_rcpf(x); }
__device__ inline float fsigm(float x) { return frcp(1.f + __builtin_amdgcn_exp2f(-LOG2E * x)); }
__device__ inline float ftanh(float x) { return 1.f - 2.f * frcp(1.f + __builtin_amdgcn_exp2f(2.f * LOG2E * x)); }

__device__ inline float b2f(short s) { return __uint_as_float(((unsigned)(unsigned short)s) << 16); }
__device__ inline short f2b(float f) {
    unsigned u = __float_as_uint(f);
    u += 0x7fff + ((u >> 16) & 1);          // round-to-nearest-even
    return (short)(u >> 16);
}
__device__ inline float wsum64(float v) {
#pragma unroll
    for (int o = 32; o > 0; o >>= 1) v += __shfl_xor(v, o);
    return v;
}

// ---------------- utility kernels -------------------------------------------
__global__ __launch_bounds__(256) void zero_f32(float* __restrict__ p, long long n)
{
    long long i = (long long)blockIdx.x * 256 + threadIdx.x;
    long long stride = (long long)gridDim.x * 256;
    for (; i < n; i += stride) p[i] = 0.f;
}

// f32 -> bf16 with row/col zero padding
__global__ __launch_bounds__(256) void conv_bf16(
    const float* __restrict__ src, short* __restrict__ dst,
    int rsrc, int rdst, int Ks, int Kd)
{
    long long n = (long long)rdst * Kd;
    long long stride = (long long)gridDim.x * 256;
    for (long long i = (long long)blockIdx.x * 256 + threadIdx.x; i < n; i += stride) {
        int r = (int)(i / Kd);
        int k = (int)(i - (long long)r * Kd);
        float v = (r < rsrc && k < Ks) ? src[(long long)r * Ks + k] : 0.f;
        dst[i] = f2b(v);
    }
}

// gate-interleaved pack of LSTM weight [1024][K]:
// new row p -> orig row gate*256+ch, gate=(p>>4)&3, ch=(p>>7)*32+((p>>6)&1)*16+(p&15)
__global__ __launch_bounds__(256) void conv_gates(
    const float* __restrict__ src, short* __restrict__ dst, int K)
{
    long long n = (long long)G4H * K;
    long long stride = (long long)gridDim.x * 256;
    for (long long i = (long long)blockIdx.x * 256 + threadIdx.x; i < n; i += stride) {
        int p = (int)(i / K);
        int k = (int)(i - (long long)p * K);
        int gate = (p >> 4) & 3;
        int ch   = (p >> 7) * 32 + ((p >> 6) & 1) * 16 + (p & 15);
        dst[i] = f2b(src[(size_t)(gate * 256 + ch) * K + k]);
    }
}

__global__ __launch_bounds__(256) void concat2_f32(
    const float* __restrict__ a, const float* __restrict__ b,
    float* __restrict__ dst, int na, int nb)
{
    int i = blockIdx.x * 256 + threadIdx.x;
    if (i < na) dst[i] = a[i];
    else if (i < na + nb) dst[i] = b[i - na];
}

// ---------------- CSR build -------------------------------------------------
__global__ __launch_bounds__(256) void edge_hist(const int* __restrict__ ei,
                                                 int* __restrict__ deg)
{
    int e = blockIdx.x * 256 + threadIdx.x;
    if (e >= EP) return;
    int d = (e < EE) ? ei[EE + e] : e - EE;
    atomicAdd(&deg[d], 1);
}

__global__ __launch_bounds__(1024) void scan_deg(const int* __restrict__ deg,
                                                 int* __restrict__ rowptr,
                                                 int* __restrict__ cursor)
{
    __shared__ int part[1024];
    int t = threadIdx.x;
    const int CH = (NN + 1023) / 1024;
    int lo = t * CH, hi = min(lo + CH, NN);
    int s = 0;
    for (int i = lo; i < hi; ++i) s += deg[i];
    part[t] = s;
    __syncthreads();
    for (int off = 1; off < 1024; off <<= 1) {
        int v = (t >= off) ? part[t - off] : 0;
        __syncthreads();
        part[t] += v;
        __syncthreads();
    }
    int run = (t == 0) ? 0 : part[t - 1];
    for (int i = lo; i < hi; ++i) { rowptr[i] = run; cursor[i] = 0; run += deg[i]; }
    if (t == 1023) rowptr[NN] = run;   // == EP
}

__global__ __launch_bounds__(256) void edge_fill(const int* __restrict__ ei,
                                                 const int* __restrict__ rowptr,
                                                 int* __restrict__ cursor,
                                                 int* __restrict__ esrc)
{
    int e = blockIdx.x * 256 + threadIdx.x;
    if (e >= EP) return;
    int s, d;
    if (e < EE) { s = ei[e]; d = ei[EE + e]; }
    else        { s = d = e - EE; }
    int slot = rowptr[d] + atomicAdd(&cursor[d], 1);
    esrc[slot] = s;
}

// ---------------- MFMA GEMM with fused epilogues ----------------------------
// C[M x N] = A1[M x K1] @ B1[N x K1]^T (+ A2[M x K2] @ B2[N x K2]^T)
// 1-D grid of (M/128)*(N/128) blocks; XCD swizzle: xcd=bid&7, slot=bid>>3,
// g=slot/nct, ct=slot%nct, row_panel=g*8+xcd. Requires (M/128)%8==0.
// Double-buffered LDS: stage t+1 issued before compute of t; one barrier/step.
// mode 0: +bias -> f32 Cf      mode 1: +bias -> bf16 Cb
// mode 2: LSTM epilogue (gate-interleaved B; N=1024): reads c_in (or 0),
//         writes c_out f32 + h_out bf16, both [M][256].
__global__ __launch_bounds__(256) void mfma_gemm(
    const short* __restrict__ A1, const short* __restrict__ B1, int K1,
    const short* __restrict__ A2, const short* __restrict__ B2, int K2,
    const float* __restrict__ bias,
    const float* __restrict__ bih, const float* __restrict__ bhh,
    const float* __restrict__ c_in, float* __restrict__ c_out,
    short* __restrict__ h_out,
    float* __restrict__ Cf, short* __restrict__ Cb, int N, int mode, int nct)
{
    __shared__ __align__(16) short sA[2][128 * 32];
    __shared__ __align__(16) short sB[2][128 * 32];
    const int tid  = threadIdx.x;
    const int w    = tid >> 6, lane = tid & 63;
    const int wr   = w >> 1,  wc   = w & 1;      // 2x2 waves of 64x64
    // XCD-aware decode (consecutive bids round-robin across 8 XCDs)
    const int bid  = blockIdx.x;
    const int xcd  = bid & 7;
    const int slot = bid >> 3;
    const int g    = slot / nct;
    const int tcol = slot - g * nct;
    const int row0 = (g * 8 + xcd) * 128;
    const int col0 = tcol * 128;

    f32x4 acc[4][4];
#pragma unroll
    for (int m = 0; m < 4; ++m)
#pragma unroll
        for (int n = 0; n < 4; ++n) acc[m][n] = (f32x4){0.f, 0.f, 0.f, 0.f};

    const int rs = lane >> 2;
    const int cs = lane & 3;
    const int KK = K1 + K2;

    auto stage = [&](int buf, int k0) {
        const short* Ak; const short* Bk; int kk, ld;
        if (k0 < K1) { Ak = A1; Bk = B1; kk = k0;      ld = K1; }
        else         { Ak = A2; Bk = B2; kk = k0 - K1; ld = K2; }
#pragma unroll
        for (int i = 0; i < 2; ++i) {
            int seg = w * 2 + i;
            int row = seg * 16 + rs;
            int c8  = cs ^ ((row + (row >> 2)) & 3);
            const short* ga = Ak + (size_t)(row0 + row) * ld + kk + c8 * 8;
            const short* gb = Bk + (size_t)(col0 + row) * ld + kk + c8 * 8;
            short* la = &sA[buf][seg * 512 + lane * 8];
            short* lb = &sB[buf][seg * 512 + lane * 8];
            __builtin_amdgcn_global_load_lds((const __attribute__((address_space(1))) void*)ga,
                                             (__attribute__((address_space(3))) void*)la, 16, 0, 0);
            __builtin_amdgcn_global_load_lds((const __attribute__((address_space(1))) void*)gb,
                                             (__attribute__((address_space(3))) void*)lb, 16, 0, 0);
        }
    };

    stage(0, 0);
    __syncthreads();               // buf0 ready
    int cur = 0;
    for (int k0 = 0; k0 < KK; k0 += 32) {
        if (k0 + 32 < KK) stage(cur ^ 1, k0 + 32);   // prefetch next step

        s16x8 af[4], bg[4];
        {
            const int rl = lane & 15;
            const int cw = lane >> 4;
#pragma unroll
            for (int m = 0; m < 4; ++m) {
                int r  = wr * 64 + m * 16 + rl;
                int sl = cw ^ ((r + (r >> 2)) & 3);
                af[m] = *(const s16x8*)(&sA[cur][r * 32 + sl * 8]);
                int c  = wc * 64 + m * 16 + rl;
                int sc = cw ^ ((c + (c >> 2)) & 3);
                bg[m] = *(const s16x8*)(&sB[cur][c * 32 + sc * 8]);
            }
        }
#pragma unroll
        for (int m = 0; m < 4; ++m)
#pragma unroll
            for (int n = 0; n < 4; ++n)
                acc[m][n] = __builtin_amdgcn_mfma_f32_16x16x32_bf16(af[m], bg[n], acc[m][n], 0, 0, 0);
        __syncthreads();           // drains prefetch vmcnt + all waves done with buf[cur]
        cur ^= 1;
    }

    // C/D layout: col=lane&15, row=(lane>>4)*4+reg
    const int l16   = lane & 15;
    const int rbase = row0 + wr * 64 + (lane >> 4) * 4;
    if (mode == 2) {
        const int ch = tcol * 32 + wc * 16 + l16;
        float bi[4];
#pragma unroll
        for (int gg2 = 0; gg2 < 4; ++gg2) bi[gg2] = bih[gg2 * 256 + ch] + bhh[gg2 * 256 + ch];
#pragma unroll
        for (int m = 0; m < 4; ++m) {
#pragma unroll
            for (int r = 0; r < 4; ++r) {
                int row = rbase + m * 16 + r;
                float gi = acc[m][0][r] + bi[0];
                float gf = acc[m][1][r] + bi[1];
                float gg = acc[m][2][r] + bi[2];
                float go = acc[m][3][r] + bi[3];
                size_t idx = (size_t)row * HID + ch;
                float co = c_in ? c_in[idx] : 0.f;
                float c2 = fsigm(gf) * co + fsigm(gi) * ftanh(gg);
                float h2 = fsigm(go) * ftanh(c2);
                c_out[idx] = c2;
                h_out[idx] = f2b(h2);
            }
        }
    } else {
        const int cbase = col0 + wc * 64 + l16;
#pragma unroll
        for (int n = 0; n < 4; ++n) {
            int col = cbase + n * 16;
            float ba = bias ? bias[col] : 0.f;
#pragma unroll
            for (int m = 0; m < 4; ++m) {
#pragma unroll
                for (int r = 0; r < 4; ++r) {
                    int row = rbase + m * 16 + r;
                    float v = acc[m][n][r] + ba;
                    size_t idx = (size_t)row * N + col;
                    if (mode == 1) Cb[idx] = f2b(v);
                    else           Cf[idx] = v;
                }
            }
        }
    }
}

// ---------------- fused GATv2 (softmax + aggregate + bias + LN + ELU) -------
// one 64-lane wave per dst node; lane l = channel h*64+l per head h.
// xlr: [MP][512] bf16, cols 0..255 = lin_l(x), 256..511 = lin_r(x).
__global__ __launch_bounds__(256) void gat_fused(
    const short* __restrict__ xlr, const int* __restrict__ rowptr,
    const int* __restrict__ esrc, const float* __restrict__ att,
    const float* __restrict__ gb, const float* __restrict__ lg,
    const float* __restrict__ lb, short* __restrict__ outb)
{
    int i    = blockIdx.x * 4 + (threadIdx.x >> 6);
    int lane = threadIdx.x & 63;
    if (i >= NN) return;
    float xr[HEADS], at[HEADS];
#pragma unroll
    for (int h = 0; h < HEADS; ++h) {
        xr[h] = b2f(xlr[(size_t)i * 512 + 256 + h * 64 + lane]);
        at[h] = att[h * 64 + lane];
    }
    float mx[HEADS], sm[HEADS], ac[HEADS];
#pragma unroll
    for (int h = 0; h < HEADS; ++h) { mx[h] = -INFINITY; sm[h] = 0.f; ac[h] = 0.f; }

    int lo = rowptr[i], hi = rowptr[i + 1];
    for (int e = lo; e < hi; ++e) {
        int s = esrc[e];
        float xs[HEADS], p[HEADS];
#pragma unroll
        for (int h = 0; h < HEADS; ++h) {
            xs[h] = b2f(xlr[(size_t)s * 512 + h * 64 + lane]);
            float v = xs[h] + xr[h];
            v = (v >= 0.f) ? v : 0.2f * v;
            p[h] = v * at[h];
        }
#pragma unroll
        for (int h = 0; h < HEADS; ++h) p[h] = wsum64(p[h]);
#pragma unroll
        for (int h = 0; h < HEADS; ++h) {
            float mn = fmaxf(mx[h], p[h]);
            float sc = fexp(mx[h] - mn);     // first iter: exp(-inf)=0
            float a  = fexp(p[h] - mn);
            sm[h] = sm[h] * sc + a;
            ac[h] = ac[h] * sc + a * xs[h];
            mx[h] = mn;
        }
    }
    // y = ac/sm (+ gat bias), then LayerNorm(256) + ELU, write bf16
    float val[HEADS], s1 = 0.f, s2 = 0.f;
#pragma unroll
    for (int h = 0; h < HEADS; ++h) {
        float v = ac[h] * frcp(sm[h]) + gb[h * 64 + lane];
        val[h] = v; s1 += v; s2 += v * v;
    }
    s1 = wsum64(s1); s2 = wsum64(s2);
    float mean = s1 * (1.f / 256.f);
    float var  = s2 * (1.f / 256.f) - mean * mean;
    float inv  = rsqrtf(var + 1e-5f);
#pragma unroll
    for (int h = 0; h < HEADS; ++h) {
        float v = (val[h] - mean) * inv * lg[h * 64 + lane] + lb[h * 64 + lane];
        v = (v > 0.f) ? v : (fexp(v) - 1.f);
        outb[(size_t)i * HID + h * 64 + lane] = f2b(v);
    }
}

// ---------------- LayerNorm (+act) for the MLP head -------------------------
__global__ __launch_bounds__(256) void ln_act_kernel(
    const float* __restrict__ in, const float* __restrict__ gamma,
    const float* __restrict__ beta, float* __restrict__ outf,
    short* __restrict__ outb, int width, int act)
{
    int row = blockIdx.x;
    const float* ip = in + (size_t)row * width;
    float vals[3];
    float s = 0.f, ss = 0.f;
    int nw = width >> 8;
    for (int i = 0; i < nw; ++i) {
        int c = threadIdx.x + (i << 8);
        float v = ip[c];
        vals[i] = v; s += v; ss += v * v;
    }
#pragma unroll
    for (int off = 32; off > 0; off >>= 1) {
        s  += __shfl_down(s, off);
        ss += __shfl_down(ss, off);
    }
    __shared__ float sh[8];
    int wv = threadIdx.x >> 6, lane = threadIdx.x & 63;
    if (lane == 0) { sh[wv] = s; sh[4 + wv] = ss; }
    __syncthreads();
    if (threadIdx.x == 0) {
        sh[0] = sh[0] + sh[1] + sh[2] + sh[3];
        sh[4] = sh[4] + sh[5] + sh[6] + sh[7];
    }
    __syncthreads();
    float mean = sh[0] / width;
    float var  = sh[4] / width - mean * mean;
    float inv  = rsqrtf(var + 1e-5f);
    for (int i = 0; i < nw; ++i) {
        int c = threadIdx.x + (i << 8);
        float v = (vals[i] - mean) * inv * gamma[c] + beta[c];
        if (act == 1) v = fmaxf(v, 0.f);
        if (outb) outb[(size_t)row * width + c] = f2b(v);
        else      outf[(size_t)row * width + c] = v;
    }
}

// ---------------- sorted-batch mean pool ------------------------------------
__global__ __launch_bounds__(256) void pool_mean(
    const short* __restrict__ h, const int* __restrict__ batch,
    short* __restrict__ poolb)
{
    int b    = blockIdx.x * 4 + (threadIdx.x >> 6);
    int lane = threadIdx.x & 63;
    if (b >= BG) return;
    auto lbound = [&](int key) {
        int lo = 0, hi = NN;
        while (lo < hi) { int mid = (lo + hi) >> 1; if (batch[mid] < key) lo = mid + 1; else hi = mid; }
        return lo;
    };
    int lo = lbound(b), hi = lbound(b + 1);
    float acc[HEADS] = {0.f, 0.f, 0.f, 0.f};
    for (int r = lo; r < hi; ++r)
#pragma unroll
        for (int hh = 0; hh < HEADS; ++hh)
            acc[hh] += b2f(h[(size_t)r * HID + hh * 64 + lane]);
    float inv = 1.f / fmaxf((float)(hi - lo), 1.f);
#pragma unroll
    for (int hh = 0; hh < HEADS; ++hh)
        poolb[(size_t)b * HID + hh * 64 + lane] = f2b(acc[hh] * inv);
}

// ---------------------------------------------------------------------------
extern "C" void kernel_launch(void* const* d_in, const int* in_sizes, int n_in,
                              void* d_out, int out_size, void* d_ws, size_t ws_size,
                              hipStream_t stream)
{
    (void)in_sizes; (void)n_in; (void)out_size; (void)ws_size;
    const float* x      = (const float*)d_in[0];
    const int*   ei     = (const int*)d_in[1];
    const int*   batch  = (const int*)d_in[2];
    const float* lin0_w = (const float*)d_in[4];
    const float* lin0_b = (const float*)d_in[5];
    const float* r0_wih = (const float*)d_in[6];
    const float* r0_bih = (const float*)d_in[8];
    const float* r0_bhh = (const float*)d_in[9];
    const float* mh1_w  = (const float*)d_in[46];
    const float* mh1_b  = (const float*)d_in[47];
    const float* ln1_g  = (const float*)d_in[48];
    const float* ln1_b  = (const float*)d_in[49];
    const float* mh2_w  = (const float*)d_in[50];
    const float* mh2_b  = (const float*)d_in[51];
    const float* ln2_g  = (const float*)d_in[52];
    const float* ln2_b  = (const float*)d_in[53];
    float* out = (float*)d_out;

    // ---- workspace bump allocation ----
    char* wsb = (char*)d_ws;
    auto alloc = [&](size_t bytes) -> void* {
        void* p = (void*)wsb;
        wsb += (bytes + 255) & ~(size_t)255;
        return p;
    };
    const size_t NH = (size_t)MP * HID;
    float* cb   = (float*)alloc(NH * 4);          // LSTM cell state f32
    short* hA   = (short*)alloc(NH * 2);          // h ping
    short* hB   = (short*)alloc(NH * 2);          // h pong
    short* ybb  = (short*)alloc(NH * 2);          // LSTM-input / x0 bf16
    short* xlr  = (short*)alloc((size_t)MP * 512 * 2);  // [xl|xr] bf16
    int*   deg    = (int*)alloc((size_t)NN * 4);
    int*   rowptr = (int*)alloc((size_t)(NN + 1) * 4);
    int*   cursor = (int*)alloc((size_t)NN * 4);
    int*   esrc   = (int*)alloc((size_t)EP * 4);
    // weights bf16
    short* w_lin0 = (short*)alloc((size_t)256 * KP0 * 2);
    short* w_r0   = (short*)alloc((size_t)G4H * 256 * 2);
    short* w_lr[3]; short* w_ih[3]; short* w_hh[3]; float* blr[3];
    for (int l = 0; l < 3; ++l) {
        int Kp = (l == 0) ? KP0 : 256;
        w_lr[l] = (short*)alloc((size_t)512 * Kp * 2);
        w_ih[l] = (short*)alloc((size_t)G4H * 256 * 2);
        w_hh[l] = (short*)alloc((size_t)G4H * 256 * 2);
        blr[l]  = (float*)alloc(512 * 4);
    }
    short* w_m1 = (short*)alloc((size_t)NH1 * 256 * 2);
    short* w_m2 = (short*)alloc((size_t)NH2 * NH1 * 2);
    // xb (layer-0 padded input) with head temps aliased over it (head runs
    // only after xb is dead)
    short* xb = (short*)alloc((size_t)MP * KP0 * 2);   // 64 MB
    float* z1    = (float*)xb;                          // BG*NH1 f32 (8.4MB)
    short* z1b   = (short*)(z1 + (size_t)BG * NH1);     // BG*NH1 bf16
    short* poolb = z1b + (size_t)BG * NH1;              // BG*HID bf16

    auto conv = [&](const float* s, short* d, int rs, int rd, int Ks, int Kd) {
        conv_bf16<<<dim3(512), dim3(256), 0, stream>>>(s, d, rs, rd, Ks, Kd);
    };
    auto convg = [&](const float* s, short* d) {
        conv_gates<<<dim3(512), dim3(256), 0, stream>>>(s, d, 256);
    };
    // mode 0/1 GEMM; 1-D grid with XCD swizzle (requires (M/128)%8==0)
    auto G = [&](const short* A, const short* B, int K, const float* bias,
                 float* Cf, short* Cbb, int M, int N, int mode) {
        int nrp = M / 128, nct = N / 128;
        mfma_gemm<<<dim3(nrp * nct), dim3(256), 0, stream>>>(
            A, B, K, nullptr, nullptr, 0, bias,
            nullptr, nullptr, nullptr, nullptr, nullptr, Cf, Cbb, N, mode, nct);
    };
    // mode 2 LSTM GEMM
    auto GL = [&](const short* A1, const short* B1, int K1,
                  const short* A2, const short* B2, int K2,
                  const float* bih, const float* bhh,
                  const float* ci, float* co, short* ho) {
        mfma_gemm<<<dim3((MP / 128) * 8), dim3(256), 0, stream>>>(
            A1, B1, K1, A2, B2, K2, nullptr,
            bih, bhh, ci, co, ho, nullptr, nullptr, G4H, 2, 8);
    };

    // ---- conversions + CSR build ----
    conv(x, xb, NN, MP, FIN, KP0);
    conv(lin0_w, w_lin0, 256, 256, FIN, KP0);
    convg(r0_wih, w_r0);
    for (int l = 0; l < 3; ++l) {
        int base = 10 + 12 * l;
        int K  = (l == 0) ? FIN : 256;
        int Kp = (l == 0) ? KP0 : 256;
        conv((const float*)d_in[base + 0], w_lr[l], 256, 256, K, Kp);
        conv((const float*)d_in[base + 2], w_lr[l] + (size_t)256 * Kp, 256, 256, K, Kp);
        convg((const float*)d_in[base + 8], w_ih[l]);
        convg((const float*)d_in[base + 9], w_hh[l]);
        concat2_f32<<<dim3(2), dim3(256), 0, stream>>>(
            (const float*)d_in[base + 1], (const float*)d_in[base + 3], blr[l], 256, 256);
    }
    conv(mh1_w, w_m1, NH1, NH1, 256, 256);
    conv(mh2_w, w_m2, NH2, NH2, NH1, NH1);

    zero_f32<<<dim3(256), dim3(256), 0, stream>>>((float*)deg, NN);
    edge_hist<<<dim3((EP + 255) / 256), dim3(256), 0, stream>>>(ei, deg);
    scan_deg<<<dim3(1), dim3(1024), 0, stream>>>(deg, rowptr, cursor);
    edge_fill<<<dim3((EP + 255) / 256), dim3(256), 0, stream>>>(ei, rowptr, cursor, esrc);

    // ---- lin0 -> x0 (bf16); rnn0 LSTM from zero state (fused epilogue) ----
    G(xb, w_lin0, KP0, lin0_b, nullptr, ybb, MP, HID, 1);
    GL(ybb, w_r0, 256, nullptr, nullptr, 0, r0_bih, r0_bhh, nullptr, cb, hA);

    // ---- 3x (GATv2 -> LN+ELU -> LSTM) ----
    short* hprev = hA;
    short* hnext = hB;
    for (int l = 0; l < 3; ++l) {
        int base = 10 + 12 * l;
        const float* att = (const float*)d_in[base + 4];
        const float* gb  = (const float*)d_in[base + 5];
        const float* lg  = (const float*)d_in[base + 6];
        const float* lb  = (const float*)d_in[base + 7];
        const float* bih = (const float*)d_in[base + 10];
        const float* bhh = (const float*)d_in[base + 11];
        const short* Ain = (l == 0) ? xb : hprev;
        int K = (l == 0) ? KP0 : 256;

        G(Ain, w_lr[l], K, blr[l], nullptr, xlr, MP, 512, 1);
        gat_fused<<<dim3((NN + 3) / 4), dim3(256), 0, stream>>>(
            xlr, rowptr, esrc, att, gb, lg, lb, ybb);
        GL(ybb, w_ih[l], 256, hprev, w_hh[l], 256, bih, bhh, cb, cb, hnext);
        short* t = hprev; hprev = hnext; hnext = t;
    }

    // ---- mean pool (sorted batch) + MLP head ----
    pool_mean<<<dim3((BG + 3) / 4), dim3(256), 0, stream>>>(hprev, batch, poolb);
    G(poolb, w_m1, 256, mh1_b, z1, nullptr, BG, NH1, 0);
    ln_act_kernel<<<dim3(BG), dim3(256), 0, stream>>>(z1, ln1_g, ln1_b, nullptr, z1b, NH1, 1);
    G(z1b, w_m2, NH1, mh2_b, out, nullptr, BG, NH2, 0);
    ln_act_kernel<<<dim3(BG), dim3(256), 0, stream>>>(out, ln2_g, ln2_b, out, nullptr, NH2, 0);
}

// Round 12
// 2169.400 us; speedup vs baseline: 1.3121x; 1.0061x over previous
//
#include <hip/hip_runtime.h>
#include <hip/hip_bf16.h>
#include <math.h>

// ---------------------------------------------------------------------------
// GraphEncoder round 12: round-11 + counted-vmcnt pipeline (T4) in mfma_gemm.
// Round-11's dbuf still drained vmcnt(0) at every __syncthreads -> prefetch
// latency stayed on the critical path (MfmaUtil 15%, latency-bound).
// New loop: raw s_barrier + s_waitcnt vmcnt(4) (never 0 mid-loop); loads for
// step t are issued at t-2 and have ~2 K-steps to land. lgkmcnt(0)+barrier
// before re-staging buf[cur] guarantees no read-overwrite race.
// ---------------------------------------------------------------------------

constexpr int NN    = 100000;
constexpr int EE    = 400000;
constexpr int EP    = EE + NN;      // 500000 (incl self loops)
constexpr int BG    = 4096;
constexpr int FIN   = 300;
constexpr int HEADS = 4;
constexpr int HID   = 256;
constexpr int G4H   = 1024;
constexpr int NH1   = 512;
constexpr int NH2   = 768;
constexpr int MP    = 100352;       // 784*128, 784 % 8 == 0
constexpr int KP0   = 320;          // FIN padded to mult of 32

typedef __attribute__((ext_vector_type(4))) float f32x4;
typedef __attribute__((ext_vector_type(8))) short s16x8;

#define LOG2E 1.4426950408889634f

// fast HW transcendentals (v_exp_f32 = 2^x, v_rcp_f32)
__device__ inline float fexp(float x)  { return __builtin_amdgcn_exp2f(x * LOG2E); }
__device__ inline float frcp(float x)  { return __builtin_amdgcn_rcpf(x); }
__device__ inline float fsigm(float x) { return frcp(1.f + __builtin_amdgcn_exp2f(-LOG2E * x)); }
__device__ inline float ftanh(float x) { return 1.f - 2.f * frcp(1.f + __builtin_amdgcn_exp2f(2.f * LOG2E * x)); }

__device__ inline float b2f(short s) { return __uint_as_float(((unsigned)(unsigned short)s) << 16); }
__device__ inline short f2b(float f) {
    unsigned u = __float_as_uint(f);
    u += 0x7fff + ((u >> 16) & 1);          // round-to-nearest-even
    return (short)(u >> 16);
}
__device__ inline float wsum64(float v) {
#pragma unroll
    for (int o = 32; o > 0; o >>= 1) v += __shfl_xor(v, o);
    return v;
}

// ---------------- utility kernels -------------------------------------------
__global__ __launch_bounds__(256) void zero_f32(float* __restrict__ p, long long n)
{
    long long i = (long long)blockIdx.x * 256 + threadIdx.x;
    long long stride = (long long)gridDim.x * 256;
    for (; i < n; i += stride) p[i] = 0.f;
}

// f32 -> bf16 with row/col zero padding
__global__ __launch_bounds__(256) void conv_bf16(
    const float* __restrict__ src, short* __restrict__ dst,
    int rsrc, int rdst, int Ks, int Kd)
{
    long long n = (long long)rdst * Kd;
    long long stride = (long long)gridDim.x * 256;
    for (long long i = (long long)blockIdx.x * 256 + threadIdx.x; i < n; i += stride) {
        int r = (int)(i / Kd);
        int k = (int)(i - (long long)r * Kd);
        float v = (r < rsrc && k < Ks) ? src[(long long)r * Ks + k] : 0.f;
        dst[i] = f2b(v);
    }
}

// gate-interleaved pack of LSTM weight [1024][K]:
// new row p -> orig row gate*256+ch, gate=(p>>4)&3, ch=(p>>7)*32+((p>>6)&1)*16+(p&15)
__global__ __launch_bounds__(256) void conv_gates(
    const float* __restrict__ src, short* __restrict__ dst, int K)
{
    long long n = (long long)G4H * K;
    long long stride = (long long)gridDim.x * 256;
    for (long long i = (long long)blockIdx.x * 256 + threadIdx.x; i < n; i += stride) {
        int p = (int)(i / K);
        int k = (int)(i - (long long)p * K);
        int gate = (p >> 4) & 3;
        int ch   = (p >> 7) * 32 + ((p >> 6) & 1) * 16 + (p & 15);
        dst[i] = f2b(src[(size_t)(gate * 256 + ch) * K + k]);
    }
}

__global__ __launch_bounds__(256) void concat2_f32(
    const float* __restrict__ a, const float* __restrict__ b,
    float* __restrict__ dst, int na, int nb)
{
    int i = blockIdx.x * 256 + threadIdx.x;
    if (i < na) dst[i] = a[i];
    else if (i < na + nb) dst[i] = b[i - na];
}

// ---------------- CSR build -------------------------------------------------
__global__ __launch_bounds__(256) void edge_hist(const int* __restrict__ ei,
                                                 int* __restrict__ deg)
{
    int e = blockIdx.x * 256 + threadIdx.x;
    if (e >= EP) return;
    int d = (e < EE) ? ei[EE + e] : e - EE;
    atomicAdd(&deg[d], 1);
}

__global__ __launch_bounds__(1024) void scan_deg(const int* __restrict__ deg,
                                                 int* __restrict__ rowptr,
                                                 int* __restrict__ cursor)
{
    __shared__ int part[1024];
    int t = threadIdx.x;
    const int CH = (NN + 1023) / 1024;
    int lo = t * CH, hi = min(lo + CH, NN);
    int s = 0;
    for (int i = lo; i < hi; ++i) s += deg[i];
    part[t] = s;
    __syncthreads();
    for (int off = 1; off < 1024; off <<= 1) {
        int v = (t >= off) ? part[t - off] : 0;
        __syncthreads();
        part[t] += v;
        __syncthreads();
    }
    int run = (t == 0) ? 0 : part[t - 1];
    for (int i = lo; i < hi; ++i) { rowptr[i] = run; cursor[i] = 0; run += deg[i]; }
    if (t == 1023) rowptr[NN] = run;   // == EP
}

__global__ __launch_bounds__(256) void edge_fill(const int* __restrict__ ei,
                                                 const int* __restrict__ rowptr,
                                                 int* __restrict__ cursor,
                                                 int* __restrict__ esrc)
{
    int e = blockIdx.x * 256 + threadIdx.x;
    if (e >= EP) return;
    int s, d;
    if (e < EE) { s = ei[e]; d = ei[EE + e]; }
    else        { s = d = e - EE; }
    int slot = rowptr[d] + atomicAdd(&cursor[d], 1);
    esrc[slot] = s;
}

// ---------------- MFMA GEMM with fused epilogues ----------------------------
// C[M x N] = A1[M x K1] @ B1[N x K1]^T (+ A2[M x K2] @ B2[N x K2]^T)
// 1-D grid of (M/128)*(N/128) blocks; XCD swizzle: xcd=bid&7, slot=bid>>3,
// g=slot/nct, ct=slot%nct, row_panel=g*8+xcd. Requires (M/128)%8==0.
// Counted-vmcnt double-buffer: loads for step t issued at t-2; vmcnt(4)
// mid-loop (vmcnt(0) only at final step); lgkmcnt(0)+s_barrier before
// re-staging a buffer. Requires KK >= 64 (all call sites have KK >= 256).
// mode 0: +bias -> f32 Cf      mode 1: +bias -> bf16 Cb
// mode 2: LSTM epilogue (gate-interleaved B; N=1024): reads c_in (or 0),
//         writes c_out f32 + h_out bf16, both [M][256].
__global__ __launch_bounds__(256) void mfma_gemm(
    const short* __restrict__ A1, const short* __restrict__ B1, int K1,
    const short* __restrict__ A2, const short* __restrict__ B2, int K2,
    const float* __restrict__ bias,
    const float* __restrict__ bih, const float* __restrict__ bhh,
    const float* __restrict__ c_in, float* __restrict__ c_out,
    short* __restrict__ h_out,
    float* __restrict__ Cf, short* __restrict__ Cb, int N, int mode, int nct)
{
    __shared__ __align__(16) short sA[2][128 * 32];
    __shared__ __align__(16) short sB[2][128 * 32];
    const int tid  = threadIdx.x;
    const int w    = tid >> 6, lane = tid & 63;
    const int wr   = w >> 1,  wc   = w & 1;      // 2x2 waves of 64x64
    // XCD-aware decode (consecutive bids round-robin across 8 XCDs)
    const int bid  = blockIdx.x;
    const int xcd  = bid & 7;
    const int slot = bid >> 3;
    const int g    = slot / nct;
    const int tcol = slot - g * nct;
    const int row0 = (g * 8 + xcd) * 128;
    const int col0 = tcol * 128;

    f32x4 acc[4][4];
#pragma unroll
    for (int m = 0; m < 4; ++m)
#pragma unroll
        for (int n = 0; n < 4; ++n) acc[m][n] = (f32x4){0.f, 0.f, 0.f, 0.f};

    const int rs = lane >> 2;
    const int cs = lane & 3;
    const int KK = K1 + K2;

    // 4 global_load_lds per wave per stage call
    auto stage = [&](int buf, int k0) {
        const short* Ak; const short* Bk; int kk, ld;
        if (k0 < K1) { Ak = A1; Bk = B1; kk = k0;      ld = K1; }
        else         { Ak = A2; Bk = B2; kk = k0 - K1; ld = K2; }
#pragma unroll
        for (int i = 0; i < 2; ++i) {
            int seg = w * 2 + i;
            int row = seg * 16 + rs;
            int c8  = cs ^ ((row + (row >> 2)) & 3);
            const short* ga = Ak + (size_t)(row0 + row) * ld + kk + c8 * 8;
            const short* gb = Bk + (size_t)(col0 + row) * ld + kk + c8 * 8;
            short* la = &sA[buf][seg * 512 + lane * 8];
            short* lb = &sB[buf][seg * 512 + lane * 8];
            __builtin_amdgcn_global_load_lds((const __attribute__((address_space(1))) void*)ga,
                                             (__attribute__((address_space(3))) void*)la, 16, 0, 0);
            __builtin_amdgcn_global_load_lds((const __attribute__((address_space(1))) void*)gb,
                                             (__attribute__((address_space(3))) void*)lb, 16, 0, 0);
        }
    };

    stage(0, 0);
    stage(1, 32);                  // KK >= 64 guaranteed by call sites
    int cur = 0;
    for (int k0 = 0; k0 < KK; k0 += 32) {
        // buf[cur]'s 4 loads are the oldest group; leave the newer group
        // (next step's buf) in flight. Last step: drain everything.
        if (k0 + 32 < KK) asm volatile("s_waitcnt vmcnt(4)" ::: "memory");
        else              asm volatile("s_waitcnt vmcnt(0)" ::: "memory");
        __builtin_amdgcn_s_barrier();          // all waves: buf[cur] ready
        asm volatile("" ::: "memory");

        s16x8 af[4], bg[4];
        {
            const int rl = lane & 15;
            const int cw = lane >> 4;
#pragma unroll
            for (int m = 0; m < 4; ++m) {
                int r  = wr * 64 + m * 16 + rl;
                int sl = cw ^ ((r + (r >> 2)) & 3);
                af[m] = *(const s16x8*)(&sA[cur][r * 32 + sl * 8]);
                int c  = wc * 64 + m * 16 + rl;
                int sc = cw ^ ((c + (c >> 2)) & 3);
                bg[m] = *(const s16x8*)(&sB[cur][c * 32 + sc * 8]);
            }
        }
        // all this wave's ds_reads complete, then block-wide barrier ->
        // no wave can still be reading buf[cur] when we overwrite it
        asm volatile("s_waitcnt lgkmcnt(0)" ::: "memory");
        __builtin_amdgcn_s_barrier();
        asm volatile("" ::: "memory");
        if (k0 + 64 < KK) stage(cur, k0 + 64);   // re-stage 2 steps ahead

#pragma unroll
        for (int m = 0; m < 4; ++m)
#pragma unroll
            for (int n = 0; n < 4; ++n)
                acc[m][n] = __builtin_amdgcn_mfma_f32_16x16x32_bf16(af[m], bg[n], acc[m][n], 0, 0, 0);
        cur ^= 1;
    }

    // C/D layout: col=lane&15, row=(lane>>4)*4+reg
    const int l16   = lane & 15;
    const int rbase = row0 + wr * 64 + (lane >> 4) * 4;
    if (mode == 2) {
        const int ch = tcol * 32 + wc * 16 + l16;
        float bi[4];
#pragma unroll
        for (int gg2 = 0; gg2 < 4; ++gg2) bi[gg2] = bih[gg2 * 256 + ch] + bhh[gg2 * 256 + ch];
#pragma unroll
        for (int m = 0; m < 4; ++m) {
#pragma unroll
            for (int r = 0; r < 4; ++r) {
                int row = rbase + m * 16 + r;
                float gi = acc[m][0][r] + bi[0];
                float gf = acc[m][1][r] + bi[1];
                float gg = acc[m][2][r] + bi[2];
                float go = acc[m][3][r] + bi[3];
                size_t idx = (size_t)row * HID + ch;
                float co = c_in ? c_in[idx] : 0.f;
                float c2 = fsigm(gf) * co + fsigm(gi) * ftanh(gg);
                float h2 = fsigm(go) * ftanh(c2);
                c_out[idx] = c2;
                h_out[idx] = f2b(h2);
            }
        }
    } else {
        const int cbase = col0 + wc * 64 + l16;
#pragma unroll
        for (int n = 0; n < 4; ++n) {
            int col = cbase + n * 16;
            float ba = bias ? bias[col] : 0.f;
#pragma unroll
            for (int m = 0; m < 4; ++m) {
#pragma unroll
                for (int r = 0; r < 4; ++r) {
                    int row = rbase + m * 16 + r;
                    float v = acc[m][n][r] + ba;
                    size_t idx = (size_t)row * N + col;
                    if (mode == 1) Cb[idx] = f2b(v);
                    else           Cf[idx] = v;
                }
            }
        }
    }
}

// ---------------- fused GATv2 (softmax + aggregate + bias + LN + ELU) -------
// one 64-lane wave per dst node; lane l = channel h*64+l per head h.
// xlr: [MP][512] bf16, cols 0..255 = lin_l(x), 256..511 = lin_r(x).
__global__ __launch_bounds__(256) void gat_fused(
    const short* __restrict__ xlr, const int* __restrict__ rowptr,
    const int* __restrict__ esrc, const float* __restrict__ att,
    const float* __restrict__ gb, const float* __restrict__ lg,
    const float* __restrict__ lb, short* __restrict__ outb)
{
    int i    = blockIdx.x * 4 + (threadIdx.x >> 6);
    int lane = threadIdx.x & 63;
    if (i >= NN) return;
    float xr[HEADS], at[HEADS];
#pragma unroll
    for (int h = 0; h < HEADS; ++h) {
        xr[h] = b2f(xlr[(size_t)i * 512 + 256 + h * 64 + lane]);
        at[h] = att[h * 64 + lane];
    }
    float mx[HEADS], sm[HEADS], ac[HEADS];
#pragma unroll
    for (int h = 0; h < HEADS; ++h) { mx[h] = -INFINITY; sm[h] = 0.f; ac[h] = 0.f; }

    int lo = rowptr[i], hi = rowptr[i + 1];
    for (int e = lo; e < hi; ++e) {
        int s = esrc[e];
        float xs[HEADS], p[HEADS];
#pragma unroll
        for (int h = 0; h < HEADS; ++h) {
            xs[h] = b2f(xlr[(size_t)s * 512 + h * 64 + lane]);
            float v = xs[h] + xr[h];
            v = (v >= 0.f) ? v : 0.2f * v;
            p[h] = v * at[h];
        }
#pragma unroll
        for (int h = 0; h < HEADS; ++h) p[h] = wsum64(p[h]);
#pragma unroll
        for (int h = 0; h < HEADS; ++h) {
            float mn = fmaxf(mx[h], p[h]);
            float sc = fexp(mx[h] - mn);     // first iter: exp(-inf)=0
            float a  = fexp(p[h] - mn);
            sm[h] = sm[h] * sc + a;
            ac[h] = ac[h] * sc + a * xs[h];
            mx[h] = mn;
        }
    }
    // y = ac/sm (+ gat bias), then LayerNorm(256) + ELU, write bf16
    float val[HEADS], s1 = 0.f, s2 = 0.f;
#pragma unroll
    for (int h = 0; h < HEADS; ++h) {
        float v = ac[h] * frcp(sm[h]) + gb[h * 64 + lane];
        val[h] = v; s1 += v; s2 += v * v;
    }
    s1 = wsum64(s1); s2 = wsum64(s2);
    float mean = s1 * (1.f / 256.f);
    float var  = s2 * (1.f / 256.f) - mean * mean;
    float inv  = rsqrtf(var + 1e-5f);
#pragma unroll
    for (int h = 0; h < HEADS; ++h) {
        float v = (val[h] - mean) * inv * lg[h * 64 + lane] + lb[h * 64 + lane];
        v = (v > 0.f) ? v : (fexp(v) - 1.f);
        outb[(size_t)i * HID + h * 64 + lane] = f2b(v);
    }
}

// ---------------- LayerNorm (+act) for the MLP head -------------------------
__global__ __launch_bounds__(256) void ln_act_kernel(
    const float* __restrict__ in, const float* __restrict__ gamma,
    const float* __restrict__ beta, float* __restrict__ outf,
    short* __restrict__ outb, int width, int act)
{
    int row = blockIdx.x;
    const float* ip = in + (size_t)row * width;
    float vals[3];
    float s = 0.f, ss = 0.f;
    int nw = width >> 8;
    for (int i = 0; i < nw; ++i) {
        int c = threadIdx.x + (i << 8);
        float v = ip[c];
        vals[i] = v; s += v; ss += v * v;
    }
#pragma unroll
    for (int off = 32; off > 0; off >>= 1) {
        s  += __shfl_down(s, off);
        ss += __shfl_down(ss, off);
    }
    __shared__ float sh[8];
    int wv = threadIdx.x >> 6, lane = threadIdx.x & 63;
    if (lane == 0) { sh[wv] = s; sh[4 + wv] = ss; }
    __syncthreads();
    if (threadIdx.x == 0) {
        sh[0] = sh[0] + sh[1] + sh[2] + sh[3];
        sh[4] = sh[4] + sh[5] + sh[6] + sh[7];
    }
    __syncthreads();
    float mean = sh[0] / width;
    float var  = sh[4] / width - mean * mean;
    float inv  = rsqrtf(var + 1e-5f);
    for (int i = 0; i < nw; ++i) {
        int c = threadIdx.x + (i << 8);
        float v = (vals[i] - mean) * inv * gamma[c] + beta[c];
        if (act == 1) v = fmaxf(v, 0.f);
        if (outb) outb[(size_t)row * width + c] = f2b(v);
        else      outf[(size_t)row * width + c] = v;
    }
}

// ---------------- sorted-batch mean pool ------------------------------------
__global__ __launch_bounds__(256) void pool_mean(
    const short* __restrict__ h, const int* __restrict__ batch,
    short* __restrict__ poolb)
{
    int b    = blockIdx.x * 4 + (threadIdx.x >> 6);
    int lane = threadIdx.x & 63;
    if (b >= BG) return;
    auto lbound = [&](int key) {
        int lo = 0, hi = NN;
        while (lo < hi) { int mid = (lo + hi) >> 1; if (batch[mid] < key) lo = mid + 1; else hi = mid; }
        return lo;
    };
    int lo = lbound(b), hi = lbound(b + 1);
    float acc[HEADS] = {0.f, 0.f, 0.f, 0.f};
    for (int r = lo; r < hi; ++r)
#pragma unroll
        for (int hh = 0; hh < HEADS; ++hh)
            acc[hh] += b2f(h[(size_t)r * HID + hh * 64 + lane]);
    float inv = 1.f / fmaxf((float)(hi - lo), 1.f);
#pragma unroll
    for (int hh = 0; hh < HEADS; ++hh)
        poolb[(size_t)b * HID + hh * 64 + lane] = f2b(acc[hh] * inv);
}

// ---------------------------------------------------------------------------
extern "C" void kernel_launch(void* const* d_in, const int* in_sizes, int n_in,
                              void* d_out, int out_size, void* d_ws, size_t ws_size,
                              hipStream_t stream)
{
    (void)in_sizes; (void)n_in; (void)out_size; (void)ws_size;
    const float* x      = (const float*)d_in[0];
    const int*   ei     = (const int*)d_in[1];
    const int*   batch  = (const int*)d_in[2];
    const float* lin0_w = (const float*)d_in[4];
    const float* lin0_b = (const float*)d_in[5];
    const float* r0_wih = (const float*)d_in[6];
    const float* r0_bih = (const float*)d_in[8];
    const float* r0_bhh = (const float*)d_in[9];
    const float* mh1_w  = (const float*)d_in[46];
    const float* mh1_b  = (const float*)d_in[47];
    const float* ln1_g  = (const float*)d_in[48];
    const float* ln1_b  = (const float*)d_in[49];
    const float* mh2_w  = (const float*)d_in[50];
    const float* mh2_b  = (const float*)d_in[51];
    const float* ln2_g  = (const float*)d_in[52];
    const float* ln2_b  = (const float*)d_in[53];
    float* out = (float*)d_out;

    // ---- workspace bump allocation ----
    char* wsb = (char*)d_ws;
    auto alloc = [&](size_t bytes) -> void* {
        void* p = (void*)wsb;
        wsb += (bytes + 255) & ~(size_t)255;
        return p;
    };
    const size_t NH = (size_t)MP * HID;
    float* cb   = (float*)alloc(NH * 4);          // LSTM cell state f32
    short* hA   = (short*)alloc(NH * 2);          // h ping
    short* hB   = (short*)alloc(NH * 2);          // h pong
    short* ybb  = (short*)alloc(NH * 2);          // LSTM-input / x0 bf16
    short* xlr  = (short*)alloc((size_t)MP * 512 * 2);  // [xl|xr] bf16
    int*   deg    = (int*)alloc((size_t)NN * 4);
    int*   rowptr = (int*)alloc((size_t)(NN + 1) * 4);
    int*   cursor = (int*)alloc((size_t)NN * 4);
    int*   esrc   = (int*)alloc((size_t)EP * 4);
    // weights bf16
    short* w_lin0 = (short*)alloc((size_t)256 * KP0 * 2);
    short* w_r0   = (short*)alloc((size_t)G4H * 256 * 2);
    short* w_lr[3]; short* w_ih[3]; short* w_hh[3]; float* blr[3];
    for (int l = 0; l < 3; ++l) {
        int Kp = (l == 0) ? KP0 : 256;
        w_lr[l] = (short*)alloc((size_t)512 * Kp * 2);
        w_ih[l] = (short*)alloc((size_t)G4H * 256 * 2);
        w_hh[l] = (short*)alloc((size_t)G4H * 256 * 2);
        blr[l]  = (float*)alloc(512 * 4);
    }
    short* w_m1 = (short*)alloc((size_t)NH1 * 256 * 2);
    short* w_m2 = (short*)alloc((size_t)NH2 * NH1 * 2);
    // xb (layer-0 padded input) with head temps aliased over it (head runs
    // only after xb is dead)
    short* xb = (short*)alloc((size_t)MP * KP0 * 2);   // 64 MB
    float* z1    = (float*)xb;                          // BG*NH1 f32 (8.4MB)
    short* z1b   = (short*)(z1 + (size_t)BG * NH1);     // BG*NH1 bf16
    short* poolb = z1b + (size_t)BG * NH1;              // BG*HID bf16

    auto conv = [&](const float* s, short* d, int rs, int rd, int Ks, int Kd) {
        conv_bf16<<<dim3(512), dim3(256), 0, stream>>>(s, d, rs, rd, Ks, Kd);
    };
    auto convg = [&](const float* s, short* d) {
        conv_gates<<<dim3(512), dim3(256), 0, stream>>>(s, d, 256);
    };
    // mode 0/1 GEMM; 1-D grid with XCD swizzle (requires (M/128)%8==0)
    auto G = [&](const short* A, const short* B, int K, const float* bias,
                 float* Cf, short* Cbb, int M, int N, int mode) {
        int nrp = M / 128, nct = N / 128;
        mfma_gemm<<<dim3(nrp * nct), dim3(256), 0, stream>>>(
            A, B, K, nullptr, nullptr, 0, bias,
            nullptr, nullptr, nullptr, nullptr, nullptr, Cf, Cbb, N, mode, nct);
    };
    // mode 2 LSTM GEMM
    auto GL = [&](const short* A1, const short* B1, int K1,
                  const short* A2, const short* B2, int K2,
                  const float* bih, const float* bhh,
                  const float* ci, float* co, short* ho) {
        mfma_gemm<<<dim3((MP / 128) * 8), dim3(256), 0, stream>>>(
            A1, B1, K1, A2, B2, K2, nullptr,
            bih, bhh, ci, co, ho, nullptr, nullptr, G4H, 2, 8);
    };

    // ---- conversions + CSR build ----
    conv(x, xb, NN, MP, FIN, KP0);
    conv(lin0_w, w_lin0, 256, 256, FIN, KP0);
    convg(r0_wih, w_r0);
    for (int l = 0; l < 3; ++l) {
        int base = 10 + 12 * l;
        int K  = (l == 0) ? FIN : 256;
        int Kp = (l == 0) ? KP0 : 256;
        conv((const float*)d_in[base + 0], w_lr[l], 256, 256, K, Kp);
        conv((const float*)d_in[base + 2], w_lr[l] + (size_t)256 * Kp, 256, 256, K, Kp);
        convg((const float*)d_in[base + 8], w_ih[l]);
        convg((const float*)d_in[base + 9], w_hh[l]);
        concat2_f32<<<dim3(2), dim3(256), 0, stream>>>(
            (const float*)d_in[base + 1], (const float*)d_in[base + 3], blr[l], 256, 256);
    }
    conv(mh1_w, w_m1, NH1, NH1, 256, 256);
    conv(mh2_w, w_m2, NH2, NH2, NH1, NH1);

    zero_f32<<<dim3(256), dim3(256), 0, stream>>>((float*)deg, NN);
    edge_hist<<<dim3((EP + 255) / 256), dim3(256), 0, stream>>>(ei, deg);
    scan_deg<<<dim3(1), dim3(1024), 0, stream>>>(deg, rowptr, cursor);
    edge_fill<<<dim3((EP + 255) / 256), dim3(256), 0, stream>>>(ei, rowptr, cursor, esrc);

    // ---- lin0 -> x0 (bf16); rnn0 LSTM from zero state (fused epilogue) ----
    G(xb, w_lin0, KP0, lin0_b, nullptr, ybb, MP, HID, 1);
    GL(ybb, w_r0, 256, nullptr, nullptr, 0, r0_bih, r0_bhh, nullptr, cb, hA);

    // ---- 3x (GATv2 -> LN+ELU -> LSTM) ----
    short* hprev = hA;
    short* hnext = hB;
    for (int l = 0; l < 3; ++l) {
        int base = 10 + 12 * l;
        const float* att = (const float*)d_in[base + 4];
        const float* gb  = (const float*)d_in[base + 5];
        const float* lg  = (const float*)d_in[base + 6];
        const float* lb  = (const float*)d_in[base + 7];
        const float* bih = (const float*)d_in[base + 10];
        const float* bhh = (const float*)d_in[base + 11];
        const short* Ain = (l == 0) ? xb : hprev;
        int K = (l == 0) ? KP0 : 256;

        G(Ain, w_lr[l], K, blr[l], nullptr, xlr, MP, 512, 1);
        gat_fused<<<dim3((NN + 3) / 4), dim3(256), 0, stream>>>(
            xlr, rowptr, esrc, att, gb, lg, lb, ybb);
        GL(ybb, w_ih[l], 256, hprev, w_hh[l], 256, bih, bhh, cb, cb, hnext);
        short* t = hprev; hprev = hnext; hnext = t;
    }

    // ---- mean pool (sorted batch) + MLP head ----
    pool_mean<<<dim3((BG + 3) / 4), dim3(256), 0, stream>>>(hprev, batch, poolb);
    G(poolb, w_m1, 256, mh1_b, z1, nullptr, BG, NH1, 0);
    ln_act_kernel<<<dim3(BG), dim3(256), 0, stream>>>(z1, ln1_g, ln1_b, nullptr, z1b, NH1, 1);
    G(z1b, w_m2, NH1, mh2_b, out, nullptr, BG, NH2, 0);
    ln_act_kernel<<<dim3(BG), dim3(256), 0, stream>>>(out, ln2_g, ln2_b, out, nullptr, NH2, 0);
}

// Round 13
// 2106.072 us; speedup vs baseline: 1.3516x; 1.0301x over previous
//
#include <hip/hip_runtime.h>
#include <hip/hip_bf16.h>
#include <math.h>

// ---------------------------------------------------------------------------
// GraphEncoder round 13: BM=256 x BN=128 tile (8 waves, 512 threads), halving
// block count per GEMM dispatch. Round-12 evidence: xlr GEMM (26 GFLOP) and
// LSTM GEMM (105 GFLOP) both take ~287us -> per-block fixed cost dominates,
// so amortize it over 2x rows/block. LDS dbuf 48KB -> 3 blocks/CU (24 waves).
// Also: mode-2 c_in prefetched into regs before the K-loop.
// Counted-vmcnt loop kept (3 loads/stage -> vmcnt(3) mid-loop).
// ---------------------------------------------------------------------------

constexpr int NN    = 100000;
constexpr int EE    = 400000;
constexpr int EP    = EE + NN;      // 500000 (incl self loops)
constexpr int BG    = 4096;
constexpr int FIN   = 300;
constexpr int HEADS = 4;
constexpr int HID   = 256;
constexpr int G4H   = 1024;
constexpr int NH1   = 512;
constexpr int NH2   = 768;
constexpr int MP    = 100352;       // 392*256, 392 % 8 == 0
constexpr int KP0   = 320;          // FIN padded to mult of 32

typedef __attribute__((ext_vector_type(4))) float f32x4;
typedef __attribute__((ext_vector_type(8))) short s16x8;

#define LOG2E 1.4426950408889634f

// fast HW transcendentals (v_exp_f32 = 2^x, v_rcp_f32)
__device__ inline float fexp(float x)  { return __builtin_amdgcn_exp2f(x * LOG2E); }
__device__ inline float frcp(float x)  { return __builtin_amdgcn_rcpf(x); }
__device__ inline float fsigm(float x) { return frcp(1.f + __builtin_amdgcn_exp2f(-LOG2E * x)); }
__device__ inline float ftanh(float x) { return 1.f - 2.f * frcp(1.f + __builtin_amdgcn_exp2f(2.f * LOG2E * x)); }

__device__ inline float b2f(short s) { return __uint_as_float(((unsigned)(unsigned short)s) << 16); }
__device__ inline short f2b(float f) {
    unsigned u = __float_as_uint(f);
    u += 0x7fff + ((u >> 16) & 1);          // round-to-nearest-even
    return (short)(u >> 16);
}
__device__ inline float wsum64(float v) {
#pragma unroll
    for (int o = 32; o > 0; o >>= 1) v += __shfl_xor(v, o);
    return v;
}

// ---------------- utility kernels -------------------------------------------
__global__ __launch_bounds__(256) void zero_f32(float* __restrict__ p, long long n)
{
    long long i = (long long)blockIdx.x * 256 + threadIdx.x;
    long long stride = (long long)gridDim.x * 256;
    for (; i < n; i += stride) p[i] = 0.f;
}

// f32 -> bf16 with row/col zero padding
__global__ __launch_bounds__(256) void conv_bf16(
    const float* __restrict__ src, short* __restrict__ dst,
    int rsrc, int rdst, int Ks, int Kd)
{
    long long n = (long long)rdst * Kd;
    long long stride = (long long)gridDim.x * 256;
    for (long long i = (long long)blockIdx.x * 256 + threadIdx.x; i < n; i += stride) {
        int r = (int)(i / Kd);
        int k = (int)(i - (long long)r * Kd);
        float v = (r < rsrc && k < Ks) ? src[(long long)r * Ks + k] : 0.f;
        dst[i] = f2b(v);
    }
}

// gate-interleaved pack of LSTM weight [1024][K]:
// new row p -> orig row gate*256+ch, gate=(p>>4)&3, ch=(p>>7)*32+((p>>6)&1)*16+(p&15)
__global__ __launch_bounds__(256) void conv_gates(
    const float* __restrict__ src, short* __restrict__ dst, int K)
{
    long long n = (long long)G4H * K;
    long long stride = (long long)gridDim.x * 256;
    for (long long i = (long long)blockIdx.x * 256 + threadIdx.x; i < n; i += stride) {
        int p = (int)(i / K);
        int k = (int)(i - (long long)p * K);
        int gate = (p >> 4) & 3;
        int ch   = (p >> 7) * 32 + ((p >> 6) & 1) * 16 + (p & 15);
        dst[i] = f2b(src[(size_t)(gate * 256 + ch) * K + k]);
    }
}

__global__ __launch_bounds__(256) void concat2_f32(
    const float* __restrict__ a, const float* __restrict__ b,
    float* __restrict__ dst, int na, int nb)
{
    int i = blockIdx.x * 256 + threadIdx.x;
    if (i < na) dst[i] = a[i];
    else if (i < na + nb) dst[i] = b[i - na];
}

// ---------------- CSR build -------------------------------------------------
__global__ __launch_bounds__(256) void edge_hist(const int* __restrict__ ei,
                                                 int* __restrict__ deg)
{
    int e = blockIdx.x * 256 + threadIdx.x;
    if (e >= EP) return;
    int d = (e < EE) ? ei[EE + e] : e - EE;
    atomicAdd(&deg[d], 1);
}

__global__ __launch_bounds__(1024) void scan_deg(const int* __restrict__ deg,
                                                 int* __restrict__ rowptr,
                                                 int* __restrict__ cursor)
{
    __shared__ int part[1024];
    int t = threadIdx.x;
    const int CH = (NN + 1023) / 1024;
    int lo = t * CH, hi = min(lo + CH, NN);
    int s = 0;
    for (int i = lo; i < hi; ++i) s += deg[i];
    part[t] = s;
    __syncthreads();
    for (int off = 1; off < 1024; off <<= 1) {
        int v = (t >= off) ? part[t - off] : 0;
        __syncthreads();
        part[t] += v;
        __syncthreads();
    }
    int run = (t == 0) ? 0 : part[t - 1];
    for (int i = lo; i < hi; ++i) { rowptr[i] = run; cursor[i] = 0; run += deg[i]; }
    if (t == 1023) rowptr[NN] = run;   // == EP
}

__global__ __launch_bounds__(256) void edge_fill(const int* __restrict__ ei,
                                                 const int* __restrict__ rowptr,
                                                 int* __restrict__ cursor,
                                                 int* __restrict__ esrc)
{
    int e = blockIdx.x * 256 + threadIdx.x;
    if (e >= EP) return;
    int s, d;
    if (e < EE) { s = ei[e]; d = ei[EE + e]; }
    else        { s = d = e - EE; }
    int slot = rowptr[d] + atomicAdd(&cursor[d], 1);
    esrc[slot] = s;
}

// ---------------- MFMA GEMM with fused epilogues ----------------------------
// C[M x N] = A1[M x K1] @ B1[N x K1]^T (+ A2[M x K2] @ B2[N x K2]^T)
// BM=256 x BN=128 tile; 8 waves (512 thr) as 4x2 of 64x64.
// 1-D grid of (M/256)*(N/128) blocks; XCD swizzle: xcd=bid&7, slot=bid>>3,
// g=slot/nct, ct=slot%nct, row_panel=g*8+xcd. Requires (M/256)%8==0.
// Counted-vmcnt double-buffer: 3 loads/stage; vmcnt(3) mid-loop.
// mode 0: +bias -> f32 Cf      mode 1: +bias -> bf16 Cb
// mode 2: LSTM epilogue (gate-interleaved B; N=1024): reads c_in (or 0,
//         prefetched to regs pre-K-loop), writes c_out f32 + h_out bf16.
__global__ __launch_bounds__(512) void mfma_gemm(
    const short* __restrict__ A1, const short* __restrict__ B1, int K1,
    const short* __restrict__ A2, const short* __restrict__ B2, int K2,
    const float* __restrict__ bias,
    const float* __restrict__ bih, const float* __restrict__ bhh,
    const float* __restrict__ c_in, float* __restrict__ c_out,
    short* __restrict__ h_out,
    float* __restrict__ Cf, short* __restrict__ Cb, int N, int mode, int nct)
{
    __shared__ __align__(16) short sA[2][256 * 32];   // 16KB each
    __shared__ __align__(16) short sB[2][128 * 32];   // 8KB each
    const int tid  = threadIdx.x;
    const int w    = tid >> 6, lane = tid & 63;
    const int wr   = w >> 1,  wc   = w & 1;      // 4x2 waves of 64x64
    // XCD-aware decode (consecutive bids round-robin across 8 XCDs)
    const int bid  = blockIdx.x;
    const int xcd  = bid & 7;
    const int slot = bid >> 3;
    const int g    = slot / nct;
    const int tcol = slot - g * nct;
    const int row0 = (g * 8 + xcd) * 256;
    const int col0 = tcol * 128;

    f32x4 acc[4][4];
#pragma unroll
    for (int m = 0; m < 4; ++m)
#pragma unroll
        for (int n = 0; n < 4; ++n) acc[m][n] = (f32x4){0.f, 0.f, 0.f, 0.f};

    const int rs = lane >> 2;
    const int cs = lane & 3;
    const int KK = K1 + K2;
    const int l16 = lane & 15;
    const int rloc = wr * 64 + ((lane >> 4) << 2);   // block-local base row

    // mode-2: prefetch c_in into regs; latency hides under the K-loop
    float co_pre[4][4] = {};
    const int ch = tcol * 32 + wc * 16 + l16;        // mode-2 channel
    if (mode == 2 && c_in) {
#pragma unroll
        for (int m = 0; m < 4; ++m)
#pragma unroll
            for (int r = 0; r < 4; ++r)
                co_pre[m][r] = c_in[(size_t)(row0 + rloc + m * 16 + r) * HID + ch];
    }

    // 3 global_load_lds per wave per stage call (2x A-seg, 1x B-seg)
    auto stage = [&](int buf, int k0) {
        const short* Ak; const short* Bk; int kk, ld;
        if (k0 < K1) { Ak = A1; Bk = B1; kk = k0;      ld = K1; }
        else         { Ak = A2; Bk = B2; kk = k0 - K1; ld = K2; }
#pragma unroll
        for (int i = 0; i < 2; ++i) {
            int seg = w * 2 + i;                     // 16 A-segs of 16 rows
            int row = seg * 16 + rs;
            int c8  = cs ^ ((row + (row >> 2)) & 3);
            const short* ga = Ak + (size_t)(row0 + row) * ld + kk + c8 * 8;
            short* la = &sA[buf][seg * 512 + lane * 8];
            __builtin_amdgcn_global_load_lds((const __attribute__((address_space(1))) void*)ga,
                                             (__attribute__((address_space(3))) void*)la, 16, 0, 0);
        }
        {
            int row = w * 16 + rs;                   // 8 B-segs of 16 rows
            int c8  = cs ^ ((row + (row >> 2)) & 3);
            const short* gb = Bk + (size_t)(col0 + row) * ld + kk + c8 * 8;
            short* lb = &sB[buf][w * 512 + lane * 8];
            __builtin_amdgcn_global_load_lds((const __attribute__((address_space(1))) void*)gb,
                                             (__attribute__((address_space(3))) void*)lb, 16, 0, 0);
        }
    };

    stage(0, 0);
    stage(1, 32);                  // KK >= 64 guaranteed by call sites
    int cur = 0;
    for (int k0 = 0; k0 < KK; k0 += 32) {
        if (k0 + 32 < KK) asm volatile("s_waitcnt vmcnt(3)" ::: "memory");
        else              asm volatile("s_waitcnt vmcnt(0)" ::: "memory");
        __builtin_amdgcn_s_barrier();          // all waves: buf[cur] ready
        asm volatile("" ::: "memory");

        s16x8 af[4], bg[4];
        {
            const int rl = lane & 15;
            const int cw = lane >> 4;
#pragma unroll
            for (int m = 0; m < 4; ++m) {
                int r  = wr * 64 + m * 16 + rl;
                int sl = cw ^ ((r + (r >> 2)) & 3);
                af[m] = *(const s16x8*)(&sA[cur][r * 32 + sl * 8]);
                int c  = wc * 64 + m * 16 + rl;
                int sc = cw ^ ((c + (c >> 2)) & 3);
                bg[m] = *(const s16x8*)(&sB[cur][c * 32 + sc * 8]);
            }
        }
        asm volatile("s_waitcnt lgkmcnt(0)" ::: "memory");
        __builtin_amdgcn_s_barrier();
        asm volatile("" ::: "memory");
        if (k0 + 64 < KK) stage(cur, k0 + 64);   // re-stage 2 steps ahead

#pragma unroll
        for (int m = 0; m < 4; ++m)
#pragma unroll
            for (int n = 0; n < 4; ++n)
                acc[m][n] = __builtin_amdgcn_mfma_f32_16x16x32_bf16(af[m], bg[n], acc[m][n], 0, 0, 0);
        cur ^= 1;
    }

    // C/D layout: col=lane&15, row=(lane>>4)*4+reg
    const int rbase = row0 + rloc;
    if (mode == 2) {
        float bi[4];
#pragma unroll
        for (int gg2 = 0; gg2 < 4; ++gg2) bi[gg2] = bih[gg2 * 256 + ch] + bhh[gg2 * 256 + ch];
#pragma unroll
        for (int m = 0; m < 4; ++m) {
#pragma unroll
            for (int r = 0; r < 4; ++r) {
                int row = rbase + m * 16 + r;
                float gi = acc[m][0][r] + bi[0];
                float gf = acc[m][1][r] + bi[1];
                float gg = acc[m][2][r] + bi[2];
                float go = acc[m][3][r] + bi[3];
                size_t idx = (size_t)row * HID + ch;
                float c2 = fsigm(gf) * co_pre[m][r] + fsigm(gi) * ftanh(gg);
                float h2 = fsigm(go) * ftanh(c2);
                c_out[idx] = c2;
                h_out[idx] = f2b(h2);
            }
        }
    } else {
        const int cbase = col0 + wc * 64 + l16;
#pragma unroll
        for (int n = 0; n < 4; ++n) {
            int col = cbase + n * 16;
            float ba = bias ? bias[col] : 0.f;
#pragma unroll
            for (int m = 0; m < 4; ++m) {
#pragma unroll
                for (int r = 0; r < 4; ++r) {
                    int row = rbase + m * 16 + r;
                    float v = acc[m][n][r] + ba;
                    size_t idx = (size_t)row * N + col;
                    if (mode == 1) Cb[idx] = f2b(v);
                    else           Cf[idx] = v;
                }
            }
        }
    }
}

// ---------------- fused GATv2 (softmax + aggregate + bias + LN + ELU) -------
// one 64-lane wave per dst node; lane l = channel h*64+l per head h.
// xlr: [MP][512] bf16, cols 0..255 = lin_l(x), 256..511 = lin_r(x).
__global__ __launch_bounds__(256) void gat_fused(
    const short* __restrict__ xlr, const int* __restrict__ rowptr,
    const int* __restrict__ esrc, const float* __restrict__ att,
    const float* __restrict__ gb, const float* __restrict__ lg,
    const float* __restrict__ lb, short* __restrict__ outb)
{
    int i    = blockIdx.x * 4 + (threadIdx.x >> 6);
    int lane = threadIdx.x & 63;
    if (i >= NN) return;
    float xr[HEADS], at[HEADS];
#pragma unroll
    for (int h = 0; h < HEADS; ++h) {
        xr[h] = b2f(xlr[(size_t)i * 512 + 256 + h * 64 + lane]);
        at[h] = att[h * 64 + lane];
    }
    float mx[HEADS], sm[HEADS], ac[HEADS];
#pragma unroll
    for (int h = 0; h < HEADS; ++h) { mx[h] = -INFINITY; sm[h] = 0.f; ac[h] = 0.f; }

    int lo = rowptr[i], hi = rowptr[i + 1];
    for (int e = lo; e < hi; ++e) {
        int s = esrc[e];
        float xs[HEADS], p[HEADS];
#pragma unroll
        for (int h = 0; h < HEADS; ++h) {
            xs[h] = b2f(xlr[(size_t)s * 512 + h * 64 + lane]);
            float v = xs[h] + xr[h];
            v = (v >= 0.f) ? v : 0.2f * v;
            p[h] = v * at[h];
        }
#pragma unroll
        for (int h = 0; h < HEADS; ++h) p[h] = wsum64(p[h]);
#pragma unroll
        for (int h = 0; h < HEADS; ++h) {
            float mn = fmaxf(mx[h], p[h]);
            float sc = fexp(mx[h] - mn);     // first iter: exp(-inf)=0
            float a  = fexp(p[h] - mn);
            sm[h] = sm[h] * sc + a;
            ac[h] = ac[h] * sc + a * xs[h];
            mx[h] = mn;
        }
    }
    // y = ac/sm (+ gat bias), then LayerNorm(256) + ELU, write bf16
    float val[HEADS], s1 = 0.f, s2 = 0.f;
#pragma unroll
    for (int h = 0; h < HEADS; ++h) {
        float v = ac[h] * frcp(sm[h]) + gb[h * 64 + lane];
        val[h] = v; s1 += v; s2 += v * v;
    }
    s1 = wsum64(s1); s2 = wsum64(s2);
    float mean = s1 * (1.f / 256.f);
    float var  = s2 * (1.f / 256.f) - mean * mean;
    float inv  = rsqrtf(var + 1e-5f);
#pragma unroll
    for (int h = 0; h < HEADS; ++h) {
        float v = (val[h] - mean) * inv * lg[h * 64 + lane] + lb[h * 64 + lane];
        v = (v > 0.f) ? v : (fexp(v) - 1.f);
        outb[(size_t)i * HID + h * 64 + lane] = f2b(v);
    }
}

// ---------------- LayerNorm (+act) for the MLP head -------------------------
__global__ __launch_bounds__(256) void ln_act_kernel(
    const float* __restrict__ in, const float* __restrict__ gamma,
    const float* __restrict__ beta, float* __restrict__ outf,
    short* __restrict__ outb, int width, int act)
{
    int row = blockIdx.x;
    const float* ip = in + (size_t)row * width;
    float vals[3];
    float s = 0.f, ss = 0.f;
    int nw = width >> 8;
    for (int i = 0; i < nw; ++i) {
        int c = threadIdx.x + (i << 8);
        float v = ip[c];
        vals[i] = v; s += v; ss += v * v;
    }
#pragma unroll
    for (int off = 32; off > 0; off >>= 1) {
        s  += __shfl_down(s, off);
        ss += __shfl_down(ss, off);
    }
    __shared__ float sh[8];
    int wv = threadIdx.x >> 6, lane = threadIdx.x & 63;
    if (lane == 0) { sh[wv] = s; sh[4 + wv] = ss; }
    __syncthreads();
    if (threadIdx.x == 0) {
        sh[0] = sh[0] + sh[1] + sh[2] + sh[3];
        sh[4] = sh[4] + sh[5] + sh[6] + sh[7];
    }
    __syncthreads();
    float mean = sh[0] / width;
    float var  = sh[4] / width - mean * mean;
    float inv  = rsqrtf(var + 1e-5f);
    for (int i = 0; i < nw; ++i) {
        int c = threadIdx.x + (i << 8);
        float v = (vals[i] - mean) * inv * gamma[c] + beta[c];
        if (act == 1) v = fmaxf(v, 0.f);
        if (outb) outb[(size_t)row * width + c] = f2b(v);
        else      outf[(size_t)row * width + c] = v;
    }
}

// ---------------- sorted-batch mean pool ------------------------------------
__global__ __launch_bounds__(256) void pool_mean(
    const short* __restrict__ h, const int* __restrict__ batch,
    short* __restrict__ poolb)
{
    int b    = blockIdx.x * 4 + (threadIdx.x >> 6);
    int lane = threadIdx.x & 63;
    if (b >= BG) return;
    auto lbound = [&](int key) {
        int lo = 0, hi = NN;
        while (lo < hi) { int mid = (lo + hi) >> 1; if (batch[mid] < key) lo = mid + 1; else hi = mid; }
        return lo;
    };
    int lo = lbound(b), hi = lbound(b + 1);
    float acc[HEADS] = {0.f, 0.f, 0.f, 0.f};
    for (int r = lo; r < hi; ++r)
#pragma unroll
        for (int hh = 0; hh < HEADS; ++hh)
            acc[hh] += b2f(h[(size_t)r * HID + hh * 64 + lane]);
    float inv = 1.f / fmaxf((float)(hi - lo), 1.f);
#pragma unroll
    for (int hh = 0; hh < HEADS; ++hh)
        poolb[(size_t)b * HID + hh * 64 + lane] = f2b(acc[hh] * inv);
}

// ---------------------------------------------------------------------------
extern "C" void kernel_launch(void* const* d_in, const int* in_sizes, int n_in,
                              void* d_out, int out_size, void* d_ws, size_t ws_size,
                              hipStream_t stream)
{
    (void)in_sizes; (void)n_in; (void)out_size; (void)ws_size;
    const float* x      = (const float*)d_in[0];
    const int*   ei     = (const int*)d_in[1];
    const int*   batch  = (const int*)d_in[2];
    const float* lin0_w = (const float*)d_in[4];
    const float* lin0_b = (const float*)d_in[5];
    const float* r0_wih = (const float*)d_in[6];
    const float* r0_bih = (const float*)d_in[8];
    const float* r0_bhh = (const float*)d_in[9];
    const float* mh1_w  = (const float*)d_in[46];
    const float* mh1_b  = (const float*)d_in[47];
    const float* ln1_g  = (const float*)d_in[48];
    const float* ln1_b  = (const float*)d_in[49];
    const float* mh2_w  = (const float*)d_in[50];
    const float* mh2_b  = (const float*)d_in[51];
    const float* ln2_g  = (const float*)d_in[52];
    const float* ln2_b  = (const float*)d_in[53];
    float* out = (float*)d_out;

    // ---- workspace bump allocation ----
    char* wsb = (char*)d_ws;
    auto alloc = [&](size_t bytes) -> void* {
        void* p = (void*)wsb;
        wsb += (bytes + 255) & ~(size_t)255;
        return p;
    };
    const size_t NH = (size_t)MP * HID;
    float* cb   = (float*)alloc(NH * 4);          // LSTM cell state f32
    short* hA   = (short*)alloc(NH * 2);          // h ping
    short* hB   = (short*)alloc(NH * 2);          // h pong
    short* ybb  = (short*)alloc(NH * 2);          // LSTM-input / x0 bf16
    short* xlr  = (short*)alloc((size_t)MP * 512 * 2);  // [xl|xr] bf16
    int*   deg    = (int*)alloc((size_t)NN * 4);
    int*   rowptr = (int*)alloc((size_t)(NN + 1) * 4);
    int*   cursor = (int*)alloc((size_t)NN * 4);
    int*   esrc   = (int*)alloc((size_t)EP * 4);
    // weights bf16
    short* w_lin0 = (short*)alloc((size_t)256 * KP0 * 2);
    short* w_r0   = (short*)alloc((size_t)G4H * 256 * 2);
    short* w_lr[3]; short* w_ih[3]; short* w_hh[3]; float* blr[3];
    for (int l = 0; l < 3; ++l) {
        int Kp = (l == 0) ? KP0 : 256;
        w_lr[l] = (short*)alloc((size_t)512 * Kp * 2);
        w_ih[l] = (short*)alloc((size_t)G4H * 256 * 2);
        w_hh[l] = (short*)alloc((size_t)G4H * 256 * 2);
        blr[l]  = (float*)alloc(512 * 4);
    }
    short* w_m1 = (short*)alloc((size_t)NH1 * 256 * 2);
    short* w_m2 = (short*)alloc((size_t)NH2 * NH1 * 2);
    // xb (layer-0 padded input) with head temps aliased over it (head runs
    // only after xb is dead)
    short* xb = (short*)alloc((size_t)MP * KP0 * 2);   // 64 MB
    float* z1    = (float*)xb;                          // BG*NH1 f32 (8.4MB)
    short* z1b   = (short*)(z1 + (size_t)BG * NH1);     // BG*NH1 bf16
    short* poolb = z1b + (size_t)BG * NH1;              // BG*HID bf16

    auto conv = [&](const float* s, short* d, int rs, int rd, int Ks, int Kd) {
        conv_bf16<<<dim3(512), dim3(256), 0, stream>>>(s, d, rs, rd, Ks, Kd);
    };
    auto convg = [&](const float* s, short* d) {
        conv_gates<<<dim3(512), dim3(256), 0, stream>>>(s, d, 256);
    };
    // mode 0/1 GEMM; 1-D grid with XCD swizzle (requires (M/256)%8==0)
    auto G = [&](const short* A, const short* B, int K, const float* bias,
                 float* Cf, short* Cbb, int M, int N, int mode) {
        int nrp = M / 256, nct = N / 128;
        mfma_gemm<<<dim3(nrp * nct), dim3(512), 0, stream>>>(
            A, B, K, nullptr, nullptr, 0, bias,
            nullptr, nullptr, nullptr, nullptr, nullptr, Cf, Cbb, N, mode, nct);
    };
    // mode 2 LSTM GEMM
    auto GL = [&](const short* A1, const short* B1, int K1,
                  const short* A2, const short* B2, int K2,
                  const float* bih, const float* bhh,
                  const float* ci, float* co, short* ho) {
        mfma_gemm<<<dim3((MP / 256) * 8), dim3(512), 0, stream>>>(
            A1, B1, K1, A2, B2, K2, nullptr,
            bih, bhh, ci, co, ho, nullptr, nullptr, G4H, 2, 8);
    };

    // ---- conversions + CSR build ----
    conv(x, xb, NN, MP, FIN, KP0);
    conv(lin0_w, w_lin0, 256, 256, FIN, KP0);
    convg(r0_wih, w_r0);
    for (int l = 0; l < 3; ++l) {
        int base = 10 + 12 * l;
        int K  = (l == 0) ? FIN : 256;
        int Kp = (l == 0) ? KP0 : 256;
        conv((const float*)d_in[base + 0], w_lr[l], 256, 256, K, Kp);
        conv((const float*)d_in[base + 2], w_lr[l] + (size_t)256 * Kp, 256, 256, K, Kp);
        convg((const float*)d_in[base + 8], w_ih[l]);
        convg((const float*)d_in[base + 9], w_hh[l]);
        concat2_f32<<<dim3(2), dim3(256), 0, stream>>>(
            (const float*)d_in[base + 1], (const float*)d_in[base + 3], blr[l], 256, 256);
    }
    conv(mh1_w, w_m1, NH1, NH1, 256, 256);
    conv(mh2_w, w_m2, NH2, NH2, NH1, NH1);

    zero_f32<<<dim3(256), dim3(256), 0, stream>>>((float*)deg, NN);
    edge_hist<<<dim3((EP + 255) / 256), dim3(256), 0, stream>>>(ei, deg);
    scan_deg<<<dim3(1), dim3(1024), 0, stream>>>(deg, rowptr, cursor);
    edge_fill<<<dim3((EP + 255) / 256), dim3(256), 0, stream>>>(ei, rowptr, cursor, esrc);

    // ---- lin0 -> x0 (bf16); rnn0 LSTM from zero state (fused epilogue) ----
    G(xb, w_lin0, KP0, lin0_b, nullptr, ybb, MP, HID, 1);
    GL(ybb, w_r0, 256, nullptr, nullptr, 0, r0_bih, r0_bhh, nullptr, cb, hA);

    // ---- 3x (GATv2 -> LN+ELU -> LSTM) ----
    short* hprev = hA;
    short* hnext = hB;
    for (int l = 0; l < 3; ++l) {
        int base = 10 + 12 * l;
        const float* att = (const float*)d_in[base + 4];
        const float* gb  = (const float*)d_in[base + 5];
        const float* lg  = (const float*)d_in[base + 6];
        const float* lb  = (const float*)d_in[base + 7];
        const float* bih = (const float*)d_in[base + 10];
        const float* bhh = (const float*)d_in[base + 11];
        const short* Ain = (l == 0) ? xb : hprev;
        int K = (l == 0) ? KP0 : 256;

        G(Ain, w_lr[l], K, blr[l], nullptr, xlr, MP, 512, 1);
        gat_fused<<<dim3((NN + 3) / 4), dim3(256), 0, stream>>>(
            xlr, rowptr, esrc, att, gb, lg, lb, ybb);
        GL(ybb, w_ih[l], 256, hprev, w_hh[l], 256, bih, bhh, cb, cb, hnext);
        short* t = hprev; hprev = hnext; hnext = t;
    }

    // ---- mean pool (sorted batch) + MLP head ----
    pool_mean<<<dim3((BG + 3) / 4), dim3(256), 0, stream>>>(hprev, batch, poolb);
    G(poolb, w_m1, 256, mh1_b, z1, nullptr, BG, NH1, 0);
    ln_act_kernel<<<dim3(BG), dim3(256), 0, stream>>>(z1, ln1_g, ln1_b, nullptr, z1b, NH1, 1);
    G(z1b, w_m2, NH1, mh2_b, out, nullptr, BG, NH2, 0);
    ln_act_kernel<<<dim3(BG), dim3(256), 0, stream>>>(out, ln2_g, ln2_b, out, nullptr, NH2, 0);
}

// Round 14
// 1819.907 us; speedup vs baseline: 1.5641x; 1.1572x over previous
//
#include <hip/hip_runtime.h>
#include <hip/hip_bf16.h>
#include <math.h>

// ---------------------------------------------------------------------------
// GraphEncoder round 14: 3-buffer / depth-3 prefetch pipeline in mfma_gemm.
// Round-13 diagnosis: all pipes <25%; L3 load latency (~500cyc) > the ~400cyc
// cover of depth-2 prefetch, and the explicit lgkmcnt(0)+barrier BETWEEN
// ds_reads and MFMAs blocked the compiler's fine-grained interleave.
// Fixes: (1) stage t+3 into a 3-slot LDS rotation (72KB, 2 blocks/CU),
// vmcnt(6) mid-loop; (2) barrier moved AFTER the MFMAs (reads are plain C++
// loads -> compiler emits fine lgkmcnt interleave; MFMA consumption implies
// read completion before the barrier).
// ---------------------------------------------------------------------------

constexpr int NN    = 100000;
constexpr int EE    = 400000;
constexpr int EP    = EE + NN;      // 500000 (incl self loops)
constexpr int BG    = 4096;
constexpr int FIN   = 300;
constexpr int HEADS = 4;
constexpr int HID   = 256;
constexpr int G4H   = 1024;
constexpr int NH1   = 512;
constexpr int NH2   = 768;
constexpr int MP    = 100352;       // 392*256, 392 % 8 == 0
constexpr int KP0   = 320;          // FIN padded to mult of 32

typedef __attribute__((ext_vector_type(4))) float f32x4;
typedef __attribute__((ext_vector_type(8))) short s16x8;

#define LOG2E 1.4426950408889634f

// fast HW transcendentals (v_exp_f32 = 2^x, v_rcp_f32)
__device__ inline float fexp(float x)  { return __builtin_amdgcn_exp2f(x * LOG2E); }
__device__ inline float frcp(float x)  { return __builtin_amdgcn_rcpf(x); }
__device__ inline float fsigm(float x) { return frcp(1.f + __builtin_amdgcn_exp2f(-LOG2E * x)); }
__device__ inline float ftanh(float x) { return 1.f - 2.f * frcp(1.f + __builtin_amdgcn_exp2f(2.f * LOG2E * x)); }

__device__ inline float b2f(short s) { return __uint_as_float(((unsigned)(unsigned short)s) << 16); }
__device__ inline short f2b(float f) {
    unsigned u = __float_as_uint(f);
    u += 0x7fff + ((u >> 16) & 1);          // round-to-nearest-even
    return (short)(u >> 16);
}
__device__ inline float wsum64(float v) {
#pragma unroll
    for (int o = 32; o > 0; o >>= 1) v += __shfl_xor(v, o);
    return v;
}

// ---------------- utility kernels -------------------------------------------
__global__ __launch_bounds__(256) void zero_f32(float* __restrict__ p, long long n)
{
    long long i = (long long)blockIdx.x * 256 + threadIdx.x;
    long long stride = (long long)gridDim.x * 256;
    for (; i < n; i += stride) p[i] = 0.f;
}

// f32 -> bf16 with row/col zero padding
__global__ __launch_bounds__(256) void conv_bf16(
    const float* __restrict__ src, short* __restrict__ dst,
    int rsrc, int rdst, int Ks, int Kd)
{
    long long n = (long long)rdst * Kd;
    long long stride = (long long)gridDim.x * 256;
    for (long long i = (long long)blockIdx.x * 256 + threadIdx.x; i < n; i += stride) {
        int r = (int)(i / Kd);
        int k = (int)(i - (long long)r * Kd);
        float v = (r < rsrc && k < Ks) ? src[(long long)r * Ks + k] : 0.f;
        dst[i] = f2b(v);
    }
}

// gate-interleaved pack of LSTM weight [1024][K]:
// new row p -> orig row gate*256+ch, gate=(p>>4)&3, ch=(p>>7)*32+((p>>6)&1)*16+(p&15)
__global__ __launch_bounds__(256) void conv_gates(
    const float* __restrict__ src, short* __restrict__ dst, int K)
{
    long long n = (long long)G4H * K;
    long long stride = (long long)gridDim.x * 256;
    for (long long i = (long long)blockIdx.x * 256 + threadIdx.x; i < n; i += stride) {
        int p = (int)(i / K);
        int k = (int)(i - (long long)p * K);
        int gate = (p >> 4) & 3;
        int ch   = (p >> 7) * 32 + ((p >> 6) & 1) * 16 + (p & 15);
        dst[i] = f2b(src[(size_t)(gate * 256 + ch) * K + k]);
    }
}

__global__ __launch_bounds__(256) void concat2_f32(
    const float* __restrict__ a, const float* __restrict__ b,
    float* __restrict__ dst, int na, int nb)
{
    int i = blockIdx.x * 256 + threadIdx.x;
    if (i < na) dst[i] = a[i];
    else if (i < na + nb) dst[i] = b[i - na];
}

// ---------------- CSR build -------------------------------------------------
__global__ __launch_bounds__(256) void edge_hist(const int* __restrict__ ei,
                                                 int* __restrict__ deg)
{
    int e = blockIdx.x * 256 + threadIdx.x;
    if (e >= EP) return;
    int d = (e < EE) ? ei[EE + e] : e - EE;
    atomicAdd(&deg[d], 1);
}

__global__ __launch_bounds__(1024) void scan_deg(const int* __restrict__ deg,
                                                 int* __restrict__ rowptr,
                                                 int* __restrict__ cursor)
{
    __shared__ int part[1024];
    int t = threadIdx.x;
    const int CH = (NN + 1023) / 1024;
    int lo = t * CH, hi = min(lo + CH, NN);
    int s = 0;
    for (int i = lo; i < hi; ++i) s += deg[i];
    part[t] = s;
    __syncthreads();
    for (int off = 1; off < 1024; off <<= 1) {
        int v = (t >= off) ? part[t - off] : 0;
        __syncthreads();
        part[t] += v;
        __syncthreads();
    }
    int run = (t == 0) ? 0 : part[t - 1];
    for (int i = lo; i < hi; ++i) { rowptr[i] = run; cursor[i] = 0; run += deg[i]; }
    if (t == 1023) rowptr[NN] = run;   // == EP
}

__global__ __launch_bounds__(256) void edge_fill(const int* __restrict__ ei,
                                                 const int* __restrict__ rowptr,
                                                 int* __restrict__ cursor,
                                                 int* __restrict__ esrc)
{
    int e = blockIdx.x * 256 + threadIdx.x;
    if (e >= EP) return;
    int s, d;
    if (e < EE) { s = ei[e]; d = ei[EE + e]; }
    else        { s = d = e - EE; }
    int slot = rowptr[d] + atomicAdd(&cursor[d], 1);
    esrc[slot] = s;
}

// ---------------- MFMA GEMM with fused epilogues ----------------------------
// C[M x N] = A1[M x K1] @ B1[N x K1]^T (+ A2[M x K2] @ B2[N x K2]^T)
// BM=256 x BN=128 tile; 8 waves (512 thr) as 4x2 of 64x64.
// 1-D grid of (M/256)*(N/128) blocks; XCD swizzle: xcd=bid&7, slot=bid>>3,
// g=slot/nct, ct=slot%nct, row_panel=g*8+xcd. Requires (M/256)%8==0.
// 3-buffer rotation, depth-3 prefetch, counted vmcnt (6/3/0 tail).
// Requires KK >= 96 (all call sites have KK >= 256).
// mode 0: +bias -> f32 Cf      mode 1: +bias -> bf16 Cb
// mode 2: LSTM epilogue (gate-interleaved B; N=1024): reads c_in (or 0,
//         prefetched to regs pre-K-loop), writes c_out f32 + h_out bf16.
__global__ __launch_bounds__(512) void mfma_gemm(
    const short* __restrict__ A1, const short* __restrict__ B1, int K1,
    const short* __restrict__ A2, const short* __restrict__ B2, int K2,
    const float* __restrict__ bias,
    const float* __restrict__ bih, const float* __restrict__ bhh,
    const float* __restrict__ c_in, float* __restrict__ c_out,
    short* __restrict__ h_out,
    float* __restrict__ Cf, short* __restrict__ Cb, int N, int mode, int nct)
{
    __shared__ __align__(16) short sA[3][256 * 32];   // 16KB each
    __shared__ __align__(16) short sB[3][128 * 32];   // 8KB each
    const int tid  = threadIdx.x;
    const int w    = tid >> 6, lane = tid & 63;
    const int wr   = w >> 1,  wc   = w & 1;      // 4x2 waves of 64x64
    // XCD-aware decode (consecutive bids round-robin across 8 XCDs)
    const int bid  = blockIdx.x;
    const int xcd  = bid & 7;
    const int slot = bid >> 3;
    const int g    = slot / nct;
    const int tcol = slot - g * nct;
    const int row0 = (g * 8 + xcd) * 256;
    const int col0 = tcol * 128;

    f32x4 acc[4][4];
#pragma unroll
    for (int m = 0; m < 4; ++m)
#pragma unroll
        for (int n = 0; n < 4; ++n) acc[m][n] = (f32x4){0.f, 0.f, 0.f, 0.f};

    const int rs = lane >> 2;
    const int cs = lane & 3;
    const int KK = K1 + K2;
    const int nsteps = KK >> 5;
    const int l16 = lane & 15;
    const int rloc = wr * 64 + ((lane >> 4) << 2);   // block-local base row

    // mode-2: prefetch c_in into regs; latency hides under the K-loop
    float co_pre[4][4] = {};
    const int ch = tcol * 32 + wc * 16 + l16;        // mode-2 channel
    if (mode == 2 && c_in) {
#pragma unroll
        for (int m = 0; m < 4; ++m)
#pragma unroll
            for (int r = 0; r < 4; ++r)
                co_pre[m][r] = c_in[(size_t)(row0 + rloc + m * 16 + r) * HID + ch];
    }

    // 3 global_load_lds per wave per stage call (2x A-seg, 1x B-seg)
    auto stage = [&](int buf, int k0) {
        const short* Ak; const short* Bk; int kk, ld;
        if (k0 < K1) { Ak = A1; Bk = B1; kk = k0;      ld = K1; }
        else         { Ak = A2; Bk = B2; kk = k0 - K1; ld = K2; }
#pragma unroll
        for (int i = 0; i < 2; ++i) {
            int seg = w * 2 + i;                     // 16 A-segs of 16 rows
            int row = seg * 16 + rs;
            int c8  = cs ^ ((row + (row >> 2)) & 3);
            const short* ga = Ak + (size_t)(row0 + row) * ld + kk + c8 * 8;
            short* la = &sA[buf][seg * 512 + lane * 8];
            __builtin_amdgcn_global_load_lds((const __attribute__((address_space(1))) void*)ga,
                                             (__attribute__((address_space(3))) void*)la, 16, 0, 0);
        }
        {
            int row = w * 16 + rs;                   // 8 B-segs of 16 rows
            int c8  = cs ^ ((row + (row >> 2)) & 3);
            const short* gb = Bk + (size_t)(col0 + row) * ld + kk + c8 * 8;
            short* lb = &sB[buf][w * 512 + lane * 8];
            __builtin_amdgcn_global_load_lds((const __attribute__((address_space(1))) void*)gb,
                                             (__attribute__((address_space(3))) void*)lb, 16, 0, 0);
        }
    };

    stage(0, 0);
    stage(1, 32);
    stage(2, 64);                  // 9 loads in flight; KK >= 96 guaranteed
    int cur = 0;
    for (int t = 0; t < nsteps; ++t) {
        // wait for group t (oldest) to land; keep newer groups in flight
        int remaining = nsteps - t;
        if (remaining >= 3)      asm volatile("s_waitcnt vmcnt(6)" ::: "memory");
        else if (remaining == 2) asm volatile("s_waitcnt vmcnt(3)" ::: "memory");
        else                     asm volatile("s_waitcnt vmcnt(0)" ::: "memory");
        __builtin_amdgcn_s_barrier();          // all waves: buf[cur] ready
        asm volatile("" ::: "memory");

        s16x8 af[4], bg[4];
        {
            const int rl = lane & 15;
            const int cw = lane >> 4;
#pragma unroll
            for (int m = 0; m < 4; ++m) {
                int r  = wr * 64 + m * 16 + rl;
                int sl = cw ^ ((r + (r >> 2)) & 3);
                af[m] = *(const s16x8*)(&sA[cur][r * 32 + sl * 8]);
                int c  = wc * 64 + m * 16 + rl;
                int sc = cw ^ ((c + (c >> 2)) & 3);
                bg[m] = *(const s16x8*)(&sB[cur][c * 32 + sc * 8]);
            }
        }
        // MFMAs consume all af/bg (compiler interleaves reads+MFMA with
        // fine-grained lgkmcnt); after them this wave's LDS reads are done.
#pragma unroll
        for (int m = 0; m < 4; ++m)
#pragma unroll
            for (int n = 0; n < 4; ++n)
                acc[m][n] = __builtin_amdgcn_mfma_f32_16x16x32_bf16(af[m], bg[n], acc[m][n], 0, 0, 0);

        __builtin_amdgcn_s_barrier();          // all waves done READING buf[cur]
        asm volatile("" ::: "memory");
        if (t + 3 < nsteps) stage(cur, (t + 3) * 32);   // re-stage 3 ahead
        cur = (cur == 2) ? 0 : cur + 1;
    }

    // C/D layout: col=lane&15, row=(lane>>4)*4+reg
    const int rbase = row0 + rloc;
    if (mode == 2) {
        float bi[4];
#pragma unroll
        for (int gg2 = 0; gg2 < 4; ++gg2) bi[gg2] = bih[gg2 * 256 + ch] + bhh[gg2 * 256 + ch];
#pragma unroll
        for (int m = 0; m < 4; ++m) {
#pragma unroll
            for (int r = 0; r < 4; ++r) {
                int row = rbase + m * 16 + r;
                float gi = acc[m][0][r] + bi[0];
                float gf = acc[m][1][r] + bi[1];
                float gg = acc[m][2][r] + bi[2];
                float go = acc[m][3][r] + bi[3];
                size_t idx = (size_t)row * HID + ch;
                float c2 = fsigm(gf) * co_pre[m][r] + fsigm(gi) * ftanh(gg);
                float h2 = fsigm(go) * ftanh(c2);
                c_out[idx] = c2;
                h_out[idx] = f2b(h2);
            }
        }
    } else {
        const int cbase = col0 + wc * 64 + l16;
#pragma unroll
        for (int n = 0; n < 4; ++n) {
            int col = cbase + n * 16;
            float ba = bias ? bias[col] : 0.f;
#pragma unroll
            for (int m = 0; m < 4; ++m) {
#pragma unroll
                for (int r = 0; r < 4; ++r) {
                    int row = rbase + m * 16 + r;
                    float v = acc[m][n][r] + ba;
                    size_t idx = (size_t)row * N + col;
                    if (mode == 1) Cb[idx] = f2b(v);
                    else           Cf[idx] = v;
                }
            }
        }
    }
}

// ---------------- fused GATv2 (softmax + aggregate + bias + LN + ELU) -------
// one 64-lane wave per dst node; lane l = channel h*64+l per head h.
// xlr: [MP][512] bf16, cols 0..255 = lin_l(x), 256..511 = lin_r(x).
__global__ __launch_bounds__(256) void gat_fused(
    const short* __restrict__ xlr, const int* __restrict__ rowptr,
    const int* __restrict__ esrc, const float* __restrict__ att,
    const float* __restrict__ gb, const float* __restrict__ lg,
    const float* __restrict__ lb, short* __restrict__ outb)
{
    int i    = blockIdx.x * 4 + (threadIdx.x >> 6);
    int lane = threadIdx.x & 63;
    if (i >= NN) return;
    float xr[HEADS], at[HEADS];
#pragma unroll
    for (int h = 0; h < HEADS; ++h) {
        xr[h] = b2f(xlr[(size_t)i * 512 + 256 + h * 64 + lane]);
        at[h] = att[h * 64 + lane];
    }
    float mx[HEADS], sm[HEADS], ac[HEADS];
#pragma unroll
    for (int h = 0; h < HEADS; ++h) { mx[h] = -INFINITY; sm[h] = 0.f; ac[h] = 0.f; }

    int lo = rowptr[i], hi = rowptr[i + 1];
    for (int e = lo; e < hi; ++e) {
        int s = esrc[e];
        float xs[HEADS], p[HEADS];
#pragma unroll
        for (int h = 0; h < HEADS; ++h) {
            xs[h] = b2f(xlr[(size_t)s * 512 + h * 64 + lane]);
            float v = xs[h] + xr[h];
            v = (v >= 0.f) ? v : 0.2f * v;
            p[h] = v * at[h];
        }
#pragma unroll
        for (int h = 0; h < HEADS; ++h) p[h] = wsum64(p[h]);
#pragma unroll
        for (int h = 0; h < HEADS; ++h) {
            float mn = fmaxf(mx[h], p[h]);
            float sc = fexp(mx[h] - mn);     // first iter: exp(-inf)=0
            float a  = fexp(p[h] - mn);
            sm[h] = sm[h] * sc + a;
            ac[h] = ac[h] * sc + a * xs[h];
            mx[h] = mn;
        }
    }
    // y = ac/sm (+ gat bias), then LayerNorm(256) + ELU, write bf16
    float val[HEADS], s1 = 0.f, s2 = 0.f;
#pragma unroll
    for (int h = 0; h < HEADS; ++h) {
        float v = ac[h] * frcp(sm[h]) + gb[h * 64 + lane];
        val[h] = v; s1 += v; s2 += v * v;
    }
    s1 = wsum64(s1); s2 = wsum64(s2);
    float mean = s1 * (1.f / 256.f);
    float var  = s2 * (1.f / 256.f) - mean * mean;
    float inv  = rsqrtf(var + 1e-5f);
#pragma unroll
    for (int h = 0; h < HEADS; ++h) {
        float v = (val[h] - mean) * inv * lg[h * 64 + lane] + lb[h * 64 + lane];
        v = (v > 0.f) ? v : (fexp(v) - 1.f);
        outb[(size_t)i * HID + h * 64 + lane] = f2b(v);
    }
}

// ---------------- LayerNorm (+act) for the MLP head -------------------------
__global__ __launch_bounds__(256) void ln_act_kernel(
    const float* __restrict__ in, const float* __restrict__ gamma,
    const float* __restrict__ beta, float* __restrict__ outf,
    short* __restrict__ outb, int width, int act)
{
    int row = blockIdx.x;
    const float* ip = in + (size_t)row * width;
    float vals[3];
    float s = 0.f, ss = 0.f;
    int nw = width >> 8;
    for (int i = 0; i < nw; ++i) {
        int c = threadIdx.x + (i << 8);
        float v = ip[c];
        vals[i] = v; s += v; ss += v * v;
    }
#pragma unroll
    for (int off = 32; off > 0; off >>= 1) {
        s  += __shfl_down(s, off);
        ss += __shfl_down(ss, off);
    }
    __shared__ float sh[8];
    int wv = threadIdx.x >> 6, lane = threadIdx.x & 63;
    if (lane == 0) { sh[wv] = s; sh[4 + wv] = ss; }
    __syncthreads();
    if (threadIdx.x == 0) {
        sh[0] = sh[0] + sh[1] + sh[2] + sh[3];
        sh[4] = sh[4] + sh[5] + sh[6] + sh[7];
    }
    __syncthreads();
    float mean = sh[0] / width;
    float var  = sh[4] / width - mean * mean;
    float inv  = rsqrtf(var + 1e-5f);
    for (int i = 0; i < nw; ++i) {
        int c = threadIdx.x + (i << 8);
        float v = (vals[i] - mean) * inv * gamma[c] + beta[c];
        if (act == 1) v = fmaxf(v, 0.f);
        if (outb) outb[(size_t)row * width + c] = f2b(v);
        else      outf[(size_t)row * width + c] = v;
    }
}

// ---------------- sorted-batch mean pool ------------------------------------
__global__ __launch_bounds__(256) void pool_mean(
    const short* __restrict__ h, const int* __restrict__ batch,
    short* __restrict__ poolb)
{
    int b    = blockIdx.x * 4 + (threadIdx.x >> 6);
    int lane = threadIdx.x & 63;
    if (b >= BG) return;
    auto lbound = [&](int key) {
        int lo = 0, hi = NN;
        while (lo < hi) { int mid = (lo + hi) >> 1; if (batch[mid] < key) lo = mid + 1; else hi = mid; }
        return lo;
    };
    int lo = lbound(b), hi = lbound(b + 1);
    float acc[HEADS] = {0.f, 0.f, 0.f, 0.f};
    for (int r = lo; r < hi; ++r)
#pragma unroll
        for (int hh = 0; hh < HEADS; ++hh)
            acc[hh] += b2f(h[(size_t)r * HID + hh * 64 + lane]);
    float inv = 1.f / fmaxf((float)(hi - lo), 1.f);
#pragma unroll
    for (int hh = 0; hh < HEADS; ++hh)
        poolb[(size_t)b * HID + hh * 64 + lane] = f2b(acc[hh] * inv);
}

// ---------------------------------------------------------------------------
extern "C" void kernel_launch(void* const* d_in, const int* in_sizes, int n_in,
                              void* d_out, int out_size, void* d_ws, size_t ws_size,
                              hipStream_t stream)
{
    (void)in_sizes; (void)n_in; (void)out_size; (void)ws_size;
    const float* x      = (const float*)d_in[0];
    const int*   ei     = (const int*)d_in[1];
    const int*   batch  = (const int*)d_in[2];
    const float* lin0_w = (const float*)d_in[4];
    const float* lin0_b = (const float*)d_in[5];
    const float* r0_wih = (const float*)d_in[6];
    const float* r0_bih = (const float*)d_in[8];
    const float* r0_bhh = (const float*)d_in[9];
    const float* mh1_w  = (const float*)d_in[46];
    const float* mh1_b  = (const float*)d_in[47];
    const float* ln1_g  = (const float*)d_in[48];
    const float* ln1_b  = (const float*)d_in[49];
    const float* mh2_w  = (const float*)d_in[50];
    const float* mh2_b  = (const float*)d_in[51];
    const float* ln2_g  = (const float*)d_in[52];
    const float* ln2_b  = (const float*)d_in[53];
    float* out = (float*)d_out;

    // ---- workspace bump allocation ----
    char* wsb = (char*)d_ws;
    auto alloc = [&](size_t bytes) -> void* {
        void* p = (void*)wsb;
        wsb += (bytes + 255) & ~(size_t)255;
        return p;
    };
    const size_t NH = (size_t)MP * HID;
    float* cb   = (float*)alloc(NH * 4);          // LSTM cell state f32
    short* hA   = (short*)alloc(NH * 2);          // h ping
    short* hB   = (short*)alloc(NH * 2);          // h pong
    short* ybb  = (short*)alloc(NH * 2);          // LSTM-input / x0 bf16
    short* xlr  = (short*)alloc((size_t)MP * 512 * 2);  // [xl|xr] bf16
    int*   deg    = (int*)alloc((size_t)NN * 4);
    int*   rowptr = (int*)alloc((size_t)(NN + 1) * 4);
    int*   cursor = (int*)alloc((size_t)NN * 4);
    int*   esrc   = (int*)alloc((size_t)EP * 4);
    // weights bf16
    short* w_lin0 = (short*)alloc((size_t)256 * KP0 * 2);
    short* w_r0   = (short*)alloc((size_t)G4H * 256 * 2);
    short* w_lr[3]; short* w_ih[3]; short* w_hh[3]; float* blr[3];
    for (int l = 0; l < 3; ++l) {
        int Kp = (l == 0) ? KP0 : 256;
        w_lr[l] = (short*)alloc((size_t)512 * Kp * 2);
        w_ih[l] = (short*)alloc((size_t)G4H * 256 * 2);
        w_hh[l] = (short*)alloc((size_t)G4H * 256 * 2);
        blr[l]  = (float*)alloc(512 * 4);
    }
    short* w_m1 = (short*)alloc((size_t)NH1 * 256 * 2);
    short* w_m2 = (short*)alloc((size_t)NH2 * NH1 * 2);
    // xb (layer-0 padded input) with head temps aliased over it (head runs
    // only after xb is dead)
    short* xb = (short*)alloc((size_t)MP * KP0 * 2);   // 64 MB
    float* z1    = (float*)xb;                          // BG*NH1 f32 (8.4MB)
    short* z1b   = (short*)(z1 + (size_t)BG * NH1);     // BG*NH1 bf16
    short* poolb = z1b + (size_t)BG * NH1;              // BG*HID bf16

    auto conv = [&](const float* s, short* d, int rs, int rd, int Ks, int Kd) {
        conv_bf16<<<dim3(512), dim3(256), 0, stream>>>(s, d, rs, rd, Ks, Kd);
    };
    auto convg = [&](const float* s, short* d) {
        conv_gates<<<dim3(512), dim3(256), 0, stream>>>(s, d, 256);
    };
    // mode 0/1 GEMM; 1-D grid with XCD swizzle (requires (M/256)%8==0)
    auto G = [&](const short* A, const short* B, int K, const float* bias,
                 float* Cf, short* Cbb, int M, int N, int mode) {
        int nrp = M / 256, nct = N / 128;
        mfma_gemm<<<dim3(nrp * nct), dim3(512), 0, stream>>>(
            A, B, K, nullptr, nullptr, 0, bias,
            nullptr, nullptr, nullptr, nullptr, nullptr, Cf, Cbb, N, mode, nct);
    };
    // mode 2 LSTM GEMM
    auto GL = [&](const short* A1, const short* B1, int K1,
                  const short* A2, const short* B2, int K2,
                  const float* bih, const float* bhh,
                  const float* ci, float* co, short* ho) {
        mfma_gemm<<<dim3((MP / 256) * 8), dim3(512), 0, stream>>>(
            A1, B1, K1, A2, B2, K2, nullptr,
            bih, bhh, ci, co, ho, nullptr, nullptr, G4H, 2, 8);
    };

    // ---- conversions + CSR build ----
    conv(x, xb, NN, MP, FIN, KP0);
    conv(lin0_w, w_lin0, 256, 256, FIN, KP0);
    convg(r0_wih, w_r0);
    for (int l = 0; l < 3; ++l) {
        int base = 10 + 12 * l;
        int K  = (l == 0) ? FIN : 256;
        int Kp = (l == 0) ? KP0 : 256;
        conv((const float*)d_in[base + 0], w_lr[l], 256, 256, K, Kp);
        conv((const float*)d_in[base + 2], w_lr[l] + (size_t)256 * Kp, 256, 256, K, Kp);
        convg((const float*)d_in[base + 8], w_ih[l]);
        convg((const float*)d_in[base + 9], w_hh[l]);
        concat2_f32<<<dim3(2), dim3(256), 0, stream>>>(
            (const float*)d_in[base + 1], (const float*)d_in[base + 3], blr[l], 256, 256);
    }
    conv(mh1_w, w_m1, NH1, NH1, 256, 256);
    conv(mh2_w, w_m2, NH2, NH2, NH1, NH1);

    zero_f32<<<dim3(256), dim3(256), 0, stream>>>((float*)deg, NN);
    edge_hist<<<dim3((EP + 255) / 256), dim3(256), 0, stream>>>(ei, deg);
    scan_deg<<<dim3(1), dim3(1024), 0, stream>>>(deg, rowptr, cursor);
    edge_fill<<<dim3((EP + 255) / 256), dim3(256), 0, stream>>>(ei, rowptr, cursor, esrc);

    // ---- lin0 -> x0 (bf16); rnn0 LSTM from zero state (fused epilogue) ----
    G(xb, w_lin0, KP0, lin0_b, nullptr, ybb, MP, HID, 1);
    GL(ybb, w_r0, 256, nullptr, nullptr, 0, r0_bih, r0_bhh, nullptr, cb, hA);

    // ---- 3x (GATv2 -> LN+ELU -> LSTM) ----
    short* hprev = hA;
    short* hnext = hB;
    for (int l = 0; l < 3; ++l) {
        int base = 10 + 12 * l;
        const float* att = (const float*)d_in[base + 4];
        const float* gb  = (const float*)d_in[base + 5];
        const float* lg  = (const float*)d_in[base + 6];
        const float* lb  = (const float*)d_in[base + 7];
        const float* bih = (const float*)d_in[base + 10];
        const float* bhh = (const float*)d_in[base + 11];
        const short* Ain = (l == 0) ? xb : hprev;
        int K = (l == 0) ? KP0 : 256;

        G(Ain, w_lr[l], K, blr[l], nullptr, xlr, MP, 512, 1);
        gat_fused<<<dim3((NN + 3) / 4), dim3(256), 0, stream>>>(
            xlr, rowptr, esrc, att, gb, lg, lb, ybb);
        GL(ybb, w_ih[l], 256, hprev, w_hh[l], 256, bih, bhh, cb, cb, hnext);
        short* t = hprev; hprev = hnext; hnext = t;
    }

    // ---- mean pool (sorted batch) + MLP head ----
    pool_mean<<<dim3((BG + 3) / 4), dim3(256), 0, stream>>>(hprev, batch, poolb);
    G(poolb, w_m1, 256, mh1_b, z1, nullptr, BG, NH1, 0);
    ln_act_kernel<<<dim3(BG), dim3(256), 0, stream>>>(z1, ln1_g, ln1_b, nullptr, z1b, NH1, 1);
    G(z1b, w_m2, NH1, mh2_b, out, nullptr, BG, NH2, 0);
    ln_act_kernel<<<dim3(BG), dim3(256), 0, stream>>>(out, ln2_g, ln2_b, out, nullptr, NH2, 0);
}

// Round 16
// 1596.333 us; speedup vs baseline: 1.7832x; 1.1401x over previous
//
#include <hip/hip_runtime.h>
#include <hip/hip_bf16.h>
#include <math.h>

// ---------------------------------------------------------------------------
// GraphEncoder round 16 (= round-15 resubmission; that bench died on container
// infra before launch, same flake as rounds 2/5/7):
// replace the single-block serial scan_deg (230us, 0.15% occupancy, the top
// dispatch after round-14's GEMM fix) with a 3-kernel hierarchical scan
// (scan_part / scan_tops / scan_fill), all coalesced + device-wide.
// GEMM pipeline unchanged from round 14 (3-buffer depth-3 prefetch,
// counted vmcnt, BM=256).
// ---------------------------------------------------------------------------

constexpr int NN    = 100000;
constexpr int EE    = 400000;
constexpr int EP    = EE + NN;      // 500000 (incl self loops)
constexpr int BG    = 4096;
constexpr int FIN   = 300;
constexpr int HEADS = 4;
constexpr int HID   = 256;
constexpr int G4H   = 1024;
constexpr int NH1   = 512;
constexpr int NH2   = 768;
constexpr int MP    = 100352;       // 392*256, 392 % 8 == 0
constexpr int KP0   = 320;          // FIN padded to mult of 32
constexpr int SCB   = 392;          // scan blocks (392*256 = 100352 >= NN)

typedef __attribute__((ext_vector_type(4))) float f32x4;
typedef __attribute__((ext_vector_type(8))) short s16x8;

#define LOG2E 1.4426950408889634f

// fast HW transcendentals (v_exp_f32 = 2^x, v_rcp_f32)
__device__ inline float fexp(float x)  { return __builtin_amdgcn_exp2f(x * LOG2E); }
__device__ inline float frcp(float x)  { return __builtin_amdgcn_rcpf(x); }
__device__ inline float fsigm(float x) { return frcp(1.f + __builtin_amdgcn_exp2f(-LOG2E * x)); }
__device__ inline float ftanh(float x) { return 1.f - 2.f * frcp(1.f + __builtin_amdgcn_exp2f(2.f * LOG2E * x)); }

__device__ inline float b2f(short s) { return __uint_as_float(((unsigned)(unsigned short)s) << 16); }
__device__ inline short f2b(float f) {
    unsigned u = __float_as_uint(f);
    u += 0x7fff + ((u >> 16) & 1);          // round-to-nearest-even
    return (short)(u >> 16);
}
__device__ inline float wsum64(float v) {
#pragma unroll
    for (int o = 32; o > 0; o >>= 1) v += __shfl_xor(v, o);
    return v;
}

// ---------------- utility kernels -------------------------------------------
__global__ __launch_bounds__(256) void zero_f32(float* __restrict__ p, long long n)
{
    long long i = (long long)blockIdx.x * 256 + threadIdx.x;
    long long stride = (long long)gridDim.x * 256;
    for (; i < n; i += stride) p[i] = 0.f;
}

// f32 -> bf16 with row/col zero padding
__global__ __launch_bounds__(256) void conv_bf16(
    const float* __restrict__ src, short* __restrict__ dst,
    int rsrc, int rdst, int Ks, int Kd)
{
    long long n = (long long)rdst * Kd;
    long long stride = (long long)gridDim.x * 256;
    for (long long i = (long long)blockIdx.x * 256 + threadIdx.x; i < n; i += stride) {
        int r = (int)(i / Kd);
        int k = (int)(i - (long long)r * Kd);
        float v = (r < rsrc && k < Ks) ? src[(long long)r * Ks + k] : 0.f;
        dst[i] = f2b(v);
    }
}

// gate-interleaved pack of LSTM weight [1024][K]:
// new row p -> orig row gate*256+ch, gate=(p>>4)&3, ch=(p>>7)*32+((p>>6)&1)*16+(p&15)
__global__ __launch_bounds__(256) void conv_gates(
    const float* __restrict__ src, short* __restrict__ dst, int K)
{
    long long n = (long long)G4H * K;
    long long stride = (long long)gridDim.x * 256;
    for (long long i = (long long)blockIdx.x * 256 + threadIdx.x; i < n; i += stride) {
        int p = (int)(i / K);
        int k = (int)(i - (long long)p * K);
        int gate = (p >> 4) & 3;
        int ch   = (p >> 7) * 32 + ((p >> 6) & 1) * 16 + (p & 15);
        dst[i] = f2b(src[(size_t)(gate * 256 + ch) * K + k]);
    }
}

__global__ __launch_bounds__(256) void concat2_f32(
    const float* __restrict__ a, const float* __restrict__ b,
    float* __restrict__ dst, int na, int nb)
{
    int i = blockIdx.x * 256 + threadIdx.x;
    if (i < na) dst[i] = a[i];
    else if (i < na + nb) dst[i] = b[i - na];
}

// ---------------- CSR build -------------------------------------------------
__global__ __launch_bounds__(256) void edge_hist(const int* __restrict__ ei,
                                                 int* __restrict__ deg)
{
    int e = blockIdx.x * 256 + threadIdx.x;
    if (e >= EP) return;
    int d = (e < EE) ? ei[EE + e] : e - EE;
    atomicAdd(&deg[d], 1);
}

// pass 1: per-block chunk sums (coalesced)
__global__ __launch_bounds__(256) void scan_part(const int* __restrict__ deg,
                                                 int* __restrict__ bsum)
{
    int b = blockIdx.x, t = threadIdx.x;
    int i = b * 256 + t;
    int v = (i < NN) ? deg[i] : 0;
#pragma unroll
    for (int o = 32; o > 0; o >>= 1) v += __shfl_down(v, o);
    __shared__ int sh[4];
    if ((t & 63) == 0) sh[t >> 6] = v;
    __syncthreads();
    if (t == 0) bsum[b] = sh[0] + sh[1] + sh[2] + sh[3];
}

// pass 2: scan the 392 block sums (single small block)
__global__ __launch_bounds__(512) void scan_tops(const int* __restrict__ bsum,
                                                 int* __restrict__ bpre,
                                                 int* __restrict__ rowptr)
{
    __shared__ int sh[512];
    int t = threadIdx.x;
    int v = (t < SCB) ? bsum[t] : 0;
    sh[t] = v;
    __syncthreads();
    for (int off = 1; off < 512; off <<= 1) {
        int u = (t >= off) ? sh[t - off] : 0;
        __syncthreads();
        sh[t] += u;
        __syncthreads();
    }
    if (t < SCB) bpre[t] = sh[t] - v;          // exclusive prefix
    if (t == SCB - 1) rowptr[NN] = sh[t];      // total == EP
}

// pass 3: intra-block exclusive scan + write rowptr/cursor (coalesced)
__global__ __launch_bounds__(256) void scan_fill(const int* __restrict__ deg,
                                                 const int* __restrict__ bpre,
                                                 int* __restrict__ rowptr,
                                                 int* __restrict__ cursor)
{
    __shared__ int sh[256];
    int b = blockIdx.x, t = threadIdx.x;
    int i = b * 256 + t;
    int v = (i < NN) ? deg[i] : 0;
    sh[t] = v;
    __syncthreads();
    for (int off = 1; off < 256; off <<= 1) {
        int u = (t >= off) ? sh[t - off] : 0;
        __syncthreads();
        sh[t] += u;
        __syncthreads();
    }
    if (i < NN) {
        rowptr[i] = bpre[b] + sh[t] - v;       // exclusive
        cursor[i] = 0;
    }
}

__global__ __launch_bounds__(256) void edge_fill(const int* __restrict__ ei,
                                                 const int* __restrict__ rowptr,
                                                 int* __restrict__ cursor,
                                                 int* __restrict__ esrc)
{
    int e = blockIdx.x * 256 + threadIdx.x;
    if (e >= EP) return;
    int s, d;
    if (e < EE) { s = ei[e]; d = ei[EE + e]; }
    else        { s = d = e - EE; }
    int slot = rowptr[d] + atomicAdd(&cursor[d], 1);
    esrc[slot] = s;
}

// ---------------- MFMA GEMM with fused epilogues ----------------------------
// C[M x N] = A1[M x K1] @ B1[N x K1]^T (+ A2[M x K2] @ B2[N x K2]^T)
// BM=256 x BN=128 tile; 8 waves (512 thr) as 4x2 of 64x64.
// 1-D grid of (M/256)*(N/128) blocks; XCD swizzle: xcd=bid&7, slot=bid>>3,
// g=slot/nct, ct=slot%nct, row_panel=g*8+xcd. Requires (M/256)%8==0.
// 3-buffer rotation, depth-3 prefetch, counted vmcnt (6/3/0 tail).
// Requires KK >= 96 (all call sites have KK >= 256).
// mode 0: +bias -> f32 Cf      mode 1: +bias -> bf16 Cb
// mode 2: LSTM epilogue (gate-interleaved B; N=1024): reads c_in (or 0,
//         prefetched to regs pre-K-loop), writes c_out f32 + h_out bf16.
__global__ __launch_bounds__(512) void mfma_gemm(
    const short* __restrict__ A1, const short* __restrict__ B1, int K1,
    const short* __restrict__ A2, const short* __restrict__ B2, int K2,
    const float* __restrict__ bias,
    const float* __restrict__ bih, const float* __restrict__ bhh,
    const float* __restrict__ c_in, float* __restrict__ c_out,
    short* __restrict__ h_out,
    float* __restrict__ Cf, short* __restrict__ Cb, int N, int mode, int nct)
{
    __shared__ __align__(16) short sA[3][256 * 32];   // 16KB each
    __shared__ __align__(16) short sB[3][128 * 32];   // 8KB each
    const int tid  = threadIdx.x;
    const int w    = tid >> 6, lane = tid & 63;
    const int wr   = w >> 1,  wc   = w & 1;      // 4x2 waves of 64x64
    // XCD-aware decode (consecutive bids round-robin across 8 XCDs)
    const int bid  = blockIdx.x;
    const int xcd  = bid & 7;
    const int slot = bid >> 3;
    const int g    = slot / nct;
    const int tcol = slot - g * nct;
    const int row0 = (g * 8 + xcd) * 256;
    const int col0 = tcol * 128;

    f32x4 acc[4][4];
#pragma unroll
    for (int m = 0; m < 4; ++m)
#pragma unroll
        for (int n = 0; n < 4; ++n) acc[m][n] = (f32x4){0.f, 0.f, 0.f, 0.f};

    const int rs = lane >> 2;
    const int cs = lane & 3;
    const int KK = K1 + K2;
    const int nsteps = KK >> 5;
    const int l16 = lane & 15;
    const int rloc = wr * 64 + ((lane >> 4) << 2);   // block-local base row

    // mode-2: prefetch c_in into regs; latency hides under the K-loop
    float co_pre[4][4] = {};
    const int ch = tcol * 32 + wc * 16 + l16;        // mode-2 channel
    if (mode == 2 && c_in) {
#pragma unroll
        for (int m = 0; m < 4; ++m)
#pragma unroll
            for (int r = 0; r < 4; ++r)
                co_pre[m][r] = c_in[(size_t)(row0 + rloc + m * 16 + r) * HID + ch];
    }

    // 3 global_load_lds per wave per stage call (2x A-seg, 1x B-seg)
    auto stage = [&](int buf, int k0) {
        const short* Ak; const short* Bk; int kk, ld;
        if (k0 < K1) { Ak = A1; Bk = B1; kk = k0;      ld = K1; }
        else         { Ak = A2; Bk = B2; kk = k0 - K1; ld = K2; }
#pragma unroll
        for (int i = 0; i < 2; ++i) {
            int seg = w * 2 + i;                     // 16 A-segs of 16 rows
            int row = seg * 16 + rs;
            int c8  = cs ^ ((row + (row >> 2)) & 3);
            const short* ga = Ak + (size_t)(row0 + row) * ld + kk + c8 * 8;
            short* la = &sA[buf][seg * 512 + lane * 8];
            __builtin_amdgcn_global_load_lds((const __attribute__((address_space(1))) void*)ga,
                                             (__attribute__((address_space(3))) void*)la, 16, 0, 0);
        }
        {
            int row = w * 16 + rs;                   // 8 B-segs of 16 rows
            int c8  = cs ^ ((row + (row >> 2)) & 3);
            const short* gb = Bk + (size_t)(col0 + row) * ld + kk + c8 * 8;
            short* lb = &sB[buf][w * 512 + lane * 8];
            __builtin_amdgcn_global_load_lds((const __attribute__((address_space(1))) void*)gb,
                                             (__attribute__((address_space(3))) void*)lb, 16, 0, 0);
        }
    };

    stage(0, 0);
    stage(1, 32);
    stage(2, 64);                  // 9 loads in flight; KK >= 96 guaranteed
    int cur = 0;
    for (int t = 0; t < nsteps; ++t) {
        // wait for group t (oldest) to land; keep newer groups in flight
        int remaining = nsteps - t;
        if (remaining >= 3)      asm volatile("s_waitcnt vmcnt(6)" ::: "memory");
        else if (remaining == 2) asm volatile("s_waitcnt vmcnt(3)" ::: "memory");
        else                     asm volatile("s_waitcnt vmcnt(0)" ::: "memory");
        __builtin_amdgcn_s_barrier();          // all waves: buf[cur] ready
        asm volatile("" ::: "memory");

        s16x8 af[4], bg[4];
        {
            const int rl = lane & 15;
            const int cw = lane >> 4;
#pragma unroll
            for (int m = 0; m < 4; ++m) {
                int r  = wr * 64 + m * 16 + rl;
                int sl = cw ^ ((r + (r >> 2)) & 3);
                af[m] = *(const s16x8*)(&sA[cur][r * 32 + sl * 8]);
                int c  = wc * 64 + m * 16 + rl;
                int sc = cw ^ ((c + (c >> 2)) & 3);
                bg[m] = *(const s16x8*)(&sB[cur][c * 32 + sc * 8]);
            }
        }
        // MFMAs consume all af/bg (compiler interleaves reads+MFMA with
        // fine-grained lgkmcnt); after them this wave's LDS reads are done.
#pragma unroll
        for (int m = 0; m < 4; ++m)
#pragma unroll
            for (int n = 0; n < 4; ++n)
                acc[m][n] = __builtin_amdgcn_mfma_f32_16x16x32_bf16(af[m], bg[n], acc[m][n], 0, 0, 0);

        __builtin_amdgcn_s_barrier();          // all waves done READING buf[cur]
        asm volatile("" ::: "memory");
        if (t + 3 < nsteps) stage(cur, (t + 3) * 32);   // re-stage 3 ahead
        cur = (cur == 2) ? 0 : cur + 1;
    }

    // C/D layout: col=lane&15, row=(lane>>4)*4+reg
    const int rbase = row0 + rloc;
    if (mode == 2) {
        float bi[4];
#pragma unroll
        for (int gg2 = 0; gg2 < 4; ++gg2) bi[gg2] = bih[gg2 * 256 + ch] + bhh[gg2 * 256 + ch];
#pragma unroll
        for (int m = 0; m < 4; ++m) {
#pragma unroll
            for (int r = 0; r < 4; ++r) {
                int row = rbase + m * 16 + r;
                float gi = acc[m][0][r] + bi[0];
                float gf = acc[m][1][r] + bi[1];
                float gg = acc[m][2][r] + bi[2];
                float go = acc[m][3][r] + bi[3];
                size_t idx = (size_t)row * HID + ch;
                float c2 = fsigm(gf) * co_pre[m][r] + fsigm(gi) * ftanh(gg);
                float h2 = fsigm(go) * ftanh(c2);
                c_out[idx] = c2;
                h_out[idx] = f2b(h2);
            }
        }
    } else {
        const int cbase = col0 + wc * 64 + l16;
#pragma unroll
        for (int n = 0; n < 4; ++n) {
            int col = cbase + n * 16;
            float ba = bias ? bias[col] : 0.f;
#pragma unroll
            for (int m = 0; m < 4; ++m) {
#pragma unroll
                for (int r = 0; r < 4; ++r) {
                    int row = rbase + m * 16 + r;
                    float v = acc[m][n][r] + ba;
                    size_t idx = (size_t)row * N + col;
                    if (mode == 1) Cb[idx] = f2b(v);
                    else           Cf[idx] = v;
                }
            }
        }
    }
}

// ---------------- fused GATv2 (softmax + aggregate + bias + LN + ELU) -------
// one 64-lane wave per dst node; lane l = channel h*64+l per head h.
// xlr: [MP][512] bf16, cols 0..255 = lin_l(x), 256..511 = lin_r(x).
__global__ __launch_bounds__(256) void gat_fused(
    const short* __restrict__ xlr, const int* __restrict__ rowptr,
    const int* __restrict__ esrc, const float* __restrict__ att,
    const float* __restrict__ gb, const float* __restrict__ lg,
    const float* __restrict__ lb, short* __restrict__ outb)
{
    int i    = blockIdx.x * 4 + (threadIdx.x >> 6);
    int lane = threadIdx.x & 63;
    if (i >= NN) return;
    float xr[HEADS], at[HEADS];
#pragma unroll
    for (int h = 0; h < HEADS; ++h) {
        xr[h] = b2f(xlr[(size_t)i * 512 + 256 + h * 64 + lane]);
        at[h] = att[h * 64 + lane];
    }
    float mx[HEADS], sm[HEADS], ac[HEADS];
#pragma unroll
    for (int h = 0; h < HEADS; ++h) { mx[h] = -INFINITY; sm[h] = 0.f; ac[h] = 0.f; }

    int lo = rowptr[i], hi = rowptr[i + 1];
    for (int e = lo; e < hi; ++e) {
        int s = esrc[e];
        float xs[HEADS], p[HEADS];
#pragma unroll
        for (int h = 0; h < HEADS; ++h) {
            xs[h] = b2f(xlr[(size_t)s * 512 + h * 64 + lane]);
            float v = xs[h] + xr[h];
            v = (v >= 0.f) ? v : 0.2f * v;
            p[h] = v * at[h];
        }
#pragma unroll
        for (int h = 0; h < HEADS; ++h) p[h] = wsum64(p[h]);
#pragma unroll
        for (int h = 0; h < HEADS; ++h) {
            float mn = fmaxf(mx[h], p[h]);
            float sc = fexp(mx[h] - mn);     // first iter: exp(-inf)=0
            float a  = fexp(p[h] - mn);
            sm[h] = sm[h] * sc + a;
            ac[h] = ac[h] * sc + a * xs[h];
            mx[h] = mn;
        }
    }
    // y = ac/sm (+ gat bias), then LayerNorm(256) + ELU, write bf16
    float val[HEADS], s1 = 0.f, s2 = 0.f;
#pragma unroll
    for (int h = 0; h < HEADS; ++h) {
        float v = ac[h] * frcp(sm[h]) + gb[h * 64 + lane];
        val[h] = v; s1 += v; s2 += v * v;
    }
    s1 = wsum64(s1); s2 = wsum64(s2);
    float mean = s1 * (1.f / 256.f);
    float var  = s2 * (1.f / 256.f) - mean * mean;
    float inv  = rsqrtf(var + 1e-5f);
#pragma unroll
    for (int h = 0; h < HEADS; ++h) {
        float v = (val[h] - mean) * inv * lg[h * 64 + lane] + lb[h * 64 + lane];
        v = (v > 0.f) ? v : (fexp(v) - 1.f);
        outb[(size_t)i * HID + h * 64 + lane] = f2b(v);
    }
}

// ---------------- LayerNorm (+act) for the MLP head -------------------------
__global__ __launch_bounds__(256) void ln_act_kernel(
    const float* __restrict__ in, const float* __restrict__ gamma,
    const float* __restrict__ beta, float* __restrict__ outf,
    short* __restrict__ outb, int width, int act)
{
    int row = blockIdx.x;
    const float* ip = in + (size_t)row * width;
    float vals[3];
    float s = 0.f, ss = 0.f;
    int nw = width >> 8;
    for (int i = 0; i < nw; ++i) {
        int c = threadIdx.x + (i << 8);
        float v = ip[c];
        vals[i] = v; s += v; ss += v * v;
    }
#pragma unroll
    for (int off = 32; off > 0; off >>= 1) {
        s  += __shfl_down(s, off);
        ss += __shfl_down(ss, off);
    }
    __shared__ float sh[8];
    int wv = threadIdx.x >> 6, lane = threadIdx.x & 63;
    if (lane == 0) { sh[wv] = s; sh[4 + wv] = ss; }
    __syncthreads();
    if (threadIdx.x == 0) {
        sh[0] = sh[0] + sh[1] + sh[2] + sh[3];
        sh[4] = sh[4] + sh[5] + sh[6] + sh[7];
    }
    __syncthreads();
    float mean = sh[0] / width;
    float var  = sh[4] / width - mean * mean;
    float inv  = rsqrtf(var + 1e-5f);
    for (int i = 0; i < nw; ++i) {
        int c = threadIdx.x + (i << 8);
        float v = (vals[i] - mean) * inv * gamma[c] + beta[c];
        if (act == 1) v = fmaxf(v, 0.f);
        if (outb) outb[(size_t)row * width + c] = f2b(v);
        else      outf[(size_t)row * width + c] = v;
    }
}

// ---------------- sorted-batch mean pool ------------------------------------
__global__ __launch_bounds__(256) void pool_mean(
    const short* __restrict__ h, const int* __restrict__ batch,
    short* __restrict__ poolb)
{
    int b    = blockIdx.x * 4 + (threadIdx.x >> 6);
    int lane = threadIdx.x & 63;
    if (b >= BG) return;
    auto lbound = [&](int key) {
        int lo = 0, hi = NN;
        while (lo < hi) { int mid = (lo + hi) >> 1; if (batch[mid] < key) lo = mid + 1; else hi = mid; }
        return lo;
    };
    int lo = lbound(b), hi = lbound(b + 1);
    float acc[HEADS] = {0.f, 0.f, 0.f, 0.f};
    for (int r = lo; r < hi; ++r)
#pragma unroll
        for (int hh = 0; hh < HEADS; ++hh)
            acc[hh] += b2f(h[(size_t)r * HID + hh * 64 + lane]);
    float inv = 1.f / fmaxf((float)(hi - lo), 1.f);
#pragma unroll
    for (int hh = 0; hh < HEADS; ++hh)
        poolb[(size_t)b * HID + hh * 64 + lane] = f2b(acc[hh] * inv);
}

// ---------------------------------------------------------------------------
extern "C" void kernel_launch(void* const* d_in, const int* in_sizes, int n_in,
                              void* d_out, int out_size, void* d_ws, size_t ws_size,
                              hipStream_t stream)
{
    (void)in_sizes; (void)n_in; (void)out_size; (void)ws_size;
    const float* x      = (const float*)d_in[0];
    const int*   ei     = (const int*)d_in[1];
    const int*   batch  = (const int*)d_in[2];
    const float* lin0_w = (const float*)d_in[4];
    const float* lin0_b = (const float*)d_in[5];
    const float* r0_wih = (const float*)d_in[6];
    const float* r0_bih = (const float*)d_in[8];
    const float* r0_bhh = (const float*)d_in[9];
    const float* mh1_w  = (const float*)d_in[46];
    const float* mh1_b  = (const float*)d_in[47];
    const float* ln1_g  = (const float*)d_in[48];
    const float* ln1_b  = (const float*)d_in[49];
    const float* mh2_w  = (const float*)d_in[50];
    const float* mh2_b  = (const float*)d_in[51];
    const float* ln2_g  = (const float*)d_in[52];
    const float* ln2_b  = (const float*)d_in[53];
    float* out = (float*)d_out;

    // ---- workspace bump allocation ----
    char* wsb = (char*)d_ws;
    auto alloc = [&](size_t bytes) -> void* {
        void* p = (void*)wsb;
        wsb += (bytes + 255) & ~(size_t)255;
        return p;
    };
    const size_t NH = (size_t)MP * HID;
    float* cb   = (float*)alloc(NH * 4);          // LSTM cell state f32
    short* hA   = (short*)alloc(NH * 2);          // h ping
    short* hB   = (short*)alloc(NH * 2);          // h pong
    short* ybb  = (short*)alloc(NH * 2);          // LSTM-input / x0 bf16
    short* xlr  = (short*)alloc((size_t)MP * 512 * 2);  // [xl|xr] bf16
    int*   deg    = (int*)alloc((size_t)NN * 4);
    int*   rowptr = (int*)alloc((size_t)(NN + 1) * 4);
    int*   cursor = (int*)alloc((size_t)NN * 4);
    int*   esrc   = (int*)alloc((size_t)EP * 4);
    int*   bsum   = (int*)alloc((size_t)SCB * 4);
    int*   bpre   = (int*)alloc((size_t)SCB * 4);
    // weights bf16
    short* w_lin0 = (short*)alloc((size_t)256 * KP0 * 2);
    short* w_r0   = (short*)alloc((size_t)G4H * 256 * 2);
    short* w_lr[3]; short* w_ih[3]; short* w_hh[3]; float* blr[3];
    for (int l = 0; l < 3; ++l) {
        int Kp = (l == 0) ? KP0 : 256;
        w_lr[l] = (short*)alloc((size_t)512 * Kp * 2);
        w_ih[l] = (short*)alloc((size_t)G4H * 256 * 2);
        w_hh[l] = (short*)alloc((size_t)G4H * 256 * 2);
        blr[l]  = (float*)alloc(512 * 4);
    }
    short* w_m1 = (short*)alloc((size_t)NH1 * 256 * 2);
    short* w_m2 = (short*)alloc((size_t)NH2 * NH1 * 2);
    // xb (layer-0 padded input) with head temps aliased over it (head runs
    // only after xb is dead)
    short* xb = (short*)alloc((size_t)MP * KP0 * 2);   // 64 MB
    float* z1    = (float*)xb;                          // BG*NH1 f32 (8.4MB)
    short* z1b   = (short*)(z1 + (size_t)BG * NH1);     // BG*NH1 bf16
    short* poolb = z1b + (size_t)BG * NH1;              // BG*HID bf16

    auto conv = [&](const float* s, short* d, int rs, int rd, int Ks, int Kd) {
        conv_bf16<<<dim3(512), dim3(256), 0, stream>>>(s, d, rs, rd, Ks, Kd);
    };
    auto convg = [&](const float* s, short* d) {
        conv_gates<<<dim3(512), dim3(256), 0, stream>>>(s, d, 256);
    };
    // mode 0/1 GEMM; 1-D grid with XCD swizzle (requires (M/256)%8==0)
    auto G = [&](const short* A, const short* B, int K, const float* bias,
                 float* Cf, short* Cbb, int M, int N, int mode) {
        int nrp = M / 256, nct = N / 128;
        mfma_gemm<<<dim3(nrp * nct), dim3(512), 0, stream>>>(
            A, B, K, nullptr, nullptr, 0, bias,
            nullptr, nullptr, nullptr, nullptr, nullptr, Cf, Cbb, N, mode, nct);
    };
    // mode 2 LSTM GEMM
    auto GL = [&](const short* A1, const short* B1, int K1,
                  const short* A2, const short* B2, int K2,
                  const float* bih, const float* bhh,
                  const float* ci, float* co, short* ho) {
        mfma_gemm<<<dim3((MP / 256) * 8), dim3(512), 0, stream>>>(
            A1, B1, K1, A2, B2, K2, nullptr,
            bih, bhh, ci, co, ho, nullptr, nullptr, G4H, 2, 8);
    };

    // ---- conversions + CSR build ----
    conv(x, xb, NN, MP, FIN, KP0);
    conv(lin0_w, w_lin0, 256, 256, FIN, KP0);
    convg(r0_wih, w_r0);
    for (int l = 0; l < 3; ++l) {
        int base = 10 + 12 * l;
        int K  = (l == 0) ? FIN : 256;
        int Kp = (l == 0) ? KP0 : 256;
        conv((const float*)d_in[base + 0], w_lr[l], 256, 256, K, Kp);
        conv((const float*)d_in[base + 2], w_lr[l] + (size_t)256 * Kp, 256, 256, K, Kp);
        convg((const float*)d_in[base + 8], w_ih[l]);
        convg((const float*)d_in[base + 9], w_hh[l]);
        concat2_f32<<<dim3(2), dim3(256), 0, stream>>>(
            (const float*)d_in[base + 1], (const float*)d_in[base + 3], blr[l], 256, 256);
    }
    conv(mh1_w, w_m1, NH1, NH1, 256, 256);
    conv(mh2_w, w_m2, NH2, NH2, NH1, NH1);

    zero_f32<<<dim3(256), dim3(256), 0, stream>>>((float*)deg, NN);
    edge_hist<<<dim3((EP + 255) / 256), dim3(256), 0, stream>>>(ei, deg);
    scan_part<<<dim3(SCB), dim3(256), 0, stream>>>(deg, bsum);
    scan_tops<<<dim3(1), dim3(512), 0, stream>>>(bsum, bpre, rowptr);
    scan_fill<<<dim3(SCB), dim3(256), 0, stream>>>(deg, bpre, rowptr, cursor);
    edge_fill<<<dim3((EP + 255) / 256), dim3(256), 0, stream>>>(ei, rowptr, cursor, esrc);

    // ---- lin0 -> x0 (bf16); rnn0 LSTM from zero state (fused epilogue) ----
    G(xb, w_lin0, KP0, lin0_b, nullptr, ybb, MP, HID, 1);
    GL(ybb, w_r0, 256, nullptr, nullptr, 0, r0_bih, r0_bhh, nullptr, cb, hA);

    // ---- 3x (GATv2 -> LN+ELU -> LSTM) ----
    short* hprev = hA;
    short* hnext = hB;
    for (int l = 0; l < 3; ++l) {
        int base = 10 + 12 * l;
        const float* att = (const float*)d_in[base + 4];
        const float* gb  = (const float*)d_in[base + 5];
        const float* lg  = (const float*)d_in[base + 6];
        const float* lb  = (const float*)d_in[base + 7];
        const float* bih = (const float*)d_in[base + 10];
        const float* bhh = (const float*)d_in[base + 11];
        const short* Ain = (l == 0) ? xb : hprev;
        int K = (l == 0) ? KP0 : 256;

        G(Ain, w_lr[l], K, blr[l], nullptr, xlr, MP, 512, 1);
        gat_fused<<<dim3((NN + 3) / 4), dim3(256), 0, stream>>>(
            xlr, rowptr, esrc, att, gb, lg, lb, ybb);
        GL(ybb, w_ih[l], 256, hprev, w_hh[l], 256, bih, bhh, cb, cb, hnext);
        short* t = hprev; hprev = hnext; hnext = t;
    }

    // ---- mean pool (sorted batch) + MLP head ----
    pool_mean<<<dim3((BG + 3) / 4), dim3(256), 0, stream>>>(hprev, batch, poolb);
    G(poolb, w_m1, 256, mh1_b, z1, nullptr, BG, NH1, 0);
    ln_act_kernel<<<dim3(BG), dim3(256), 0, stream>>>(z1, ln1_g, ln1_b, nullptr, z1b, NH1, 1);
    G(z1b, w_m2, NH1, mh2_b, out, nullptr, BG, NH2, 0);
    ln_act_kernel<<<dim3(BG), dim3(256), 0, stream>>>(out, ln2_g, ln2_b, out, nullptr, NH2, 0);
}

// Round 17
// 1593.330 us; speedup vs baseline: 1.7865x; 1.0019x over previous
//
#include <hip/hip_runtime.h>
#include <hip/hip_bf16.h>
#include <math.h>

// ---------------------------------------------------------------------------
// GraphEncoder round 17: depth-2 / 2-slot LDS pipeline (48KB) -> 3 blocks/CU
// (24 waves, 75% occupancy cap) vs round-16's depth-3/72KB (2 blocks, 50%).
// Round-16 analysis: LDS-read + VALU co-bind at only 16 waves/CU resident;
// occupancy is the overlap limiter. Depth-2 is safe now because (a) the
// round-13 lgkmcnt-pinning defect is fixed (barrier after MFMAs), (b) block
// step time >=1000cyc >> 900cyc load latency, (c) VGPR=64 allows 24 waves.
// vmcnt: stage=3 loads; mid vmcnt(3), final step vmcnt(0); re-stage t+2.
// Everything else identical to round 16 (hierarchical scan, fused GAT, etc).
// ---------------------------------------------------------------------------

constexpr int NN    = 100000;
constexpr int EE    = 400000;
constexpr int EP    = EE + NN;      // 500000 (incl self loops)
constexpr int BG    = 4096;
constexpr int FIN   = 300;
constexpr int HEADS = 4;
constexpr int HID   = 256;
constexpr int G4H   = 1024;
constexpr int NH1   = 512;
constexpr int NH2   = 768;
constexpr int MP    = 100352;       // 392*256, 392 % 8 == 0
constexpr int KP0   = 320;          // FIN padded to mult of 32
constexpr int SCB   = 392;          // scan blocks (392*256 = 100352 >= NN)

typedef __attribute__((ext_vector_type(4))) float f32x4;
typedef __attribute__((ext_vector_type(8))) short s16x8;

#define LOG2E 1.4426950408889634f

// fast HW transcendentals (v_exp_f32 = 2^x, v_rcp_f32)
__device__ inline float fexp(float x)  { return __builtin_amdgcn_exp2f(x * LOG2E); }
__device__ inline float frcp(float x)  { return __builtin_amdgcn_rcpf(x); }
__device__ inline float fsigm(float x) { return frcp(1.f + __builtin_amdgcn_exp2f(-LOG2E * x)); }
__device__ inline float ftanh(float x) { return 1.f - 2.f * frcp(1.f + __builtin_amdgcn_exp2f(2.f * LOG2E * x)); }

__device__ inline float b2f(short s) { return __uint_as_float(((unsigned)(unsigned short)s) << 16); }
__device__ inline short f2b(float f) {
    unsigned u = __float_as_uint(f);
    u += 0x7fff + ((u >> 16) & 1);          // round-to-nearest-even
    return (short)(u >> 16);
}
__device__ inline float wsum64(float v) {
#pragma unroll
    for (int o = 32; o > 0; o >>= 1) v += __shfl_xor(v, o);
    return v;
}

// ---------------- utility kernels -------------------------------------------
__global__ __launch_bounds__(256) void zero_f32(float* __restrict__ p, long long n)
{
    long long i = (long long)blockIdx.x * 256 + threadIdx.x;
    long long stride = (long long)gridDim.x * 256;
    for (; i < n; i += stride) p[i] = 0.f;
}

// f32 -> bf16 with row/col zero padding
__global__ __launch_bounds__(256) void conv_bf16(
    const float* __restrict__ src, short* __restrict__ dst,
    int rsrc, int rdst, int Ks, int Kd)
{
    long long n = (long long)rdst * Kd;
    long long stride = (long long)gridDim.x * 256;
    for (long long i = (long long)blockIdx.x * 256 + threadIdx.x; i < n; i += stride) {
        int r = (int)(i / Kd);
        int k = (int)(i - (long long)r * Kd);
        float v = (r < rsrc && k < Ks) ? src[(long long)r * Ks + k] : 0.f;
        dst[i] = f2b(v);
    }
}

// gate-interleaved pack of LSTM weight [1024][K]:
// new row p -> orig row gate*256+ch, gate=(p>>4)&3, ch=(p>>7)*32+((p>>6)&1)*16+(p&15)
__global__ __launch_bounds__(256) void conv_gates(
    const float* __restrict__ src, short* __restrict__ dst, int K)
{
    long long n = (long long)G4H * K;
    long long stride = (long long)gridDim.x * 256;
    for (long long i = (long long)blockIdx.x * 256 + threadIdx.x; i < n; i += stride) {
        int p = (int)(i / K);
        int k = (int)(i - (long long)p * K);
        int gate = (p >> 4) & 3;
        int ch   = (p >> 7) * 32 + ((p >> 6) & 1) * 16 + (p & 15);
        dst[i] = f2b(src[(size_t)(gate * 256 + ch) * K + k]);
    }
}

__global__ __launch_bounds__(256) void concat2_f32(
    const float* __restrict__ a, const float* __restrict__ b,
    float* __restrict__ dst, int na, int nb)
{
    int i = blockIdx.x * 256 + threadIdx.x;
    if (i < na) dst[i] = a[i];
    else if (i < na + nb) dst[i] = b[i - na];
}

// ---------------- CSR build -------------------------------------------------
__global__ __launch_bounds__(256) void edge_hist(const int* __restrict__ ei,
                                                 int* __restrict__ deg)
{
    int e = blockIdx.x * 256 + threadIdx.x;
    if (e >= EP) return;
    int d = (e < EE) ? ei[EE + e] : e - EE;
    atomicAdd(&deg[d], 1);
}

// pass 1: per-block chunk sums (coalesced)
__global__ __launch_bounds__(256) void scan_part(const int* __restrict__ deg,
                                                 int* __restrict__ bsum)
{
    int b = blockIdx.x, t = threadIdx.x;
    int i = b * 256 + t;
    int v = (i < NN) ? deg[i] : 0;
#pragma unroll
    for (int o = 32; o > 0; o >>= 1) v += __shfl_down(v, o);
    __shared__ int sh[4];
    if ((t & 63) == 0) sh[t >> 6] = v;
    __syncthreads();
    if (t == 0) bsum[b] = sh[0] + sh[1] + sh[2] + sh[3];
}

// pass 2: scan the 392 block sums (single small block)
__global__ __launch_bounds__(512) void scan_tops(const int* __restrict__ bsum,
                                                 int* __restrict__ bpre,
                                                 int* __restrict__ rowptr)
{
    __shared__ int sh[512];
    int t = threadIdx.x;
    int v = (t < SCB) ? bsum[t] : 0;
    sh[t] = v;
    __syncthreads();
    for (int off = 1; off < 512; off <<= 1) {
        int u = (t >= off) ? sh[t - off] : 0;
        __syncthreads();
        sh[t] += u;
        __syncthreads();
    }
    if (t < SCB) bpre[t] = sh[t] - v;          // exclusive prefix
    if (t == SCB - 1) rowptr[NN] = sh[t];      // total == EP
}

// pass 3: intra-block exclusive scan + write rowptr/cursor (coalesced)
__global__ __launch_bounds__(256) void scan_fill(const int* __restrict__ deg,
                                                 const int* __restrict__ bpre,
                                                 int* __restrict__ rowptr,
                                                 int* __restrict__ cursor)
{
    __shared__ int sh[256];
    int b = blockIdx.x, t = threadIdx.x;
    int i = b * 256 + t;
    int v = (i < NN) ? deg[i] : 0;
    sh[t] = v;
    __syncthreads();
    for (int off = 1; off < 256; off <<= 1) {
        int u = (t >= off) ? sh[t - off] : 0;
        __syncthreads();
        sh[t] += u;
        __syncthreads();
    }
    if (i < NN) {
        rowptr[i] = bpre[b] + sh[t] - v;       // exclusive
        cursor[i] = 0;
    }
}

__global__ __launch_bounds__(256) void edge_fill(const int* __restrict__ ei,
                                                 const int* __restrict__ rowptr,
                                                 int* __restrict__ cursor,
                                                 int* __restrict__ esrc)
{
    int e = blockIdx.x * 256 + threadIdx.x;
    if (e >= EP) return;
    int s, d;
    if (e < EE) { s = ei[e]; d = ei[EE + e]; }
    else        { s = d = e - EE; }
    int slot = rowptr[d] + atomicAdd(&cursor[d], 1);
    esrc[slot] = s;
}

// ---------------- MFMA GEMM with fused epilogues ----------------------------
// C[M x N] = A1[M x K1] @ B1[N x K1]^T (+ A2[M x K2] @ B2[N x K2]^T)
// BM=256 x BN=128 tile; 8 waves (512 thr) as 4x2 of 64x64.
// 1-D grid of (M/256)*(N/128) blocks; XCD swizzle: xcd=bid&7, slot=bid>>3,
// g=slot/nct, ct=slot%nct, row_panel=g*8+xcd. Requires (M/256)%8==0.
// 2-slot LDS (48KB -> 3 blocks/CU), depth-2 prefetch, counted vmcnt (3/0).
// Requires KK >= 64 (all call sites have KK >= 256).
// mode 0: +bias -> f32 Cf      mode 1: +bias -> bf16 Cb
// mode 2: LSTM epilogue (gate-interleaved B; N=1024): reads c_in (or 0,
//         prefetched to regs pre-K-loop), writes c_out f32 + h_out bf16.
__global__ __launch_bounds__(512) void mfma_gemm(
    const short* __restrict__ A1, const short* __restrict__ B1, int K1,
    const short* __restrict__ A2, const short* __restrict__ B2, int K2,
    const float* __restrict__ bias,
    const float* __restrict__ bih, const float* __restrict__ bhh,
    const float* __restrict__ c_in, float* __restrict__ c_out,
    short* __restrict__ h_out,
    float* __restrict__ Cf, short* __restrict__ Cb, int N, int mode, int nct)
{
    __shared__ __align__(16) short sA[2][256 * 32];   // 16KB each
    __shared__ __align__(16) short sB[2][128 * 32];   // 8KB each
    const int tid  = threadIdx.x;
    const int w    = tid >> 6, lane = tid & 63;
    const int wr   = w >> 1,  wc   = w & 1;      // 4x2 waves of 64x64
    // XCD-aware decode (consecutive bids round-robin across 8 XCDs)
    const int bid  = blockIdx.x;
    const int xcd  = bid & 7;
    const int slot = bid >> 3;
    const int g    = slot / nct;
    const int tcol = slot - g * nct;
    const int row0 = (g * 8 + xcd) * 256;
    const int col0 = tcol * 128;

    f32x4 acc[4][4];
#pragma unroll
    for (int m = 0; m < 4; ++m)
#pragma unroll
        for (int n = 0; n < 4; ++n) acc[m][n] = (f32x4){0.f, 0.f, 0.f, 0.f};

    const int rs = lane >> 2;
    const int cs = lane & 3;
    const int KK = K1 + K2;
    const int nsteps = KK >> 5;
    const int l16 = lane & 15;
    const int rloc = wr * 64 + ((lane >> 4) << 2);   // block-local base row

    // mode-2: prefetch c_in into regs; latency hides under the K-loop
    float co_pre[4][4] = {};
    const int ch = tcol * 32 + wc * 16 + l16;        // mode-2 channel
    if (mode == 2 && c_in) {
#pragma unroll
        for (int m = 0; m < 4; ++m)
#pragma unroll
            for (int r = 0; r < 4; ++r)
                co_pre[m][r] = c_in[(size_t)(row0 + rloc + m * 16 + r) * HID + ch];
    }

    // 3 global_load_lds per wave per stage call (2x A-seg, 1x B-seg)
    auto stage = [&](int buf, int k0) {
        const short* Ak; const short* Bk; int kk, ld;
        if (k0 < K1) { Ak = A1; Bk = B1; kk = k0;      ld = K1; }
        else         { Ak = A2; Bk = B2; kk = k0 - K1; ld = K2; }
#pragma unroll
        for (int i = 0; i < 2; ++i) {
            int seg = w * 2 + i;                     // 16 A-segs of 16 rows
            int row = seg * 16 + rs;
            int c8  = cs ^ ((row + (row >> 2)) & 3);
            const short* ga = Ak + (size_t)(row0 + row) * ld + kk + c8 * 8;
            short* la = &sA[buf][seg * 512 + lane * 8];
            __builtin_amdgcn_global_load_lds((const __attribute__((address_space(1))) void*)ga,
                                             (__attribute__((address_space(3))) void*)la, 16, 0, 0);
        }
        {
            int row = w * 16 + rs;                   // 8 B-segs of 16 rows
            int c8  = cs ^ ((row + (row >> 2)) & 3);
            const short* gb = Bk + (size_t)(col0 + row) * ld + kk + c8 * 8;
            short* lb = &sB[buf][w * 512 + lane * 8];
            __builtin_amdgcn_global_load_lds((const __attribute__((address_space(1))) void*)gb,
                                             (__attribute__((address_space(3))) void*)lb, 16, 0, 0);
        }
    };

    stage(0, 0);
    stage(1, 32);                  // 6 loads in flight; KK >= 64 guaranteed
    int cur = 0;
    for (int t = 0; t < nsteps; ++t) {
        // wait for group t (oldest); keep the newer group in flight
        if (t + 1 < nsteps) asm volatile("s_waitcnt vmcnt(3)" ::: "memory");
        else                asm volatile("s_waitcnt vmcnt(0)" ::: "memory");
        __builtin_amdgcn_s_barrier();          // all waves: buf[cur] ready
        asm volatile("" ::: "memory");

        s16x8 af[4], bg[4];
        {
            const int rl = lane & 15;
            const int cw = lane >> 4;
#pragma unroll
            for (int m = 0; m < 4; ++m) {
                int r  = wr * 64 + m * 16 + rl;
                int sl = cw ^ ((r + (r >> 2)) & 3);
                af[m] = *(const s16x8*)(&sA[cur][r * 32 + sl * 8]);
                int c  = wc * 64 + m * 16 + rl;
                int sc = cw ^ ((c + (c >> 2)) & 3);
                bg[m] = *(const s16x8*)(&sB[cur][c * 32 + sc * 8]);
            }
        }
        // MFMAs consume all af/bg (compiler interleaves reads+MFMA with
        // fine-grained lgkmcnt); after them this wave's LDS reads are done.
#pragma unroll
        for (int m = 0; m < 4; ++m)
#pragma unroll
            for (int n = 0; n < 4; ++n)
                acc[m][n] = __builtin_amdgcn_mfma_f32_16x16x32_bf16(af[m], bg[n], acc[m][n], 0, 0, 0);

        __builtin_amdgcn_s_barrier();          // all waves done READING buf[cur]
        asm volatile("" ::: "memory");
        if (t + 2 < nsteps) stage(cur, (t + 2) * 32);   // re-stage 2 ahead
        cur ^= 1;
    }

    // C/D layout: col=lane&15, row=(lane>>4)*4+reg
    const int rbase = row0 + rloc;
    if (mode == 2) {
        float bi[4];
#pragma unroll
        for (int gg2 = 0; gg2 < 4; ++gg2) bi[gg2] = bih[gg2 * 256 + ch] + bhh[gg2 * 256 + ch];
#pragma unroll
        for (int m = 0; m < 4; ++m) {
#pragma unroll
            for (int r = 0; r < 4; ++r) {
                int row = rbase + m * 16 + r;
                float gi = acc[m][0][r] + bi[0];
                float gf = acc[m][1][r] + bi[1];
                float gg = acc[m][2][r] + bi[2];
                float go = acc[m][3][r] + bi[3];
                size_t idx = (size_t)row * HID + ch;
                float c2 = fsigm(gf) * co_pre[m][r] + fsigm(gi) * ftanh(gg);
                float h2 = fsigm(go) * ftanh(c2);
                c_out[idx] = c2;
                h_out[idx] = f2b(h2);
            }
        }
    } else {
        const int cbase = col0 + wc * 64 + l16;
#pragma unroll
        for (int n = 0; n < 4; ++n) {
            int col = cbase + n * 16;
            float ba = bias ? bias[col] : 0.f;
#pragma unroll
            for (int m = 0; m < 4; ++m) {
#pragma unroll
                for (int r = 0; r < 4; ++r) {
                    int row = rbase + m * 16 + r;
                    float v = acc[m][n][r] + ba;
                    size_t idx = (size_t)row * N + col;
                    if (mode == 1) Cb[idx] = f2b(v);
                    else           Cf[idx] = v;
                }
            }
        }
    }
}

// ---------------- fused GATv2 (softmax + aggregate + bias + LN + ELU) -------
// one 64-lane wave per dst node; lane l = channel h*64+l per head h.
// xlr: [MP][512] bf16, cols 0..255 = lin_l(x), 256..511 = lin_r(x).
__global__ __launch_bounds__(256) void gat_fused(
    const short* __restrict__ xlr, const int* __restrict__ rowptr,
    const int* __restrict__ esrc, const float* __restrict__ att,
    const float* __restrict__ gb, const float* __restrict__ lg,
    const float* __restrict__ lb, short* __restrict__ outb)
{
    int i    = blockIdx.x * 4 + (threadIdx.x >> 6);
    int lane = threadIdx.x & 63;
    if (i >= NN) return;
    float xr[HEADS], at[HEADS];
#pragma unroll
    for (int h = 0; h < HEADS; ++h) {
        xr[h] = b2f(xlr[(size_t)i * 512 + 256 + h * 64 + lane]);
        at[h] = att[h * 64 + lane];
    }
    float mx[HEADS], sm[HEADS], ac[HEADS];
#pragma unroll
    for (int h = 0; h < HEADS; ++h) { mx[h] = -INFINITY; sm[h] = 0.f; ac[h] = 0.f; }

    int lo = rowptr[i], hi = rowptr[i + 1];
    for (int e = lo; e < hi; ++e) {
        int s = esrc[e];
        float xs[HEADS], p[HEADS];
#pragma unroll
        for (int h = 0; h < HEADS; ++h) {
            xs[h] = b2f(xlr[(size_t)s * 512 + h * 64 + lane]);
            float v = xs[h] + xr[h];
            v = (v >= 0.f) ? v : 0.2f * v;
            p[h] = v * at[h];
        }
#pragma unroll
        for (int h = 0; h < HEADS; ++h) p[h] = wsum64(p[h]);
#pragma unroll
        for (int h = 0; h < HEADS; ++h) {
            float mn = fmaxf(mx[h], p[h]);
            float sc = fexp(mx[h] - mn);     // first iter: exp(-inf)=0
            float a  = fexp(p[h] - mn);
            sm[h] = sm[h] * sc + a;
            ac[h] = ac[h] * sc + a * xs[h];
            mx[h] = mn;
        }
    }
    // y = ac/sm (+ gat bias), then LayerNorm(256) + ELU, write bf16
    float val[HEADS], s1 = 0.f, s2 = 0.f;
#pragma unroll
    for (int h = 0; h < HEADS; ++h) {
        float v = ac[h] * frcp(sm[h]) + gb[h * 64 + lane];
        val[h] = v; s1 += v; s2 += v * v;
    }
    s1 = wsum64(s1); s2 = wsum64(s2);
    float mean = s1 * (1.f / 256.f);
    float var  = s2 * (1.f / 256.f) - mean * mean;
    float inv  = rsqrtf(var + 1e-5f);
#pragma unroll
    for (int h = 0; h < HEADS; ++h) {
        float v = (val[h] - mean) * inv * lg[h * 64 + lane] + lb[h * 64 + lane];
        v = (v > 0.f) ? v : (fexp(v) - 1.f);
        outb[(size_t)i * HID + h * 64 + lane] = f2b(v);
    }
}

// ---------------- LayerNorm (+act) for the MLP head -------------------------
__global__ __launch_bounds__(256) void ln_act_kernel(
    const float* __restrict__ in, const float* __restrict__ gamma,
    const float* __restrict__ beta, float* __restrict__ outf,
    short* __restrict__ outb, int width, int act)
{
    int row = blockIdx.x;
    const float* ip = in + (size_t)row * width;
    float vals[3];
    float s = 0.f, ss = 0.f;
    int nw = width >> 8;
    for (int i = 0; i < nw; ++i) {
        int c = threadIdx.x + (i << 8);
        float v = ip[c];
        vals[i] = v; s += v; ss += v * v;
    }
#pragma unroll
    for (int off = 32; off > 0; off >>= 1) {
        s  += __shfl_down(s, off);
        ss += __shfl_down(ss, off);
    }
    __shared__ float sh[8];
    int wv = threadIdx.x >> 6, lane = threadIdx.x & 63;
    if (lane == 0) { sh[wv] = s; sh[4 + wv] = ss; }
    __syncthreads();
    if (threadIdx.x == 0) {
        sh[0] = sh[0] + sh[1] + sh[2] + sh[3];
        sh[4] = sh[4] + sh[5] + sh[6] + sh[7];
    }
    __syncthreads();
    float mean = sh[0] / width;
    float var  = sh[4] / width - mean * mean;
    float inv  = rsqrtf(var + 1e-5f);
    for (int i = 0; i < nw; ++i) {
        int c = threadIdx.x + (i << 8);
        float v = (vals[i] - mean) * inv * gamma[c] + beta[c];
        if (act == 1) v = fmaxf(v, 0.f);
        if (outb) outb[(size_t)row * width + c] = f2b(v);
        else      outf[(size_t)row * width + c] = v;
    }
}

// ---------------- sorted-batch mean pool ------------------------------------
__global__ __launch_bounds__(256) void pool_mean(
    const short* __restrict__ h, const int* __restrict__ batch,
    short* __restrict__ poolb)
{
    int b    = blockIdx.x * 4 + (threadIdx.x >> 6);
    int lane = threadIdx.x & 63;
    if (b >= BG) return;
    auto lbound = [&](int key) {
        int lo = 0, hi = NN;
        while (lo < hi) { int mid = (lo + hi) >> 1; if (batch[mid] < key) lo = mid + 1; else hi = mid; }
        return lo;
    };
    int lo = lbound(b), hi = lbound(b + 1);
    float acc[HEADS] = {0.f, 0.f, 0.f, 0.f};
    for (int r = lo; r < hi; ++r)
#pragma unroll
        for (int hh = 0; hh < HEADS; ++hh)
            acc[hh] += b2f(h[(size_t)r * HID + hh * 64 + lane]);
    float inv = 1.f / fmaxf((float)(hi - lo), 1.f);
#pragma unroll
    for (int hh = 0; hh < HEADS; ++hh)
        poolb[(size_t)b * HID + hh * 64 + lane] = f2b(acc[hh] * inv);
}

// ---------------------------------------------------------------------------
extern "C" void kernel_launch(void* const* d_in, const int* in_sizes, int n_in,
                              void* d_out, int out_size, void* d_ws, size_t ws_size,
                              hipStream_t stream)
{
    (void)in_sizes; (void)n_in; (void)out_size; (void)ws_size;
    const float* x      = (const float*)d_in[0];
    const int*   ei     = (const int*)d_in[1];
    const int*   batch  = (const int*)d_in[2];
    const float* lin0_w = (const float*)d_in[4];
    const float* lin0_b = (const float*)d_in[5];
    const float* r0_wih = (const float*)d_in[6];
    const float* r0_bih = (const float*)d_in[8];
    const float* r0_bhh = (const float*)d_in[9];
    const float* mh1_w  = (const float*)d_in[46];
    const float* mh1_b  = (const float*)d_in[47];
    const float* ln1_g  = (const float*)d_in[48];
    const float* ln1_b  = (const float*)d_in[49];
    const float* mh2_w  = (const float*)d_in[50];
    const float* mh2_b  = (const float*)d_in[51];
    const float* ln2_g  = (const float*)d_in[52];
    const float* ln2_b  = (const float*)d_in[53];
    float* out = (float*)d_out;

    // ---- workspace bump allocation ----
    char* wsb = (char*)d_ws;
    auto alloc = [&](size_t bytes) -> void* {
        void* p = (void*)wsb;
        wsb += (bytes + 255) & ~(size_t)255;
        return p;
    };
    const size_t NH = (size_t)MP * HID;
    float* cb   = (float*)alloc(NH * 4);          // LSTM cell state f32
    short* hA   = (short*)alloc(NH * 2);          // h ping
    short* hB   = (short*)alloc(NH * 2);          // h pong
    short* ybb  = (short*)alloc(NH * 2);          // LSTM-input / x0 bf16
    short* xlr  = (short*)alloc((size_t)MP * 512 * 2);  // [xl|xr] bf16
    int*   deg    = (int*)alloc((size_t)NN * 4);
    int*   rowptr = (int*)alloc((size_t)(NN + 1) * 4);
    int*   cursor = (int*)alloc((size_t)NN * 4);
    int*   esrc   = (int*)alloc((size_t)EP * 4);
    int*   bsum   = (int*)alloc((size_t)SCB * 4);
    int*   bpre   = (int*)alloc((size_t)SCB * 4);
    // weights bf16
    short* w_lin0 = (short*)alloc((size_t)256 * KP0 * 2);
    short* w_r0   = (short*)alloc((size_t)G4H * 256 * 2);
    short* w_lr[3]; short* w_ih[3]; short* w_hh[3]; float* blr[3];
    for (int l = 0; l < 3; ++l) {
        int Kp = (l == 0) ? KP0 : 256;
        w_lr[l] = (short*)alloc((size_t)512 * Kp * 2);
        w_ih[l] = (short*)alloc((size_t)G4H * 256 * 2);
        w_hh[l] = (short*)alloc((size_t)G4H * 256 * 2);
        blr[l]  = (float*)alloc(512 * 4);
    }
    short* w_m1 = (short*)alloc((size_t)NH1 * 256 * 2);
    short* w_m2 = (short*)alloc((size_t)NH2 * NH1 * 2);
    // xb (layer-0 padded input) with head temps aliased over it (head runs
    // only after xb is dead)
    short* xb = (short*)alloc((size_t)MP * KP0 * 2);   // 64 MB
    float* z1    = (float*)xb;                          // BG*NH1 f32 (8.4MB)
    short* z1b   = (short*)(z1 + (size_t)BG * NH1);     // BG*NH1 bf16
    short* poolb = z1b + (size_t)BG * NH1;              // BG*HID bf16

    auto conv = [&](const float* s, short* d, int rs, int rd, int Ks, int Kd) {
        conv_bf16<<<dim3(512), dim3(256), 0, stream>>>(s, d, rs, rd, Ks, Kd);
    };
    auto convg = [&](const float* s, short* d) {
        conv_gates<<<dim3(512), dim3(256), 0, stream>>>(s, d, 256);
    };
    // mode 0/1 GEMM; 1-D grid with XCD swizzle (requires (M/256)%8==0)
    auto G = [&](const short* A, const short* B, int K, const float* bias,
                 float* Cf, short* Cbb, int M, int N, int mode) {
        int nrp = M / 256, nct = N / 128;
        mfma_gemm<<<dim3(nrp * nct), dim3(512), 0, stream>>>(
            A, B, K, nullptr, nullptr, 0, bias,
            nullptr, nullptr, nullptr, nullptr, nullptr, Cf, Cbb, N, mode, nct);
    };
    // mode 2 LSTM GEMM
    auto GL = [&](const short* A1, const short* B1, int K1,
                  const short* A2, const short* B2, int K2,
                  const float* bih, const float* bhh,
                  const float* ci, float* co, short* ho) {
        mfma_gemm<<<dim3((MP / 256) * 8), dim3(512), 0, stream>>>(
            A1, B1, K1, A2, B2, K2, nullptr,
            bih, bhh, ci, co, ho, nullptr, nullptr, G4H, 2, 8);
    };

    // ---- conversions + CSR build ----
    conv(x, xb, NN, MP, FIN, KP0);
    conv(lin0_w, w_lin0, 256, 256, FIN, KP0);
    convg(r0_wih, w_r0);
    for (int l = 0; l < 3; ++l) {
        int base = 10 + 12 * l;
        int K  = (l == 0) ? FIN : 256;
        int Kp = (l == 0) ? KP0 : 256;
        conv((const float*)d_in[base + 0], w_lr[l], 256, 256, K, Kp);
        conv((const float*)d_in[base + 2], w_lr[l] + (size_t)256 * Kp, 256, 256, K, Kp);
        convg((const float*)d_in[base + 8], w_ih[l]);
        convg((const float*)d_in[base + 9], w_hh[l]);
        concat2_f32<<<dim3(2), dim3(256), 0, stream>>>(
            (const float*)d_in[base + 1], (const float*)d_in[base + 3], blr[l], 256, 256);
    }
    conv(mh1_w, w_m1, NH1, NH1, 256, 256);
    conv(mh2_w, w_m2, NH2, NH2, NH1, NH1);

    zero_f32<<<dim3(256), dim3(256), 0, stream>>>((float*)deg, NN);
    edge_hist<<<dim3((EP + 255) / 256), dim3(256), 0, stream>>>(ei, deg);
    scan_part<<<dim3(SCB), dim3(256), 0, stream>>>(deg, bsum);
    scan_tops<<<dim3(1), dim3(512), 0, stream>>>(bsum, bpre, rowptr);
    scan_fill<<<dim3(SCB), dim3(256), 0, stream>>>(deg, bpre, rowptr, cursor);
    edge_fill<<<dim3((EP + 255) / 256), dim3(256), 0, stream>>>(ei, rowptr, cursor, esrc);

    // ---- lin0 -> x0 (bf16); rnn0 LSTM from zero state (fused epilogue) ----
    G(xb, w_lin0, KP0, lin0_b, nullptr, ybb, MP, HID, 1);
    GL(ybb, w_r0, 256, nullptr, nullptr, 0, r0_bih, r0_bhh, nullptr, cb, hA);

    // ---- 3x (GATv2 -> LN+ELU -> LSTM) ----
    short* hprev = hA;
    short* hnext = hB;
    for (int l = 0; l < 3; ++l) {
        int base = 10 + 12 * l;
        const float* att = (const float*)d_in[base + 4];
        const float* gb  = (const float*)d_in[base + 5];
        const float* lg  = (const float*)d_in[base + 6];
        const float* lb  = (const float*)d_in[base + 7];
        const float* bih = (const float*)d_in[base + 10];
        const float* bhh = (const float*)d_in[base + 11];
        const short* Ain = (l == 0) ? xb : hprev;
        int K = (l == 0) ? KP0 : 256;

        G(Ain, w_lr[l], K, blr[l], nullptr, xlr, MP, 512, 1);
        gat_fused<<<dim3((NN + 3) / 4), dim3(256), 0, stream>>>(
            xlr, rowptr, esrc, att, gb, lg, lb, ybb);
        GL(ybb, w_ih[l], 256, hprev, w_hh[l], 256, bih, bhh, cb, cb, hnext);
        short* t = hprev; hprev = hnext; hnext = t;
    }

    // ---- mean pool (sorted batch) + MLP head ----
    pool_mean<<<dim3((BG + 3) / 4), dim3(256), 0, stream>>>(hprev, batch, poolb);
    G(poolb, w_m1, 256, mh1_b, z1, nullptr, BG, NH1, 0);
    ln_act_kernel<<<dim3(BG), dim3(256), 0, stream>>>(z1, ln1_g, ln1_b, nullptr, z1b, NH1, 1);
    G(z1b, w_m2, NH1, mh2_b, out, nullptr, BG, NH2, 0);
    ln_act_kernel<<<dim3(BG), dim3(256), 0, stream>>>(out, ln2_g, ln2_b, out, nullptr, NH2, 0);
}